// Round 7
// baseline (370.224 us; speedup 1.0000x reference)
//
#include <hip/hip_runtime.h>
#include <math.h>
#include <float.h>

#define N_ROWS 32768
#define D_DIM  256
#define K_DIM  8192

#define EPS1 0.40f   // tier-1 (f16) gap threshold, full-distance scale
#define EPS2 0.02f   // tier-2 (fp32) gap threshold
#define T2CAP 4096   // tier-2 row capacity
#define T3CAP 512    // tier-3 row capacity
#define NSPLIT3 16   // tier-3 K splits (512 cols each)

typedef _Float16 f16;
typedef _Float16 f16x8 __attribute__((ext_vector_type(8)));
typedef float f32x4 __attribute__((ext_vector_type(4)));

#define KSPLIT 8
#define COLS_PER_SPLIT (K_DIM / KSPLIT)      // 1024
#define CHUNK_COLS 64
#define NCHUNK (COLS_PER_SPLIT / CHUNK_COLS) // 16
#define CHUNK_BYTES (CHUNK_COLS * D_DIM * 2) // 32768

// global_load_lds plumbing (clang builtin needs explicit address spaces)
typedef unsigned int u32;
typedef const u32 __attribute__((address_space(1)))* gas1_u32;
typedef u32 __attribute__((address_space(3)))* las3_u32;
__device__ __forceinline__ void gload_lds16(const void* g, void* l) {
    __builtin_amdgcn_global_load_lds((gas1_u32)g, (las3_u32)l, 16, 0, 0);
}

// ---------------------------------------------------------------------------
// convert X fp32 -> f16, [N][D] row-major. 8 elems/thread.
// ---------------------------------------------------------------------------
__global__ void convx_kernel(const float* __restrict__ X, f16* __restrict__ X16) {
    const size_t i = ((size_t)blockIdx.x * 256 + threadIdx.x) * 8;
    float4 a = *reinterpret_cast<const float4*>(X + i);
    float4 b = *reinterpret_cast<const float4*>(X + i + 4);
    f16x8 o;
    o[0]=(f16)a.x; o[1]=(f16)a.y; o[2]=(f16)a.z; o[3]=(f16)a.w;
    o[4]=(f16)b.x; o[5]=(f16)b.y; o[6]=(f16)b.z; o[7]=(f16)b.w;
    *reinterpret_cast<f16x8*>(X16 + i) = o;
}

// ---------------------------------------------------------------------------
// pack E fp32 [D][K] -> Epack f16 in B-fragment-linear order.
// B-frag (16x16x32): lane l, elem j  <-  E[32t + (l>>4)*8 + j][16*tile + (l&15)]
// Epack[(tile*8 + t)*512 + l*8 + j]   (one tile = 16 cols = 4096 f16)
// ---------------------------------------------------------------------------
__global__ void packe_kernel(const float* __restrict__ E, f16* __restrict__ Epack) {
    const int gid = blockIdx.x * 256 + threadIdx.x;  // 512*8*64 = 262144
    const int l    = gid & 63;
    const int t    = (gid >> 6) & 7;
    const int tile = gid >> 9;
    const int k  = 16 * tile + (l & 15);
    const int d0 = 32 * t + (l >> 4) * 8;
    f16x8 o;
#pragma unroll
    for (int j = 0; j < 8; ++j) o[j] = (f16)E[(size_t)(d0 + j) * K_DIM + k];
    *reinterpret_cast<f16x8*>(Epack + (size_t)gid * 8) = o;
}

// ---------------------------------------------------------------------------
// nhen[k] = -0.5 * sum_d E[d][k]^2   (fp32)
// ---------------------------------------------------------------------------
__global__ void nhen_kernel(const float* __restrict__ E, float* __restrict__ nhen) {
    const int k = blockIdx.x * 256 + threadIdx.x;
    float s = 0.0f;
#pragma unroll 8
    for (int d = 0; d < D_DIM; ++d) {
        float v = E[(size_t)d * K_DIM + k];
        s = fmaf(v, v, s);
    }
    nhen[k] = -0.5f * s;
}

// ---------------------------------------------------------------------------
// tiled transpose: ET[k][d] = E[d][k]  (for coalesced gather)
// ---------------------------------------------------------------------------
__global__ void transpose_kernel(const float* __restrict__ E, float* __restrict__ ET) {
    __shared__ float t[64][65];
    const int bk = blockIdx.x & (K_DIM / 64 - 1);   // 128 k-tiles
    const int bd = blockIdx.x >> 7;                 // 4 d-tiles
    const int c  = threadIdx.x & 63;
    const int r0 = (threadIdx.x >> 6) * 16;
    const int d0 = bd * 64, k0 = bk * 64;
#pragma unroll
    for (int i = 0; i < 16; ++i)
        t[r0 + i][c] = E[(size_t)(d0 + r0 + i) * K_DIM + k0 + c];
    __syncthreads();
#pragma unroll
    for (int i = 0; i < 16; ++i)
        ET[(size_t)(k0 + r0 + i) * D_DIM + d0 + c] = t[c][r0 + i];
}

// ---------------------------------------------------------------------------
// pass1: f16 MFMA fused GEMM + per-row top-2 argmax of u = x.e - 0.5||e||^2
// 64-col chunks, double-buffered via global_load_lds (async, frag-linear ->
// linear LDS dest matches the wave-uniform-base + lane*16 write pattern).
// One barrier per chunk; prefetch issued right after it.
// ---------------------------------------------------------------------------
__launch_bounds__(256, 2)
__global__ void pass1_kernel(const f16* __restrict__ X16,
                             const f16* __restrict__ Epack,
                             const float* __restrict__ nhen,
                             float* __restrict__ p_best,
                             float* __restrict__ p_sec,
                             int*   __restrict__ p_idx) {
    __shared__ f16 B_lds[2][CHUNK_BYTES / 2];   // 2 x 32KB (64 cols x 256 d)

    const int tid = threadIdx.x;
    const int wv = tid >> 6;
    const int lane = tid & 63;
    const int l15 = lane & 15;
    const int l4  = lane >> 4;
    const int rg = blockIdx.x >> 3;
    const int ks = blockIdx.x & 7;
    const int rowW = rg * 256 + wv * 64;
    const int colBase = ks * COLS_PER_SPLIT;

    f16x8 A[4][8];
#pragma unroll
    for (int rt = 0; rt < 4; ++rt)
#pragma unroll
        for (int t = 0; t < 8; ++t)
            A[rt][t] = *reinterpret_cast<const f16x8*>(
                X16 + (size_t)(rowW + 16*rt + l15) * D_DIM + 32*t + l4*8);

    float best[16], sec[16];
    int bbase[16];
#pragma unroll
    for (int s = 0; s < 16; ++s) { best[s] = -INFINITY; sec[s] = -INFINITY; bbase[s] = 0; }

    // chunk source: tile = col/16, tile stride 8KB -> split base = colBase*512 bytes
    const char* splitSrc = (const char*)Epack + (size_t)colBase * 512;

    // stage chunk ci into buf b: 32 segments of 1KB; wave wv issues 8.
    // LDS dest (uniform per wave+seg): buf + seg*1024. Global src per-lane.
    auto STAGE = [&](int b, int ci) {
        const char* csrc = splitSrc + (size_t)ci * CHUNK_BYTES;
        char* cdst = (char*)&B_lds[b][0];
#pragma unroll
        for (int c = 0; c < 8; ++c) {
            const int seg = wv * 8 + c;
            gload_lds16(csrc + seg * 1024 + (lane << 4), cdst + seg * 1024);
        }
    };

    STAGE(0, 0);

    for (int ci = 0; ci < NCHUNK; ++ci) {
        __syncthreads();   // drains stage(ci); all waves past compute(ci-1)
        if (ci + 1 < NCHUNK) STAGE((ci + 1) & 1, ci + 1);

        const f16* bufc = &B_lds[ci & 1][0];
        const int c0 = colBase + ci * CHUNK_COLS;

#pragma unroll
        for (int ct = 0; ct < 4; ++ct) {
            const float nh = nhen[c0 + 16*ct + l15];
            const f32x4 nh4 = {nh, nh, nh, nh};
            f32x4 acc[4];
            {
                f16x8 B = *reinterpret_cast<const f16x8*>(bufc + (ct*8)*512 + lane*8);
#pragma unroll
                for (int rt = 0; rt < 4; ++rt)
                    acc[rt] = __builtin_amdgcn_mfma_f32_16x16x32_f16(A[rt][0], B, nh4, 0, 0, 0);
            }
#pragma unroll
            for (int t = 1; t < 8; ++t) {
                f16x8 B = *reinterpret_cast<const f16x8*>(bufc + (ct*8 + t)*512 + lane*8);
#pragma unroll
                for (int rt = 0; rt < 4; ++rt)
                    acc[rt] = __builtin_amdgcn_mfma_f32_16x16x32_f16(A[rt][t], B, acc[rt], 0, 0, 0);
            }
            // top-2 tracking, 4 VALU/elem: med3 + cmp + 2 sel.
            // sec' = median(v, best_old, sec_old) (invariant best >= sec).
#pragma unroll
            for (int rt = 0; rt < 4; ++rt) {
#pragma unroll
                for (int r = 0; r < 4; ++r) {
                    const float v = acc[rt][r];
                    const int sl = rt*4 + r;
                    sec[sl] = __builtin_amdgcn_fmed3f(v, best[sl], sec[sl]);
                    const bool gt = v > best[sl];
                    best[sl] = gt ? v : best[sl];
                    bbase[sl] = gt ? (c0 + 16*ct) : bbase[sl];
                }
            }
        }
    }

#pragma unroll
    for (int s = 0; s < 16; ++s) {
        float b = best[s], sc = sec[s];
        int k = bbase[s] + l15;
#pragma unroll
        for (int off = 8; off >= 1; off >>= 1) {
            float ob = __shfl_xor(b, off, 16);
            float os = __shfl_xor(sc, off, 16);
            int   ok = __shfl_xor(k, off, 16);
            float sm = fmaxf(fmaxf(sc, os), fminf(b, ob));
            bool take = (ob > b) || (ob == b && ok < k);
            b = take ? ob : b;
            k = take ? ok : k;
            sc = sm;
        }
        if (l15 == 0) {
            const int row = rowW + 16*(s >> 2) + 4*l4 + (s & 3);
            p_best[ks * N_ROWS + row] = b;
            p_sec [ks * N_ROWS + row] = sc;
            p_idx [ks * N_ROWS + row] = k;
        }
    }
}

// ---------------------------------------------------------------------------
__global__ void zero_counts_kernel(int* count, int* count3) { *count = 0; *count3 = 0; }

// merge K-splits; flag rows with gap < EPS1 into compacted tier-2 list
__global__ void merge_kernel(const float* __restrict__ p_best,
                             const float* __restrict__ p_sec,
                             const int*   __restrict__ p_idx,
                             int* __restrict__ idxf,
                             int* __restrict__ list, int* __restrict__ count) {
    const int n = blockIdx.x * 256 + threadIdx.x;
    float b = p_best[n], sc = p_sec[n];
    int k = p_idx[n];
#pragma unroll
    for (int s = 1; s < KSPLIT; ++s) {
        float ob = p_best[s * N_ROWS + n];
        float os = p_sec [s * N_ROWS + n];
        int   ok = p_idx [s * N_ROWS + n];
        float sm = fmaxf(fmaxf(sc, os), fminf(b, ob));
        bool take = ob > b;            // equal -> keep earlier split (smaller k)
        b = take ? ob : b; k = take ? ok : k; sc = sm;
    }
    idxf[n] = k;
    if (2.0f * (b - sc) < EPS1) {
        int pos = atomicAdd(count, 1);
        if (pos < T2CAP) list[pos] = n;
    }
}

// ---------------------------------------------------------------------------
// tier-2: fp32 rescan of flagged rows. Block = (group of 64 rows) x (512-col
// split). Tracks top-2 max of u = dot + nhen.
// ---------------------------------------------------------------------------
__launch_bounds__(256, 2)
__global__ void tier2_kernel(const float* __restrict__ X,
                             const float* __restrict__ E,
                             const float* __restrict__ nhen,
                             const int* __restrict__ list,
                             const int* __restrict__ count,
                             float* __restrict__ t2b, float* __restrict__ t2s,
                             int* __restrict__ t2i) {
    const int g  = blockIdx.x >> 4;
    const int sp = blockIdx.x & 15;
    const int cnt = min(*count, T2CAP);
    if (g * 64 >= cnt) return;

    __shared__ float xT[D_DIM][64];
    __shared__ float es[64][64];
    const int tid = threadIdx.x;
    const int tx = tid & 15, ty = tid >> 4;

    {
        const int r = tid >> 2;
        const int slot = min(g * 64 + r, cnt - 1);
        const int row = list[slot];
        const int d0 = (tid & 3) * 64;
        const float* xp = X + (size_t)row * D_DIM + d0;
#pragma unroll
        for (int i = 0; i < 64; i += 4) {
            float4 v = *reinterpret_cast<const float4*>(xp + i);
            xT[d0+i+0][r] = v.x; xT[d0+i+1][r] = v.y;
            xT[d0+i+2][r] = v.z; xT[d0+i+3][r] = v.w;
        }
    }

    float best[4], sec[4]; int bidx[4];
#pragma unroll
    for (int i = 0; i < 4; ++i) { best[i] = -INFINITY; sec[i] = -INFINITY; bidx[i] = 0; }

    const int colBase = sp * 512;
    for (int kc = 0; kc < 512; kc += 64) {
        float acc[4][4];
#pragma unroll
        for (int i = 0; i < 4; ++i)
#pragma unroll
            for (int j = 0; j < 4; ++j) acc[i][j] = 0.0f;

        for (int dc = 0; dc < D_DIM; dc += 64) {
            __syncthreads();
#pragma unroll
            for (int dd = 0; dd < 64; dd += 16) {
                int d = dd + (tid >> 4);
                float4 v = *reinterpret_cast<const float4*>(
                    &E[(size_t)(dc + d) * K_DIM + colBase + kc + (tid & 15) * 4]);
                *reinterpret_cast<float4*>(&es[d][(tid & 15) * 4]) = v;
            }
            __syncthreads();
#pragma unroll 8
            for (int d = 0; d < 64; ++d) {
                float4 xv = *reinterpret_cast<const float4*>(&xT[dc + d][ty * 4]);
                float4 ev = *reinterpret_cast<const float4*>(&es[d][tx * 4]);
                float xr[4] = {xv.x, xv.y, xv.z, xv.w};
                float ec[4] = {ev.x, ev.y, ev.z, ev.w};
#pragma unroll
                for (int i = 0; i < 4; ++i)
#pragma unroll
                    for (int j = 0; j < 4; ++j)
                        acc[i][j] = fmaf(xr[i], ec[j], acc[i][j]);
            }
        }
        float4 nhv = *reinterpret_cast<const float4*>(&nhen[colBase + kc + tx * 4]);
        float nh[4] = {nhv.x, nhv.y, nhv.z, nhv.w};
#pragma unroll
        for (int j = 0; j < 4; ++j) {
            const int k = colBase + kc + tx * 4 + j;
#pragma unroll
            for (int i = 0; i < 4; ++i) {
                float u = nh[j] + acc[i][j];
                bool gt = u > best[i];
                sec[i]  = fmaxf(sec[i], fminf(u, best[i]));
                best[i] = gt ? u : best[i];
                bidx[i] = gt ? k : bidx[i];
            }
        }
    }

#pragma unroll
    for (int off = 8; off >= 1; off >>= 1) {
#pragma unroll
        for (int i = 0; i < 4; ++i) {
            float ob = __shfl_xor(best[i], off, 16);
            float os = __shfl_xor(sec[i], off, 16);
            int   ok = __shfl_xor(bidx[i], off, 16);
            float sm = fmaxf(fmaxf(sec[i], os), fminf(best[i], ob));
            bool take = (ob > best[i]) || (ob == best[i] && ok < bidx[i]);
            best[i] = take ? ob : best[i];
            bidx[i] = take ? ok : bidx[i];
            sec[i] = sm;
        }
    }
    if (tx == 0) {
#pragma unroll
        for (int i = 0; i < 4; ++i) {
            const int slot = g * 64 + ty * 4 + i;
            if (slot < cnt) {
                t2b[sp * T2CAP + slot] = best[i];
                t2s[sp * T2CAP + slot] = sec[i];
                t2i[sp * T2CAP + slot] = bidx[i];
            }
        }
    }
}

// merge tier-2 splits; flag knife-edge rows into compacted tier-3 list
__global__ void merge2_kernel(const float* __restrict__ t2b,
                              const float* __restrict__ t2s,
                              const int*   __restrict__ t2i,
                              const int* __restrict__ list,
                              const int* __restrict__ count,
                              int* __restrict__ idxf,
                              int* __restrict__ list3, int* __restrict__ count3) {
    const int slot = blockIdx.x * 256 + threadIdx.x;
    const int cnt = min(*count, T2CAP);
    if (slot >= cnt) return;
    float b = t2b[slot], sc = t2s[slot];
    int k = t2i[slot];
#pragma unroll
    for (int sp = 1; sp < 16; ++sp) {
        float ob = t2b[sp * T2CAP + slot];
        float os = t2s[sp * T2CAP + slot];
        int   ok = t2i[sp * T2CAP + slot];
        float sm = fmaxf(fmaxf(sc, os), fminf(b, ob));
        bool take = ob > b;
        b = take ? ob : b; k = take ? ok : k; sc = sm;
    }
    const int n = list[slot];
    idxf[n] = k;
    if (2.0f * (b - sc) < EPS2) {
        int pos = atomicAdd(count3, 1);
        if (pos < T3CAP) list3[pos] = n;
    }
}

// ---------------------------------------------------------------------------
// tier-3: fp64 exact rescan, K split 16 ways across blocks.
// ---------------------------------------------------------------------------
__launch_bounds__(256)
__global__ void tier3_kernel(const float* __restrict__ X,
                             const float* __restrict__ E,
                             const int* __restrict__ list3,
                             const int* __restrict__ count3,
                             double* __restrict__ t3b, int* __restrict__ t3i) {
    const int slot = blockIdx.x >> 4;
    const int sp   = blockIdx.x & 15;
    const int cnt = min(*count3, T3CAP);
    if (slot >= cnt) return;
    const int n = list3[slot];

    __shared__ float xs[D_DIM];
    const int tid = threadIdx.x;
    xs[tid] = X[(size_t)n * D_DIM + tid];
    __syncthreads();

    const int colBase = sp * 512;
    double best = DBL_MAX;
    int bi = 0x7fffffff;
#pragma unroll
    for (int kk = 0; kk < 512; kk += 256) {
        const int k = colBase + kk + tid;
        double s0 = 0.0, s1 = 0.0, s2 = 0.0, s3 = 0.0;
#pragma unroll 4
        for (int d = 0; d < D_DIM; d += 4) {
            double f0 = (double)xs[d+0] - (double)E[(size_t)(d+0) * K_DIM + k];
            double f1 = (double)xs[d+1] - (double)E[(size_t)(d+1) * K_DIM + k];
            double f2 = (double)xs[d+2] - (double)E[(size_t)(d+2) * K_DIM + k];
            double f3 = (double)xs[d+3] - (double)E[(size_t)(d+3) * K_DIM + k];
            s0 = fma(f0, f0, s0); s1 = fma(f1, f1, s1);
            s2 = fma(f2, f2, s2); s3 = fma(f3, f3, s3);
        }
        double s = (s0 + s1) + (s2 + s3);
        if (s < best) { best = s; bi = k; }
    }

    __shared__ double bv[256];
    __shared__ int bix[256];
    bv[tid] = best; bix[tid] = bi;
    __syncthreads();
    if (tid == 0) {
        double b = bv[0]; int ix = bix[0];
        for (int t = 1; t < 256; ++t)
            if (bv[t] < b || (bv[t] == b && bix[t] < ix)) { b = bv[t]; ix = bix[t]; }
        t3b[sp * T3CAP + slot] = b;
        t3i[sp * T3CAP + slot] = ix;
    }
}

__global__ void merge3_kernel(const double* __restrict__ t3b,
                              const int* __restrict__ t3i,
                              const int* __restrict__ list3,
                              const int* __restrict__ count3,
                              int* __restrict__ idxf) {
    const int slot = blockIdx.x * 256 + threadIdx.x;
    const int cnt = min(*count3, T3CAP);
    if (slot >= cnt) return;
    double b = t3b[slot];
    int k = t3i[slot];
#pragma unroll
    for (int sp = 1; sp < NSPLIT3; ++sp) {
        double ob = t3b[sp * T3CAP + slot];
        int   ok = t3i[sp * T3CAP + slot];
        if (ob < b || (ob == b && ok < k)) { b = ob; k = ok; }
    }
    idxf[list3[slot]] = k;
}

// ---------------------------------------------------------------------------
// gather from transposed table: out[n][:] = ET[idx[n]][:]  (coalesced)
// ---------------------------------------------------------------------------
__global__ void gather2_kernel(const float* __restrict__ ET,
                               const int* __restrict__ idx,
                               float* __restrict__ out) {
    const int n  = blockIdx.x * 4 + (threadIdx.x >> 6);
    const int d4 = (threadIdx.x & 63) * 4;
    const int k  = idx[n];
    *reinterpret_cast<float4*>(&out[(size_t)n * D_DIM + d4]) =
        *reinterpret_cast<const float4*>(&ET[(size_t)k * D_DIM + d4]);
}

// strided fallback gather (no ET workspace)
__global__ void gather_kernel(const float* __restrict__ E,
                              const int* __restrict__ idx,
                              float* __restrict__ out) {
    const int n = blockIdx.x;
    const int d = threadIdx.x;
    const int k = idx[n];
    out[(size_t)n * D_DIM + d] = E[(size_t)d * K_DIM + k];
}

// ======================= fallback path (proven round-2) =====================
__global__ void fb_enorm_kernel(const float* __restrict__ E, float* __restrict__ enorm) {
    int k = blockIdx.x * 256 + threadIdx.x;
    float s = 0.0f;
#pragma unroll 8
    for (int d = 0; d < D_DIM; ++d) { float v = E[(size_t)d * K_DIM + k]; s = fmaf(v, v, s); }
    enorm[k] = s;
}

__launch_bounds__(256, 2)
__global__ void fb_dist_kernel(const float* __restrict__ X, const float* __restrict__ E,
                               const float* __restrict__ enorm,
                               int* __restrict__ idx_out, float* __restrict__ gap_out) {
    __shared__ float xT[D_DIM][64];
    __shared__ float es[64][64];
    const int tid = threadIdx.x;
    const int tx = tid & 15, ty = tid >> 4;
    const int rowBase = blockIdx.x * 64;
    {
        const int r = tid >> 2;
        const int d0 = (tid & 3) * 64;
        const float* xp = X + (size_t)(rowBase + r) * D_DIM + d0;
#pragma unroll
        for (int i = 0; i < 64; i += 4) {
            float4 v = *reinterpret_cast<const float4*>(xp + i);
            xT[d0+i+0][r]=v.x; xT[d0+i+1][r]=v.y; xT[d0+i+2][r]=v.z; xT[d0+i+3][r]=v.w;
        }
    }
    float bestVal[4], secVal[4]; int bestIdx[4];
#pragma unroll
    for (int i = 0; i < 4; ++i) { bestVal[i]=INFINITY; secVal[i]=INFINITY; bestIdx[i]=0; }
    for (int kc = 0; kc < K_DIM; kc += 64) {
        float acc[4][4];
#pragma unroll
        for (int i=0;i<4;++i)
#pragma unroll
            for (int j=0;j<4;++j) acc[i][j]=0.f;
        for (int dc = 0; dc < D_DIM; dc += 64) {
            __syncthreads();
#pragma unroll
            for (int dd = 0; dd < 64; dd += 16) {
                int d = dd + (tid >> 4);
                float4 v = *reinterpret_cast<const float4*>(
                    &E[(size_t)(dc+d)*K_DIM + kc + (tid&15)*4]);
                *reinterpret_cast<float4*>(&es[d][(tid&15)*4]) = v;
            }
            __syncthreads();
#pragma unroll 8
            for (int d = 0; d < 64; ++d) {
                float4 xv = *reinterpret_cast<const float4*>(&xT[dc+d][ty*4]);
                float4 ev = *reinterpret_cast<const float4*>(&es[d][tx*4]);
                float xr[4]={xv.x,xv.y,xv.z,xv.w}, ec[4]={ev.x,ev.y,ev.z,ev.w};
#pragma unroll
                for (int i=0;i<4;++i)
#pragma unroll
                    for (int j=0;j<4;++j) acc[i][j]=fmaf(xr[i],ec[j],acc[i][j]);
            }
        }
        float4 env = *reinterpret_cast<const float4*>(&enorm[kc + tx*4]);
        float en[4]={env.x,env.y,env.z,env.w};
#pragma unroll
        for (int j=0;j<4;++j) {
            int k = kc + tx*4 + j;
#pragma unroll
            for (int i=0;i<4;++i) {
                float s = fmaf(-2.0f, acc[i][j], en[j]);
                if (s < bestVal[i]) { secVal[i]=bestVal[i]; bestVal[i]=s; bestIdx[i]=k; }
                else if (s < secVal[i]) secVal[i]=s;
            }
        }
    }
#pragma unroll
    for (int off=8; off>=1; off>>=1) {
#pragma unroll
        for (int i=0;i<4;++i) {
            float oB=__shfl_xor(bestVal[i],off,16);
            int oI=__shfl_xor(bestIdx[i],off,16);
            float oS=__shfl_xor(secVal[i],off,16);
            float ms=fminf(fminf(secVal[i],oS),fmaxf(bestVal[i],oB));
            if (oB<bestVal[i] || (oB==bestVal[i] && oI<bestIdx[i])) { bestVal[i]=oB; bestIdx[i]=oI; }
            secVal[i]=ms;
        }
    }
    if (tx==0) {
#pragma unroll
        for (int i=0;i<4;++i) {
            idx_out[rowBase + ty*4 + i] = bestIdx[i];
            gap_out[rowBase + ty*4 + i] = secVal[i]-bestVal[i];
        }
    }
}

__launch_bounds__(256)
__global__ void fb_refine_kernel(const float* __restrict__ X, const float* __restrict__ E,
                                 const float* __restrict__ gap, int* __restrict__ idx) {
    const int n = blockIdx.x;
    if (gap[n] >= 0.0625f) return;
    __shared__ float xs[D_DIM];
    const int tid = threadIdx.x;
    xs[tid] = X[(size_t)n * D_DIM + tid];
    __syncthreads();
    double best = DBL_MAX; int bi = 0x7fffffff;
    for (int k = tid; k < K_DIM; k += 256) {
        double s0=0,s1=0,s2=0,s3=0;
#pragma unroll 4
        for (int d = 0; d < D_DIM; d += 4) {
            double f0=(double)xs[d+0]-(double)E[(size_t)(d+0)*K_DIM+k];
            double f1=(double)xs[d+1]-(double)E[(size_t)(d+1)*K_DIM+k];
            double f2=(double)xs[d+2]-(double)E[(size_t)(d+2)*K_DIM+k];
            double f3=(double)xs[d+3]-(double)E[(size_t)(d+3)*K_DIM+k];
            s0=fma(f0,f0,s0); s1=fma(f1,f1,s1); s2=fma(f2,f2,s2); s3=fma(f3,f3,s3);
        }
        double s=(s0+s1)+(s2+s3);
        if (s<best){best=s;bi=k;}
    }
    __shared__ double bv[256]; __shared__ int bix[256];
    bv[tid]=best; bix[tid]=bi;
    __syncthreads();
    if (tid==0) {
        double b=bv[0]; int ix=bix[0];
        for (int t=1;t<256;++t)
            if (bv[t]<b || (bv[t]==b && bix[t]<ix)) { b=bv[t]; ix=bix[t]; }
        idx[n]=ix;
    }
}

// ---------------------------------------------------------------------------
extern "C" void kernel_launch(void* const* d_in, const int* in_sizes, int n_in,
                              void* d_out, int out_size, void* d_ws, size_t ws_size,
                              hipStream_t stream) {
    const float* X = (const float*)d_in[0];
    const float* E = (const float*)d_in[1];
    float* out = (float*)d_out;
    char* ws = (char*)d_ws;

    // fast-path workspace layout
    const size_t o_nhen  = 0;                                       // K*4
    const size_t o_pb    = 32768;
    const size_t o_ps    = o_pb  + (size_t)KSPLIT * N_ROWS * 4;
    const size_t o_pi    = o_ps  + (size_t)KSPLIT * N_ROWS * 4;
    const size_t o_idx   = o_pi  + (size_t)KSPLIT * N_ROWS * 4;
    const size_t o_list  = o_idx + (size_t)N_ROWS * 4;
    const size_t o_count = o_list + (size_t)T2CAP * 4;              // count @+0, count3 @+4
    const size_t o_t2b   = o_count + 256;
    const size_t o_t2s   = o_t2b + (size_t)16 * T2CAP * 4;
    const size_t o_t2i   = o_t2s + (size_t)16 * T2CAP * 4;
    const size_t o_list3 = o_t2i + (size_t)16 * T2CAP * 4;
    const size_t o_t3b   = o_list3 + (size_t)T3CAP * 4;             // 8B-aligned
    const size_t o_t3i   = o_t3b + (size_t)NSPLIT3 * T3CAP * 8;
    const size_t o_x16   = o_t3i + (size_t)NSPLIT3 * T3CAP * 4;
    const size_t o_epack = o_x16 + (size_t)N_ROWS * D_DIM * 2;
    const size_t NEED_BASE = o_epack + (size_t)D_DIM * K_DIM * 2;
    const size_t o_et    = NEED_BASE;                               // optional ET
    const size_t NEED_FULL = o_et + (size_t)D_DIM * K_DIM * 4;

    if (ws_size >= NEED_BASE) {
        float*  nhen  = (float*) (ws + o_nhen);
        float*  p_b   = (float*) (ws + o_pb);
        float*  p_s   = (float*) (ws + o_ps);
        int*    p_i   = (int*)   (ws + o_pi);
        int*    idxf  = (int*)   (ws + o_idx);
        int*    list  = (int*)   (ws + o_list);
        int*    count = (int*)   (ws + o_count);
        int*    count3= (int*)   (ws + o_count + 4);
        float*  t2b   = (float*) (ws + o_t2b);
        float*  t2s   = (float*) (ws + o_t2s);
        int*    t2i   = (int*)   (ws + o_t2i);
        int*    list3 = (int*)   (ws + o_list3);
        double* t3b   = (double*)(ws + o_t3b);
        int*    t3i   = (int*)   (ws + o_t3i);
        f16*    X16   = (f16*)   (ws + o_x16);
        f16*    Epack = (f16*)   (ws + o_epack);
        float*  ET    = (float*) (ws + o_et);
        const bool haveET = ws_size >= NEED_FULL;

        convx_kernel<<<(N_ROWS * D_DIM / 8) / 256, 256, 0, stream>>>(X, X16);
        packe_kernel<<<(K_DIM / 16) * 8 * 64 / 256, 256, 0, stream>>>(E, Epack);
        nhen_kernel<<<K_DIM / 256, 256, 0, stream>>>(E, nhen);
        if (haveET)
            transpose_kernel<<<(K_DIM / 64) * (D_DIM / 64), 256, 0, stream>>>(E, ET);
        zero_counts_kernel<<<1, 1, 0, stream>>>(count, count3);
        pass1_kernel<<<(N_ROWS / 256) * KSPLIT, 256, 0, stream>>>(
            X16, Epack, nhen, p_b, p_s, p_i);
        merge_kernel<<<N_ROWS / 256, 256, 0, stream>>>(
            p_b, p_s, p_i, idxf, list, count);
        tier2_kernel<<<(T2CAP / 64) * 16, 256, 0, stream>>>(
            X, E, nhen, list, count, t2b, t2s, t2i);
        merge2_kernel<<<T2CAP / 256, 256, 0, stream>>>(
            t2b, t2s, t2i, list, count, idxf, list3, count3);
        tier3_kernel<<<T3CAP * NSPLIT3, 256, 0, stream>>>(
            X, E, list3, count3, t3b, t3i);
        merge3_kernel<<<T3CAP / 256, 256, 0, stream>>>(
            t3b, t3i, list3, count3, idxf);
        if (haveET)
            gather2_kernel<<<N_ROWS / 4, 256, 0, stream>>>(ET, idxf, out);
        else
            gather_kernel<<<N_ROWS, 256, 0, stream>>>(E, idxf, out);
    } else {
        float* enorm = (float*)ws;
        int*   idx   = (int*)(ws + 32768);
        float* gap   = (float*)(ws + 32768 + (size_t)N_ROWS * 4);
        fb_enorm_kernel<<<K_DIM / 256, 256, 0, stream>>>(E, enorm);
        fb_dist_kernel<<<N_ROWS / 64, 256, 0, stream>>>(X, E, enorm, idx, gap);
        fb_refine_kernel<<<N_ROWS, 256, 0, stream>>>(X, E, gap, idx);
        gather_kernel<<<N_ROWS, 256, 0, stream>>>(E, idx, out);
    }
}

// Round 8
// 327.666 us; speedup vs baseline: 1.1299x; 1.1299x over previous
//
#include <hip/hip_runtime.h>
#include <math.h>
#include <float.h>

#define N_ROWS 32768
#define D_DIM  256
#define K_DIM  8192

#define EPS1 0.25f   // tier-1 (f16) gap threshold, full-distance scale (28 sigma)
#define EPS2 0.02f   // tier-2 (fp32) gap threshold
#define T2CAP 4096   // tier-2 row capacity
#define T3CAP 512    // tier-3 row capacity
#define NSPLIT3 16   // tier-3 K splits (512 cols each)

typedef _Float16 f16;
typedef _Float16 f16x8 __attribute__((ext_vector_type(8)));
typedef float f32x4 __attribute__((ext_vector_type(4)));

#define KSPLIT 8
#define COLS_PER_SPLIT (K_DIM / KSPLIT)      // 1024
#define CHUNK_COLS 32
#define NCHUNK (COLS_PER_SPLIT / CHUNK_COLS) // 32

// ---------------------------------------------------------------------------
// convert X fp32 -> f16, [N][D] row-major. 8 elems/thread.
// ---------------------------------------------------------------------------
__global__ void convx_kernel(const float* __restrict__ X, f16* __restrict__ X16) {
    const size_t i = ((size_t)blockIdx.x * 256 + threadIdx.x) * 8;
    float4 a = *reinterpret_cast<const float4*>(X + i);
    float4 b = *reinterpret_cast<const float4*>(X + i + 4);
    f16x8 o;
    o[0]=(f16)a.x; o[1]=(f16)a.y; o[2]=(f16)a.z; o[3]=(f16)a.w;
    o[4]=(f16)b.x; o[5]=(f16)b.y; o[6]=(f16)b.z; o[7]=(f16)b.w;
    *reinterpret_cast<f16x8*>(X16 + i) = o;
}

// ---------------------------------------------------------------------------
// tiled transpose: ET[k][d] = E[d][k]  (for coalesced gather + packe)
// ---------------------------------------------------------------------------
__global__ void transpose_kernel(const float* __restrict__ E, float* __restrict__ ET) {
    __shared__ float t[64][65];
    const int bk = blockIdx.x & (K_DIM / 64 - 1);   // 128 k-tiles
    const int bd = blockIdx.x >> 7;                 // 4 d-tiles
    const int c  = threadIdx.x & 63;
    const int r0 = (threadIdx.x >> 6) * 16;
    const int d0 = bd * 64, k0 = bk * 64;
#pragma unroll
    for (int i = 0; i < 16; ++i)
        t[r0 + i][c] = E[(size_t)(d0 + r0 + i) * K_DIM + k0 + c];
    __syncthreads();
#pragma unroll
    for (int i = 0; i < 16; ++i)
        ET[(size_t)(k0 + r0 + i) * D_DIM + d0 + c] = t[c][r0 + i];
}

// ---------------------------------------------------------------------------
// pack E -> Epack f16 in B-fragment-linear order, reading from ET (coalesced:
// each thread 2x16B contiguous; lane groups {l,l+16,l+32,l+48} share a line).
// B-frag (16x16x32): lane l, elem j <- E[32t + (l>>4)*8 + j][16*tile + (l&15)]
// Epack[(tile*8 + t)*512 + l*8 + j]   (one tile = 16 cols = 4096 f16)
// ---------------------------------------------------------------------------
__global__ void packe_et_kernel(const float* __restrict__ ET, f16* __restrict__ Epack) {
    const int gid = blockIdx.x * 256 + threadIdx.x;  // 512*8*64 = 262144
    const int l    = gid & 63;
    const int t    = (gid >> 6) & 7;
    const int tile = gid >> 9;
    const int k  = 16 * tile + (l & 15);
    const int d0 = 32 * t + (l >> 4) * 8;
    float4 a = *reinterpret_cast<const float4*>(&ET[(size_t)k * D_DIM + d0]);
    float4 b = *reinterpret_cast<const float4*>(&ET[(size_t)k * D_DIM + d0 + 4]);
    f16x8 o;
    o[0]=(f16)a.x; o[1]=(f16)a.y; o[2]=(f16)a.z; o[3]=(f16)a.w;
    o[4]=(f16)b.x; o[5]=(f16)b.y; o[6]=(f16)b.z; o[7]=(f16)b.w;
    *reinterpret_cast<f16x8*>(Epack + (size_t)gid * 8) = o;
}

// fallback packe reading E directly (no ET workspace)
__global__ void packe_kernel(const float* __restrict__ E, f16* __restrict__ Epack) {
    const int gid = blockIdx.x * 256 + threadIdx.x;
    const int l    = gid & 63;
    const int t    = (gid >> 6) & 7;
    const int tile = gid >> 9;
    const int k  = 16 * tile + (l & 15);
    const int d0 = 32 * t + (l >> 4) * 8;
    f16x8 o;
#pragma unroll
    for (int j = 0; j < 8; ++j) o[j] = (f16)E[(size_t)(d0 + j) * K_DIM + k];
    *reinterpret_cast<f16x8*>(Epack + (size_t)gid * 8) = o;
}

// ---------------------------------------------------------------------------
// nhen[k] = -0.5 * sum_d E[d][k]^2   (fp32)
// ---------------------------------------------------------------------------
__global__ void nhen_kernel(const float* __restrict__ E, float* __restrict__ nhen) {
    const int k = blockIdx.x * 256 + threadIdx.x;
    float s = 0.0f;
#pragma unroll 8
    for (int d = 0; d < D_DIM; ++d) {
        float v = E[(size_t)d * K_DIM + k];
        s = fmaf(v, v, s);
    }
    nhen[k] = -0.5f * s;
}

// ---------------------------------------------------------------------------
// pass1 (round-6 proven version): f16 MFMA fused GEMM + per-row top-2 argmax
// of u = x.e - 0.5||e||^2. KSPLIT=8, 32-col chunks, reg-staged double buffer.
// ---------------------------------------------------------------------------
__launch_bounds__(256, 2)
__global__ void pass1_kernel(const f16* __restrict__ X16,
                             const f16* __restrict__ Epack,
                             const float* __restrict__ nhen,
                             float* __restrict__ p_best,
                             float* __restrict__ p_sec,
                             int*   __restrict__ p_idx) {
    __shared__ f16 B_lds[2][8192];   // 2 x 16KB (32 cols x 256 d)

    const int tid = threadIdx.x;
    const int wv = tid >> 6;
    const int lane = tid & 63;
    const int l15 = lane & 15;
    const int l4  = lane >> 4;
    const int rg = blockIdx.x >> 3;
    const int ks = blockIdx.x & 7;
    const int rowW = rg * 256 + wv * 64;
    const int colBase = ks * COLS_PER_SPLIT;

    f16x8 A[4][8];
#pragma unroll
    for (int rt = 0; rt < 4; ++rt)
#pragma unroll
        for (int t = 0; t < 8; ++t)
            A[rt][t] = *reinterpret_cast<const f16x8*>(
                X16 + (size_t)(rowW + 16*rt + l15) * D_DIM + 32*t + l4*8);

    float best[16], sec[16];
    int bbase[16];
#pragma unroll
    for (int s = 0; s < 16; ++s) { best[s] = -INFINITY; sec[s] = -INFINITY; bbase[s] = 0; }

    // chunk source: tile index = colBase/16, each tile = 8*512 f16
    // -> f16 offset = (colBase/16)*4096 = colBase*256
    const float4* src = reinterpret_cast<const float4*>(
        Epack + (size_t)colBase * 256);

    float4 sreg[4];
#pragma unroll
    for (int q = 0; q < 4; ++q) sreg[q] = src[q*256 + tid];
    {
        float4* bw = reinterpret_cast<float4*>(&B_lds[0][0]);
#pragma unroll
        for (int q = 0; q < 4; ++q) bw[q*256 + tid] = sreg[q];
    }

    for (int ci = 0; ci < NCHUNK; ++ci) {
        __syncthreads();
        if (ci + 1 < NCHUNK) {
#pragma unroll
            for (int q = 0; q < 4; ++q)
                sreg[q] = src[(size_t)(ci+1)*1024 + q*256 + tid];
        }
        const f16* bufc = &B_lds[ci & 1][0];
        const int c0 = colBase + ci * CHUNK_COLS;

#pragma unroll
        for (int ct = 0; ct < 2; ++ct) {
            const float nh = nhen[c0 + 16*ct + l15];
            const f32x4 nh4 = {nh, nh, nh, nh};
            f32x4 acc[4];
            {
                f16x8 B = *reinterpret_cast<const f16x8*>(bufc + (ct*8)*512 + lane*8);
#pragma unroll
                for (int rt = 0; rt < 4; ++rt)
                    acc[rt] = __builtin_amdgcn_mfma_f32_16x16x32_f16(A[rt][0], B, nh4, 0, 0, 0);
            }
#pragma unroll
            for (int t = 1; t < 8; ++t) {
                f16x8 B = *reinterpret_cast<const f16x8*>(bufc + (ct*8 + t)*512 + lane*8);
#pragma unroll
                for (int rt = 0; rt < 4; ++rt)
                    acc[rt] = __builtin_amdgcn_mfma_f32_16x16x32_f16(A[rt][t], B, acc[rt], 0, 0, 0);
            }
            // top-2 tracking, 4 VALU/elem: med3 + cmp + 2 sel.
            // sec' = median(v, best_old, sec_old) (invariant best >= sec).
#pragma unroll
            for (int rt = 0; rt < 4; ++rt) {
#pragma unroll
                for (int r = 0; r < 4; ++r) {
                    const float v = acc[rt][r];
                    const int sl = rt*4 + r;
                    sec[sl] = __builtin_amdgcn_fmed3f(v, best[sl], sec[sl]);
                    const bool gt = v > best[sl];
                    best[sl] = gt ? v : best[sl];
                    bbase[sl] = gt ? (c0 + 16*ct) : bbase[sl];
                }
            }
        }

        if (ci + 1 < NCHUNK) {
            float4* bw = reinterpret_cast<float4*>(&B_lds[(ci+1) & 1][0]);
#pragma unroll
            for (int q = 0; q < 4; ++q) bw[q*256 + tid] = sreg[q];
        }
    }

#pragma unroll
    for (int s = 0; s < 16; ++s) {
        float b = best[s], sc = sec[s];
        int k = bbase[s] + l15;
#pragma unroll
        for (int off = 8; off >= 1; off >>= 1) {
            float ob = __shfl_xor(b, off, 16);
            float os = __shfl_xor(sc, off, 16);
            int   ok = __shfl_xor(k, off, 16);
            float sm = fmaxf(fmaxf(sc, os), fminf(b, ob));
            bool take = (ob > b) || (ob == b && ok < k);
            b = take ? ob : b;
            k = take ? ok : k;
            sc = sm;
        }
        if (l15 == 0) {
            const int row = rowW + 16*(s >> 2) + 4*l4 + (s & 3);
            p_best[ks * N_ROWS + row] = b;
            p_sec [ks * N_ROWS + row] = sc;
            p_idx [ks * N_ROWS + row] = k;
        }
    }
}

// ---------------------------------------------------------------------------
__global__ void zero_counts_kernel(int* count, int* count3) { *count = 0; *count3 = 0; }

// merge K-splits; flag rows with gap < EPS1 into compacted tier-2 list
__global__ void merge_kernel(const float* __restrict__ p_best,
                             const float* __restrict__ p_sec,
                             const int*   __restrict__ p_idx,
                             int* __restrict__ idxf,
                             int* __restrict__ list, int* __restrict__ count) {
    const int n = blockIdx.x * 256 + threadIdx.x;
    float b = p_best[n], sc = p_sec[n];
    int k = p_idx[n];
#pragma unroll
    for (int s = 1; s < KSPLIT; ++s) {
        float ob = p_best[s * N_ROWS + n];
        float os = p_sec [s * N_ROWS + n];
        int   ok = p_idx [s * N_ROWS + n];
        float sm = fmaxf(fmaxf(sc, os), fminf(b, ob));
        bool take = ob > b;            // equal -> keep earlier split (smaller k)
        b = take ? ob : b; k = take ? ok : k; sc = sm;
    }
    idxf[n] = k;
    if (2.0f * (b - sc) < EPS1) {
        int pos = atomicAdd(count, 1);
        if (pos < T2CAP) list[pos] = n;
    }
}

// ---------------------------------------------------------------------------
// tier-2: fp32 rescan of flagged rows. Block = (group of 64 rows) x (512-col
// split). Tracks top-2 max of u = dot + nhen.
// ---------------------------------------------------------------------------
__launch_bounds__(256, 2)
__global__ void tier2_kernel(const float* __restrict__ X,
                             const float* __restrict__ E,
                             const float* __restrict__ nhen,
                             const int* __restrict__ list,
                             const int* __restrict__ count,
                             float* __restrict__ t2b, float* __restrict__ t2s,
                             int* __restrict__ t2i) {
    const int g  = blockIdx.x >> 4;
    const int sp = blockIdx.x & 15;
    const int cnt = min(*count, T2CAP);
    if (g * 64 >= cnt) return;

    __shared__ float xT[D_DIM][64];
    __shared__ float es[64][64];
    const int tid = threadIdx.x;
    const int tx = tid & 15, ty = tid >> 4;

    {
        const int r = tid >> 2;
        const int slot = min(g * 64 + r, cnt - 1);
        const int row = list[slot];
        const int d0 = (tid & 3) * 64;
        const float* xp = X + (size_t)row * D_DIM + d0;
#pragma unroll
        for (int i = 0; i < 64; i += 4) {
            float4 v = *reinterpret_cast<const float4*>(xp + i);
            xT[d0+i+0][r] = v.x; xT[d0+i+1][r] = v.y;
            xT[d0+i+2][r] = v.z; xT[d0+i+3][r] = v.w;
        }
    }

    float best[4], sec[4]; int bidx[4];
#pragma unroll
    for (int i = 0; i < 4; ++i) { best[i] = -INFINITY; sec[i] = -INFINITY; bidx[i] = 0; }

    const int colBase = sp * 512;
    for (int kc = 0; kc < 512; kc += 64) {
        float acc[4][4];
#pragma unroll
        for (int i = 0; i < 4; ++i)
#pragma unroll
            for (int j = 0; j < 4; ++j) acc[i][j] = 0.0f;

        for (int dc = 0; dc < D_DIM; dc += 64) {
            __syncthreads();
#pragma unroll
            for (int dd = 0; dd < 64; dd += 16) {
                int d = dd + (tid >> 4);
                float4 v = *reinterpret_cast<const float4*>(
                    &E[(size_t)(dc + d) * K_DIM + colBase + kc + (tid & 15) * 4]);
                *reinterpret_cast<float4*>(&es[d][(tid & 15) * 4]) = v;
            }
            __syncthreads();
#pragma unroll 8
            for (int d = 0; d < 64; ++d) {
                float4 xv = *reinterpret_cast<const float4*>(&xT[dc + d][ty * 4]);
                float4 ev = *reinterpret_cast<const float4*>(&es[d][tx * 4]);
                float xr[4] = {xv.x, xv.y, xv.z, xv.w};
                float ec[4] = {ev.x, ev.y, ev.z, ev.w};
#pragma unroll
                for (int i = 0; i < 4; ++i)
#pragma unroll
                    for (int j = 0; j < 4; ++j)
                        acc[i][j] = fmaf(xr[i], ec[j], acc[i][j]);
            }
        }
        float4 nhv = *reinterpret_cast<const float4*>(&nhen[colBase + kc + tx * 4]);
        float nh[4] = {nhv.x, nhv.y, nhv.z, nhv.w};
#pragma unroll
        for (int j = 0; j < 4; ++j) {
            const int k = colBase + kc + tx * 4 + j;
#pragma unroll
            for (int i = 0; i < 4; ++i) {
                float u = nh[j] + acc[i][j];
                bool gt = u > best[i];
                sec[i]  = fmaxf(sec[i], fminf(u, best[i]));
                best[i] = gt ? u : best[i];
                bidx[i] = gt ? k : bidx[i];
            }
        }
    }

#pragma unroll
    for (int off = 8; off >= 1; off >>= 1) {
#pragma unroll
        for (int i = 0; i < 4; ++i) {
            float ob = __shfl_xor(best[i], off, 16);
            float os = __shfl_xor(sec[i], off, 16);
            int   ok = __shfl_xor(bidx[i], off, 16);
            float sm = fmaxf(fmaxf(sec[i], os), fminf(best[i], ob));
            bool take = (ob > best[i]) || (ob == best[i] && ok < bidx[i]);
            best[i] = take ? ob : best[i];
            bidx[i] = take ? ok : bidx[i];
            sec[i] = sm;
        }
    }
    if (tx == 0) {
#pragma unroll
        for (int i = 0; i < 4; ++i) {
            const int slot = g * 64 + ty * 4 + i;
            if (slot < cnt) {
                t2b[sp * T2CAP + slot] = best[i];
                t2s[sp * T2CAP + slot] = sec[i];
                t2i[sp * T2CAP + slot] = bidx[i];
            }
        }
    }
}

// merge tier-2 splits; flag knife-edge rows into compacted tier-3 list
__global__ void merge2_kernel(const float* __restrict__ t2b,
                              const float* __restrict__ t2s,
                              const int*   __restrict__ t2i,
                              const int* __restrict__ list,
                              const int* __restrict__ count,
                              int* __restrict__ idxf,
                              int* __restrict__ list3, int* __restrict__ count3) {
    const int slot = blockIdx.x * 256 + threadIdx.x;
    const int cnt = min(*count, T2CAP);
    if (slot >= cnt) return;
    float b = t2b[slot], sc = t2s[slot];
    int k = t2i[slot];
#pragma unroll
    for (int sp = 1; sp < 16; ++sp) {
        float ob = t2b[sp * T2CAP + slot];
        float os = t2s[sp * T2CAP + slot];
        int   ok = t2i[sp * T2CAP + slot];
        float sm = fmaxf(fmaxf(sc, os), fminf(b, ob));
        bool take = ob > b;
        b = take ? ob : b; k = take ? ok : k; sc = sm;
    }
    const int n = list[slot];
    idxf[n] = k;
    if (2.0f * (b - sc) < EPS2) {
        int pos = atomicAdd(count3, 1);
        if (pos < T3CAP) list3[pos] = n;
    }
}

// ---------------------------------------------------------------------------
// tier-3: fp64 exact rescan, K split 16 ways across blocks.
// ---------------------------------------------------------------------------
__launch_bounds__(256)
__global__ void tier3_kernel(const float* __restrict__ X,
                             const float* __restrict__ E,
                             const int* __restrict__ list3,
                             const int* __restrict__ count3,
                             double* __restrict__ t3b, int* __restrict__ t3i) {
    const int slot = blockIdx.x >> 4;
    const int sp   = blockIdx.x & 15;
    const int cnt = min(*count3, T3CAP);
    if (slot >= cnt) return;
    const int n = list3[slot];

    __shared__ float xs[D_DIM];
    const int tid = threadIdx.x;
    xs[tid] = X[(size_t)n * D_DIM + tid];
    __syncthreads();

    const int colBase = sp * 512;
    double best = DBL_MAX;
    int bi = 0x7fffffff;
#pragma unroll
    for (int kk = 0; kk < 512; kk += 256) {
        const int k = colBase + kk + tid;
        double s0 = 0.0, s1 = 0.0, s2 = 0.0, s3 = 0.0;
#pragma unroll 4
        for (int d = 0; d < D_DIM; d += 4) {
            double f0 = (double)xs[d+0] - (double)E[(size_t)(d+0) * K_DIM + k];
            double f1 = (double)xs[d+1] - (double)E[(size_t)(d+1) * K_DIM + k];
            double f2 = (double)xs[d+2] - (double)E[(size_t)(d+2) * K_DIM + k];
            double f3 = (double)xs[d+3] - (double)E[(size_t)(d+3) * K_DIM + k];
            s0 = fma(f0, f0, s0); s1 = fma(f1, f1, s1);
            s2 = fma(f2, f2, s2); s3 = fma(f3, f3, s3);
        }
        double s = (s0 + s1) + (s2 + s3);
        if (s < best) { best = s; bi = k; }
    }

    __shared__ double bv[256];
    __shared__ int bix[256];
    bv[tid] = best; bix[tid] = bi;
    __syncthreads();
    if (tid == 0) {
        double b = bv[0]; int ix = bix[0];
        for (int t = 1; t < 256; ++t)
            if (bv[t] < b || (bv[t] == b && bix[t] < ix)) { b = bv[t]; ix = bix[t]; }
        t3b[sp * T3CAP + slot] = b;
        t3i[sp * T3CAP + slot] = ix;
    }
}

__global__ void merge3_kernel(const double* __restrict__ t3b,
                              const int* __restrict__ t3i,
                              const int* __restrict__ list3,
                              const int* __restrict__ count3,
                              int* __restrict__ idxf) {
    const int slot = blockIdx.x * 256 + threadIdx.x;
    const int cnt = min(*count3, T3CAP);
    if (slot >= cnt) return;
    double b = t3b[slot];
    int k = t3i[slot];
#pragma unroll
    for (int sp = 1; sp < NSPLIT3; ++sp) {
        double ob = t3b[sp * T3CAP + slot];
        int   ok = t3i[sp * T3CAP + slot];
        if (ob < b || (ob == b && ok < k)) { b = ob; k = ok; }
    }
    idxf[list3[slot]] = k;
}

// ---------------------------------------------------------------------------
// gather from transposed table: out[n][:] = ET[idx[n]][:]  (coalesced)
// ---------------------------------------------------------------------------
__global__ void gather2_kernel(const float* __restrict__ ET,
                               const int* __restrict__ idx,
                               float* __restrict__ out) {
    const int n  = blockIdx.x * 4 + (threadIdx.x >> 6);
    const int d4 = (threadIdx.x & 63) * 4;
    const int k  = idx[n];
    *reinterpret_cast<float4*>(&out[(size_t)n * D_DIM + d4]) =
        *reinterpret_cast<const float4*>(&ET[(size_t)k * D_DIM + d4]);
}

// strided fallback gather (no ET workspace)
__global__ void gather_kernel(const float* __restrict__ E,
                              const int* __restrict__ idx,
                              float* __restrict__ out) {
    const int n = blockIdx.x;
    const int d = threadIdx.x;
    const int k = idx[n];
    out[(size_t)n * D_DIM + d] = E[(size_t)d * K_DIM + k];
}

// ======================= fallback path (proven round-2) =====================
__global__ void fb_enorm_kernel(const float* __restrict__ E, float* __restrict__ enorm) {
    int k = blockIdx.x * 256 + threadIdx.x;
    float s = 0.0f;
#pragma unroll 8
    for (int d = 0; d < D_DIM; ++d) { float v = E[(size_t)d * K_DIM + k]; s = fmaf(v, v, s); }
    enorm[k] = s;
}

__launch_bounds__(256, 2)
__global__ void fb_dist_kernel(const float* __restrict__ X, const float* __restrict__ E,
                               const float* __restrict__ enorm,
                               int* __restrict__ idx_out, float* __restrict__ gap_out) {
    __shared__ float xT[D_DIM][64];
    __shared__ float es[64][64];
    const int tid = threadIdx.x;
    const int tx = tid & 15, ty = tid >> 4;
    const int rowBase = blockIdx.x * 64;
    {
        const int r = tid >> 2;
        const int d0 = (tid & 3) * 64;
        const float* xp = X + (size_t)(rowBase + r) * D_DIM + d0;
#pragma unroll
        for (int i = 0; i < 64; i += 4) {
            float4 v = *reinterpret_cast<const float4*>(xp + i);
            xT[d0+i+0][r]=v.x; xT[d0+i+1][r]=v.y; xT[d0+i+2][r]=v.z; xT[d0+i+3][r]=v.w;
        }
    }
    float bestVal[4], secVal[4]; int bestIdx[4];
#pragma unroll
    for (int i = 0; i < 4; ++i) { bestVal[i]=INFINITY; secVal[i]=INFINITY; bestIdx[i]=0; }
    for (int kc = 0; kc < K_DIM; kc += 64) {
        float acc[4][4];
#pragma unroll
        for (int i=0;i<4;++i)
#pragma unroll
            for (int j=0;j<4;++j) acc[i][j]=0.f;
        for (int dc = 0; dc < D_DIM; dc += 64) {
            __syncthreads();
#pragma unroll
            for (int dd = 0; dd < 64; dd += 16) {
                int d = dd + (tid >> 4);
                float4 v = *reinterpret_cast<const float4*>(
                    &E[(size_t)(dc+d)*K_DIM + kc + (tid&15)*4]);
                *reinterpret_cast<float4*>(&es[d][(tid&15)*4]) = v;
            }
            __syncthreads();
#pragma unroll 8
            for (int d = 0; d < 64; ++d) {
                float4 xv = *reinterpret_cast<const float4*>(&xT[dc+d][ty*4]);
                float4 ev = *reinterpret_cast<const float4*>(&es[d][tx*4]);
                float xr[4]={xv.x,xv.y,xv.z,xv.w}, ec[4]={ev.x,ev.y,ev.z,ev.w};
#pragma unroll
                for (int i=0;i<4;++i)
#pragma unroll
                    for (int j=0;j<4;++j) acc[i][j]=fmaf(xr[i],ec[j],acc[i][j]);
            }
        }
        float4 env = *reinterpret_cast<const float4*>(&enorm[kc + tx*4]);
        float en[4]={env.x,env.y,env.z,env.w};
#pragma unroll
        for (int j=0;j<4;++j) {
            int k = kc + tx*4 + j;
#pragma unroll
            for (int i=0;i<4;++i) {
                float s = fmaf(-2.0f, acc[i][j], en[j]);
                if (s < bestVal[i]) { secVal[i]=bestVal[i]; bestVal[i]=s; bestIdx[i]=k; }
                else if (s < secVal[i]) secVal[i]=s;
            }
        }
    }
#pragma unroll
    for (int off=8; off>=1; off>>=1) {
#pragma unroll
        for (int i=0;i<4;++i) {
            float oB=__shfl_xor(bestVal[i],off,16);
            int oI=__shfl_xor(bestIdx[i],off,16);
            float oS=__shfl_xor(secVal[i],off,16);
            float ms=fminf(fminf(secVal[i],oS),fmaxf(bestVal[i],oB));
            if (oB<bestVal[i] || (oB==bestVal[i] && oI<bestIdx[i])) { bestVal[i]=oB; bestIdx[i]=oI; }
            secVal[i]=ms;
        }
    }
    if (tx==0) {
#pragma unroll
        for (int i=0;i<4;++i) {
            idx_out[rowBase + ty*4 + i] = bestIdx[i];
            gap_out[rowBase + ty*4 + i] = secVal[i]-bestVal[i];
        }
    }
}

__launch_bounds__(256)
__global__ void fb_refine_kernel(const float* __restrict__ X, const float* __restrict__ E,
                                 const float* __restrict__ gap, int* __restrict__ idx) {
    const int n = blockIdx.x;
    if (gap[n] >= 0.0625f) return;
    __shared__ float xs[D_DIM];
    const int tid = threadIdx.x;
    xs[tid] = X[(size_t)n * D_DIM + tid];
    __syncthreads();
    double best = DBL_MAX; int bi = 0x7fffffff;
    for (int k = tid; k < K_DIM; k += 256) {
        double s0=0,s1=0,s2=0,s3=0;
#pragma unroll 4
        for (int d = 0; d < D_DIM; d += 4) {
            double f0=(double)xs[d+0]-(double)E[(size_t)(d+0)*K_DIM+k];
            double f1=(double)xs[d+1]-(double)E[(size_t)(d+1)*K_DIM+k];
            double f2=(double)xs[d+2]-(double)E[(size_t)(d+2)*K_DIM+k];
            double f3=(double)xs[d+3]-(double)E[(size_t)(d+3)*K_DIM+k];
            s0=fma(f0,f0,s0); s1=fma(f1,f1,s1); s2=fma(f2,f2,s2); s3=fma(f3,f3,s3);
        }
        double s=(s0+s1)+(s2+s3);
        if (s<best){best=s;bi=k;}
    }
    __shared__ double bv[256]; __shared__ int bix[256];
    bv[tid]=best; bix[tid]=bi;
    __syncthreads();
    if (tid==0) {
        double b=bv[0]; int ix=bix[0];
        for (int t=1;t<256;++t)
            if (bv[t]<b || (bv[t]==b && bix[t]<ix)) { b=bv[t]; ix=bix[t]; }
        idx[n]=ix;
    }
}

// ---------------------------------------------------------------------------
extern "C" void kernel_launch(void* const* d_in, const int* in_sizes, int n_in,
                              void* d_out, int out_size, void* d_ws, size_t ws_size,
                              hipStream_t stream) {
    const float* X = (const float*)d_in[0];
    const float* E = (const float*)d_in[1];
    float* out = (float*)d_out;
    char* ws = (char*)d_ws;

    // fast-path workspace layout
    const size_t o_nhen  = 0;                                       // K*4
    const size_t o_pb    = 32768;
    const size_t o_ps    = o_pb  + (size_t)KSPLIT * N_ROWS * 4;
    const size_t o_pi    = o_ps  + (size_t)KSPLIT * N_ROWS * 4;
    const size_t o_idx   = o_pi  + (size_t)KSPLIT * N_ROWS * 4;
    const size_t o_list  = o_idx + (size_t)N_ROWS * 4;
    const size_t o_count = o_list + (size_t)T2CAP * 4;              // count @+0, count3 @+4
    const size_t o_t2b   = o_count + 256;
    const size_t o_t2s   = o_t2b + (size_t)16 * T2CAP * 4;
    const size_t o_t2i   = o_t2s + (size_t)16 * T2CAP * 4;
    const size_t o_list3 = o_t2i + (size_t)16 * T2CAP * 4;
    const size_t o_t3b   = o_list3 + (size_t)T3CAP * 4;             // 8B-aligned
    const size_t o_t3i   = o_t3b + (size_t)NSPLIT3 * T3CAP * 8;
    const size_t o_x16   = o_t3i + (size_t)NSPLIT3 * T3CAP * 4;
    const size_t o_epack = o_x16 + (size_t)N_ROWS * D_DIM * 2;
    const size_t NEED_BASE = o_epack + (size_t)D_DIM * K_DIM * 2;
    const size_t o_et    = NEED_BASE;                               // optional ET
    const size_t NEED_FULL = o_et + (size_t)D_DIM * K_DIM * 4;

    if (ws_size >= NEED_BASE) {
        float*  nhen  = (float*) (ws + o_nhen);
        float*  p_b   = (float*) (ws + o_pb);
        float*  p_s   = (float*) (ws + o_ps);
        int*    p_i   = (int*)   (ws + o_pi);
        int*    idxf  = (int*)   (ws + o_idx);
        int*    list  = (int*)   (ws + o_list);
        int*    count = (int*)   (ws + o_count);
        int*    count3= (int*)   (ws + o_count + 4);
        float*  t2b   = (float*) (ws + o_t2b);
        float*  t2s   = (float*) (ws + o_t2s);
        int*    t2i   = (int*)   (ws + o_t2i);
        int*    list3 = (int*)   (ws + o_list3);
        double* t3b   = (double*)(ws + o_t3b);
        int*    t3i   = (int*)   (ws + o_t3i);
        f16*    X16   = (f16*)   (ws + o_x16);
        f16*    Epack = (f16*)   (ws + o_epack);
        float*  ET    = (float*) (ws + o_et);
        const bool haveET = ws_size >= NEED_FULL;

        convx_kernel<<<(N_ROWS * D_DIM / 8) / 256, 256, 0, stream>>>(X, X16);
        if (haveET) {
            transpose_kernel<<<(K_DIM / 64) * (D_DIM / 64), 256, 0, stream>>>(E, ET);
            packe_et_kernel<<<(K_DIM / 16) * 8 * 64 / 256, 256, 0, stream>>>(ET, Epack);
        } else {
            packe_kernel<<<(K_DIM / 16) * 8 * 64 / 256, 256, 0, stream>>>(E, Epack);
        }
        nhen_kernel<<<K_DIM / 256, 256, 0, stream>>>(E, nhen);
        zero_counts_kernel<<<1, 1, 0, stream>>>(count, count3);
        pass1_kernel<<<(N_ROWS / 256) * KSPLIT, 256, 0, stream>>>(
            X16, Epack, nhen, p_b, p_s, p_i);
        merge_kernel<<<N_ROWS / 256, 256, 0, stream>>>(
            p_b, p_s, p_i, idxf, list, count);
        tier2_kernel<<<(T2CAP / 64) * 16, 256, 0, stream>>>(
            X, E, nhen, list, count, t2b, t2s, t2i);
        merge2_kernel<<<T2CAP / 256, 256, 0, stream>>>(
            t2b, t2s, t2i, list, count, idxf, list3, count3);
        tier3_kernel<<<T3CAP * NSPLIT3, 256, 0, stream>>>(
            X, E, list3, count3, t3b, t3i);
        merge3_kernel<<<T3CAP / 256, 256, 0, stream>>>(
            t3b, t3i, list3, count3, idxf);
        if (haveET)
            gather2_kernel<<<N_ROWS / 4, 256, 0, stream>>>(ET, idxf, out);
        else
            gather_kernel<<<N_ROWS, 256, 0, stream>>>(E, idxf, out);
    } else {
        float* enorm = (float*)ws;
        int*   idx   = (int*)(ws + 32768);
        float* gap   = (float*)(ws + 32768 + (size_t)N_ROWS * 4);
        fb_enorm_kernel<<<K_DIM / 256, 256, 0, stream>>>(E, enorm);
        fb_dist_kernel<<<N_ROWS / 64, 256, 0, stream>>>(X, E, enorm, idx, gap);
        fb_refine_kernel<<<N_ROWS, 256, 0, stream>>>(X, E, gap, idx);
        gather_kernel<<<N_ROWS, 256, 0, stream>>>(E, idx, out);
    }
}

// Round 9
// 325.176 us; speedup vs baseline: 1.1385x; 1.0077x over previous
//
#include <hip/hip_runtime.h>
#include <math.h>
#include <float.h>

#define N_ROWS 32768
#define D_DIM  256
#define K_DIM  8192

#define EPS1 0.25f   // tier-1 (f16) gap threshold, full-distance scale (28 sigma)
#define EPS2 0.02f   // tier-2 (fp32) gap threshold
#define T2CAP 4096   // tier-2 row capacity
#define T3CAP 512    // tier-3 row capacity
#define NSPLIT3 16   // tier-3 K splits (512 cols each)

typedef _Float16 f16;
typedef _Float16 f16x8 __attribute__((ext_vector_type(8)));
typedef float f32x4 __attribute__((ext_vector_type(4)));

#define KSPLIT 8
#define COLS_PER_SPLIT (K_DIM / KSPLIT)      // 1024
#define CHUNK_COLS 32
#define NCHUNK (COLS_PER_SPLIT / CHUNK_COLS) // 32
#define CHUNK_BYTES (CHUNK_COLS * D_DIM * 2) // 16384

// global_load_lds plumbing (clang builtin needs explicit address spaces)
typedef unsigned int u32;
typedef const u32 __attribute__((address_space(1)))* gas1_u32;
typedef u32 __attribute__((address_space(3)))* las3_u32;
__device__ __forceinline__ void gload_lds16(const void* g, void* l) {
    __builtin_amdgcn_global_load_lds((gas1_u32)g, (las3_u32)l, 16, 0, 0);
}

// ---------------------------------------------------------------------------
// convert X fp32 -> f16, [N][D] row-major. 8 elems/thread.
// ---------------------------------------------------------------------------
__global__ void convx_kernel(const float* __restrict__ X, f16* __restrict__ X16) {
    const size_t i = ((size_t)blockIdx.x * 256 + threadIdx.x) * 8;
    float4 a = *reinterpret_cast<const float4*>(X + i);
    float4 b = *reinterpret_cast<const float4*>(X + i + 4);
    f16x8 o;
    o[0]=(f16)a.x; o[1]=(f16)a.y; o[2]=(f16)a.z; o[3]=(f16)a.w;
    o[4]=(f16)b.x; o[5]=(f16)b.y; o[6]=(f16)b.z; o[7]=(f16)b.w;
    *reinterpret_cast<f16x8*>(X16 + i) = o;
}

// ---------------------------------------------------------------------------
// tiled transpose: ET[k][d] = E[d][k]  (for coalesced gather + packe)
// ---------------------------------------------------------------------------
__global__ void transpose_kernel(const float* __restrict__ E, float* __restrict__ ET) {
    __shared__ float t[64][65];
    const int bk = blockIdx.x & (K_DIM / 64 - 1);   // 128 k-tiles
    const int bd = blockIdx.x >> 7;                 // 4 d-tiles
    const int c  = threadIdx.x & 63;
    const int r0 = (threadIdx.x >> 6) * 16;
    const int d0 = bd * 64, k0 = bk * 64;
#pragma unroll
    for (int i = 0; i < 16; ++i)
        t[r0 + i][c] = E[(size_t)(d0 + r0 + i) * K_DIM + k0 + c];
    __syncthreads();
#pragma unroll
    for (int i = 0; i < 16; ++i)
        ET[(size_t)(k0 + r0 + i) * D_DIM + d0 + c] = t[c][r0 + i];
}

// ---------------------------------------------------------------------------
// pack E -> Epack f16 in B-fragment-linear order, reading from ET (coalesced).
// B-frag (16x16x32): lane l, elem j <- E[32t + (l>>4)*8 + j][16*tile + (l&15)]
// Epack[(tile*8 + t)*512 + l*8 + j]   (one tile = 16 cols = 4096 f16)
// ---------------------------------------------------------------------------
__global__ void packe_et_kernel(const float* __restrict__ ET, f16* __restrict__ Epack) {
    const int gid = blockIdx.x * 256 + threadIdx.x;  // 512*8*64 = 262144
    const int l    = gid & 63;
    const int t    = (gid >> 6) & 7;
    const int tile = gid >> 9;
    const int k  = 16 * tile + (l & 15);
    const int d0 = 32 * t + (l >> 4) * 8;
    float4 a = *reinterpret_cast<const float4*>(&ET[(size_t)k * D_DIM + d0]);
    float4 b = *reinterpret_cast<const float4*>(&ET[(size_t)k * D_DIM + d0 + 4]);
    f16x8 o;
    o[0]=(f16)a.x; o[1]=(f16)a.y; o[2]=(f16)a.z; o[3]=(f16)a.w;
    o[4]=(f16)b.x; o[5]=(f16)b.y; o[6]=(f16)b.z; o[7]=(f16)b.w;
    *reinterpret_cast<f16x8*>(Epack + (size_t)gid * 8) = o;
}

// fallback packe reading E directly (no ET workspace)
__global__ void packe_kernel(const float* __restrict__ E, f16* __restrict__ Epack) {
    const int gid = blockIdx.x * 256 + threadIdx.x;
    const int l    = gid & 63;
    const int t    = (gid >> 6) & 7;
    const int tile = gid >> 9;
    const int k  = 16 * tile + (l & 15);
    const int d0 = 32 * t + (l >> 4) * 8;
    f16x8 o;
#pragma unroll
    for (int j = 0; j < 8; ++j) o[j] = (f16)E[(size_t)(d0 + j) * K_DIM + k];
    *reinterpret_cast<f16x8*>(Epack + (size_t)gid * 8) = o;
}

// ---------------------------------------------------------------------------
// nhen[k] = -0.5 * sum_d E[d][k]^2   (fp32)
// ---------------------------------------------------------------------------
__global__ void nhen_kernel(const float* __restrict__ E, float* __restrict__ nhen) {
    const int k = blockIdx.x * 256 + threadIdx.x;
    float s = 0.0f;
#pragma unroll 8
    for (int d = 0; d < D_DIM; ++d) {
        float v = E[(size_t)d * K_DIM + k];
        s = fmaf(v, v, s);
    }
    nhen[k] = -0.5f * s;
}

// ---------------------------------------------------------------------------
// pass1 v2: f16 MFMA fused GEMM + per-row top-2 argmax of u = x.e - 0.5||e||^2.
// Counted-vmcnt pipeline (T3/T4): 3 rotating LDS buffers filled by
// global_load_lds; raw s_barrier; steady-state wait is vmcnt(4) (own stage(ci)
// done, stage(ci+1) still in flight) -- never a full drain in the main loop.
// nhen staged to LDS so staging loads are the only vmcnt traffic.
// ---------------------------------------------------------------------------
__launch_bounds__(256, 2)
__global__ void pass1_kernel(const f16* __restrict__ X16,
                             const f16* __restrict__ Epack,
                             const float* __restrict__ nhen,
                             float* __restrict__ p_best,
                             float* __restrict__ p_sec,
                             int*   __restrict__ p_idx) {
    __shared__ f16 B_lds[3][CHUNK_BYTES / 2];   // 3 x 16KB rotating
    __shared__ float nh_lds[COLS_PER_SPLIT];    // 4KB

    const int tid = threadIdx.x;
    const int wv = tid >> 6;
    const int lane = tid & 63;
    const int l15 = lane & 15;
    const int l4  = lane >> 4;
    const int rg = blockIdx.x >> 3;
    const int ks = blockIdx.x & 7;
    const int rowW = rg * 256 + wv * 64;
    const int colBase = ks * COLS_PER_SPLIT;

    // A fragments resident in VGPRs (issued first; oldest vmcnt items)
    f16x8 A[4][8];
#pragma unroll
    for (int rt = 0; rt < 4; ++rt)
#pragma unroll
        for (int t = 0; t < 8; ++t)
            A[rt][t] = *reinterpret_cast<const f16x8*>(
                X16 + (size_t)(rowW + 16*rt + l15) * D_DIM + 32*t + l4*8);

    // nhen split -> LDS (256 x float4)
    *reinterpret_cast<float4*>(&nh_lds[tid * 4]) =
        *reinterpret_cast<const float4*>(nhen + colBase + tid * 4);

    float best[16], sec[16];
    int bbase[16];
#pragma unroll
    for (int s = 0; s < 16; ++s) { best[s] = -INFINITY; sec[s] = -INFINITY; bbase[s] = 0; }

    // chunk source: tile = col/16, 8KB/tile -> byte offset colBase*512
    const char* splitSrc = (const char*)Epack + (size_t)colBase * 512;

    // STAGE: 16KB chunk = 16 x 1KB segments; wave wv issues segments wv*4..wv*4+3.
    // LDS dest wave-uniform base + lane*16 (linear), matching gload_lds semantics.
    auto STAGE = [&](int buf, int ci) {
        const char* csrc = splitSrc + (size_t)ci * CHUNK_BYTES;
        char* cdst = (char*)&B_lds[buf][0];
#pragma unroll
        for (int c = 0; c < 4; ++c) {
            const int seg = wv * 4 + c;
            gload_lds16(csrc + seg * 1024 + (lane << 4), cdst + seg * 1024);
        }
    };

    auto COMPUTE = [&](int bi, int ci) {
        const f16* bufc = &B_lds[bi][0];
        const int c0 = colBase + ci * CHUNK_COLS;
#pragma unroll
        for (int ct = 0; ct < 2; ++ct) {
            const float nh = nh_lds[ci * CHUNK_COLS + ct * 16 + l15];
            const f32x4 nh4 = {nh, nh, nh, nh};
            f32x4 acc[4];
            {
                f16x8 B = *reinterpret_cast<const f16x8*>(bufc + (ct*8)*512 + lane*8);
#pragma unroll
                for (int rt = 0; rt < 4; ++rt)
                    acc[rt] = __builtin_amdgcn_mfma_f32_16x16x32_f16(A[rt][0], B, nh4, 0, 0, 0);
            }
#pragma unroll
            for (int t = 1; t < 8; ++t) {
                f16x8 B = *reinterpret_cast<const f16x8*>(bufc + (ct*8 + t)*512 + lane*8);
#pragma unroll
                for (int rt = 0; rt < 4; ++rt)
                    acc[rt] = __builtin_amdgcn_mfma_f32_16x16x32_f16(A[rt][t], B, acc[rt], 0, 0, 0);
            }
            // top-2 tracking: sec' = median(v, best_old, sec_old); best' = max.
#pragma unroll
            for (int rt = 0; rt < 4; ++rt) {
#pragma unroll
                for (int r = 0; r < 4; ++r) {
                    const float v = acc[rt][r];
                    const int sl = rt*4 + r;
                    sec[sl] = __builtin_amdgcn_fmed3f(v, best[sl], sec[sl]);
                    const bool gt = v > best[sl];
                    best[sl] = gt ? v : best[sl];
                    bbase[sl] = gt ? (c0 + 16*ct) : bbase[sl];
                }
            }
        }
    };

    STAGE(0, 0);
    STAGE(1, 1);
    // drain own LDS writes (nh_lds) before the first raw barrier
    asm volatile("s_waitcnt lgkmcnt(0)" ::: "memory");

    int cur = 0;
    for (int ci = 0; ci < NCHUNK - 1; ++ci) {
        // own stage(ci) segments complete (stage(ci+1)'s 4 may remain in flight)
        asm volatile("s_waitcnt vmcnt(4)" ::: "memory");
        __builtin_amdgcn_s_barrier();   // all waves' stage(ci) complete
        if (ci + 2 < NCHUNK) {
            int nb = cur + 2; if (nb >= 3) nb -= 3;
            STAGE(nb, ci + 2);          // overwrites buf last read in compute(ci-1)
        }
        COMPUTE(cur, ci);
        cur = (cur + 1 == 3) ? 0 : cur + 1;
    }
    asm volatile("s_waitcnt vmcnt(0)" ::: "memory");
    __builtin_amdgcn_s_barrier();
    COMPUTE(cur, NCHUNK - 1);

    // top-2 merge across the 16 l15 lanes of each quarter-wave
#pragma unroll
    for (int s = 0; s < 16; ++s) {
        float b = best[s], sc = sec[s];
        int k = bbase[s] + l15;
#pragma unroll
        for (int off = 8; off >= 1; off >>= 1) {
            float ob = __shfl_xor(b, off, 16);
            float os = __shfl_xor(sc, off, 16);
            int   ok = __shfl_xor(k, off, 16);
            float sm = fmaxf(fmaxf(sc, os), fminf(b, ob));
            bool take = (ob > b) || (ob == b && ok < k);
            b = take ? ob : b;
            k = take ? ok : k;
            sc = sm;
        }
        if (l15 == 0) {
            const int row = rowW + 16*(s >> 2) + 4*l4 + (s & 3);
            p_best[ks * N_ROWS + row] = b;
            p_sec [ks * N_ROWS + row] = sc;
            p_idx [ks * N_ROWS + row] = k;
        }
    }
}

// ---------------------------------------------------------------------------
__global__ void zero_counts_kernel(int* count, int* count3) { *count = 0; *count3 = 0; }

// merge K-splits; flag rows with gap < EPS1 into compacted tier-2 list
__global__ void merge_kernel(const float* __restrict__ p_best,
                             const float* __restrict__ p_sec,
                             const int*   __restrict__ p_idx,
                             int* __restrict__ idxf,
                             int* __restrict__ list, int* __restrict__ count) {
    const int n = blockIdx.x * 256 + threadIdx.x;
    float b = p_best[n], sc = p_sec[n];
    int k = p_idx[n];
#pragma unroll
    for (int s = 1; s < KSPLIT; ++s) {
        float ob = p_best[s * N_ROWS + n];
        float os = p_sec [s * N_ROWS + n];
        int   ok = p_idx [s * N_ROWS + n];
        float sm = fmaxf(fmaxf(sc, os), fminf(b, ob));
        bool take = ob > b;            // equal -> keep earlier split (smaller k)
        b = take ? ob : b; k = take ? ok : k; sc = sm;
    }
    idxf[n] = k;
    if (2.0f * (b - sc) < EPS1) {
        int pos = atomicAdd(count, 1);
        if (pos < T2CAP) list[pos] = n;
    }
}

// ---------------------------------------------------------------------------
// tier-2: fp32 rescan of flagged rows. Block = (group of 64 rows) x (512-col
// split). Tracks top-2 max of u = dot + nhen.
// ---------------------------------------------------------------------------
__launch_bounds__(256, 2)
__global__ void tier2_kernel(const float* __restrict__ X,
                             const float* __restrict__ E,
                             const float* __restrict__ nhen,
                             const int* __restrict__ list,
                             const int* __restrict__ count,
                             float* __restrict__ t2b, float* __restrict__ t2s,
                             int* __restrict__ t2i) {
    const int g  = blockIdx.x >> 4;
    const int sp = blockIdx.x & 15;
    const int cnt = min(*count, T2CAP);
    if (g * 64 >= cnt) return;

    __shared__ float xT[D_DIM][64];
    __shared__ float es[64][64];
    const int tid = threadIdx.x;
    const int tx = tid & 15, ty = tid >> 4;

    {
        const int r = tid >> 2;
        const int slot = min(g * 64 + r, cnt - 1);
        const int row = list[slot];
        const int d0 = (tid & 3) * 64;
        const float* xp = X + (size_t)row * D_DIM + d0;
#pragma unroll
        for (int i = 0; i < 64; i += 4) {
            float4 v = *reinterpret_cast<const float4*>(xp + i);
            xT[d0+i+0][r] = v.x; xT[d0+i+1][r] = v.y;
            xT[d0+i+2][r] = v.z; xT[d0+i+3][r] = v.w;
        }
    }

    float best[4], sec[4]; int bidx[4];
#pragma unroll
    for (int i = 0; i < 4; ++i) { best[i] = -INFINITY; sec[i] = -INFINITY; bidx[i] = 0; }

    const int colBase = sp * 512;
    for (int kc = 0; kc < 512; kc += 64) {
        float acc[4][4];
#pragma unroll
        for (int i = 0; i < 4; ++i)
#pragma unroll
            for (int j = 0; j < 4; ++j) acc[i][j] = 0.0f;

        for (int dc = 0; dc < D_DIM; dc += 64) {
            __syncthreads();
#pragma unroll
            for (int dd = 0; dd < 64; dd += 16) {
                int d = dd + (tid >> 4);
                float4 v = *reinterpret_cast<const float4*>(
                    &E[(size_t)(dc + d) * K_DIM + colBase + kc + (tid & 15) * 4]);
                *reinterpret_cast<float4*>(&es[d][(tid & 15) * 4]) = v;
            }
            __syncthreads();
#pragma unroll 8
            for (int d = 0; d < 64; ++d) {
                float4 xv = *reinterpret_cast<const float4*>(&xT[dc + d][ty * 4]);
                float4 ev = *reinterpret_cast<const float4*>(&es[d][tx * 4]);
                float xr[4] = {xv.x, xv.y, xv.z, xv.w};
                float ec[4] = {ev.x, ev.y, ev.z, ev.w};
#pragma unroll
                for (int i = 0; i < 4; ++i)
#pragma unroll
                    for (int j = 0; j < 4; ++j)
                        acc[i][j] = fmaf(xr[i], ec[j], acc[i][j]);
            }
        }
        float4 nhv = *reinterpret_cast<const float4*>(&nhen[colBase + kc + tx * 4]);
        float nh[4] = {nhv.x, nhv.y, nhv.z, nhv.w};
#pragma unroll
        for (int j = 0; j < 4; ++j) {
            const int k = colBase + kc + tx * 4 + j;
#pragma unroll
            for (int i = 0; i < 4; ++i) {
                float u = nh[j] + acc[i][j];
                bool gt = u > best[i];
                sec[i]  = fmaxf(sec[i], fminf(u, best[i]));
                best[i] = gt ? u : best[i];
                bidx[i] = gt ? k : bidx[i];
            }
        }
    }

#pragma unroll
    for (int off = 8; off >= 1; off >>= 1) {
#pragma unroll
        for (int i = 0; i < 4; ++i) {
            float ob = __shfl_xor(best[i], off, 16);
            float os = __shfl_xor(sec[i], off, 16);
            int   ok = __shfl_xor(bidx[i], off, 16);
            float sm = fmaxf(fmaxf(sec[i], os), fminf(best[i], ob));
            bool take = (ob > best[i]) || (ob == best[i] && ok < bidx[i]);
            best[i] = take ? ob : best[i];
            bidx[i] = take ? ok : bidx[i];
            sec[i] = sm;
        }
    }
    if (tx == 0) {
#pragma unroll
        for (int i = 0; i < 4; ++i) {
            const int slot = g * 64 + ty * 4 + i;
            if (slot < cnt) {
                t2b[sp * T2CAP + slot] = best[i];
                t2s[sp * T2CAP + slot] = sec[i];
                t2i[sp * T2CAP + slot] = bidx[i];
            }
        }
    }
}

// merge tier-2 splits; flag knife-edge rows into compacted tier-3 list
__global__ void merge2_kernel(const float* __restrict__ t2b,
                              const float* __restrict__ t2s,
                              const int*   __restrict__ t2i,
                              const int* __restrict__ list,
                              const int* __restrict__ count,
                              int* __restrict__ idxf,
                              int* __restrict__ list3, int* __restrict__ count3) {
    const int slot = blockIdx.x * 256 + threadIdx.x;
    const int cnt = min(*count, T2CAP);
    if (slot >= cnt) return;
    float b = t2b[slot], sc = t2s[slot];
    int k = t2i[slot];
#pragma unroll
    for (int sp = 1; sp < 16; ++sp) {
        float ob = t2b[sp * T2CAP + slot];
        float os = t2s[sp * T2CAP + slot];
        int   ok = t2i[sp * T2CAP + slot];
        float sm = fmaxf(fmaxf(sc, os), fminf(b, ob));
        bool take = ob > b;
        b = take ? ob : b; k = take ? ok : k; sc = sm;
    }
    const int n = list[slot];
    idxf[n] = k;
    if (2.0f * (b - sc) < EPS2) {
        int pos = atomicAdd(count3, 1);
        if (pos < T3CAP) list3[pos] = n;
    }
}

// ---------------------------------------------------------------------------
// tier-3: fp64 exact rescan, K split 16 ways across blocks.
// ---------------------------------------------------------------------------
__launch_bounds__(256)
__global__ void tier3_kernel(const float* __restrict__ X,
                             const float* __restrict__ E,
                             const int* __restrict__ list3,
                             const int* __restrict__ count3,
                             double* __restrict__ t3b, int* __restrict__ t3i) {
    const int slot = blockIdx.x >> 4;
    const int sp   = blockIdx.x & 15;
    const int cnt = min(*count3, T3CAP);
    if (slot >= cnt) return;
    const int n = list3[slot];

    __shared__ float xs[D_DIM];
    const int tid = threadIdx.x;
    xs[tid] = X[(size_t)n * D_DIM + tid];
    __syncthreads();

    const int colBase = sp * 512;
    double best = DBL_MAX;
    int bi = 0x7fffffff;
#pragma unroll
    for (int kk = 0; kk < 512; kk += 256) {
        const int k = colBase + kk + tid;
        double s0 = 0.0, s1 = 0.0, s2 = 0.0, s3 = 0.0;
#pragma unroll 4
        for (int d = 0; d < D_DIM; d += 4) {
            double f0 = (double)xs[d+0] - (double)E[(size_t)(d+0) * K_DIM + k];
            double f1 = (double)xs[d+1] - (double)E[(size_t)(d+1) * K_DIM + k];
            double f2 = (double)xs[d+2] - (double)E[(size_t)(d+2) * K_DIM + k];
            double f3 = (double)xs[d+3] - (double)E[(size_t)(d+3) * K_DIM + k];
            s0 = fma(f0, f0, s0); s1 = fma(f1, f1, s1);
            s2 = fma(f2, f2, s2); s3 = fma(f3, f3, s3);
        }
        double s = (s0 + s1) + (s2 + s3);
        if (s < best) { best = s; bi = k; }
    }

    __shared__ double bv[256];
    __shared__ int bix[256];
    bv[tid] = best; bix[tid] = bi;
    __syncthreads();
    if (tid == 0) {
        double b = bv[0]; int ix = bix[0];
        for (int t = 1; t < 256; ++t)
            if (bv[t] < b || (bv[t] == b && bix[t] < ix)) { b = bv[t]; ix = bix[t]; }
        t3b[sp * T3CAP + slot] = b;
        t3i[sp * T3CAP + slot] = ix;
    }
}

__global__ void merge3_kernel(const double* __restrict__ t3b,
                              const int* __restrict__ t3i,
                              const int* __restrict__ list3,
                              const int* __restrict__ count3,
                              int* __restrict__ idxf) {
    const int slot = blockIdx.x * 256 + threadIdx.x;
    const int cnt = min(*count3, T3CAP);
    if (slot >= cnt) return;
    double b = t3b[slot];
    int k = t3i[slot];
#pragma unroll
    for (int sp = 1; sp < NSPLIT3; ++sp) {
        double ob = t3b[sp * T3CAP + slot];
        int   ok = t3i[sp * T3CAP + slot];
        if (ob < b || (ob == b && ok < k)) { b = ob; k = ok; }
    }
    idxf[list3[slot]] = k;
}

// ---------------------------------------------------------------------------
// gather from transposed table: out[n][:] = ET[idx[n]][:]  (coalesced)
// ---------------------------------------------------------------------------
__global__ void gather2_kernel(const float* __restrict__ ET,
                               const int* __restrict__ idx,
                               float* __restrict__ out) {
    const int n  = blockIdx.x * 4 + (threadIdx.x >> 6);
    const int d4 = (threadIdx.x & 63) * 4;
    const int k  = idx[n];
    *reinterpret_cast<float4*>(&out[(size_t)n * D_DIM + d4]) =
        *reinterpret_cast<const float4*>(&ET[(size_t)k * D_DIM + d4]);
}

// strided fallback gather (no ET workspace)
__global__ void gather_kernel(const float* __restrict__ E,
                              const int* __restrict__ idx,
                              float* __restrict__ out) {
    const int n = blockIdx.x;
    const int d = threadIdx.x;
    const int k = idx[n];
    out[(size_t)n * D_DIM + d] = E[(size_t)d * K_DIM + k];
}

// ======================= fallback path (proven round-2) =====================
__global__ void fb_enorm_kernel(const float* __restrict__ E, float* __restrict__ enorm) {
    int k = blockIdx.x * 256 + threadIdx.x;
    float s = 0.0f;
#pragma unroll 8
    for (int d = 0; d < D_DIM; ++d) { float v = E[(size_t)d * K_DIM + k]; s = fmaf(v, v, s); }
    enorm[k] = s;
}

__launch_bounds__(256, 2)
__global__ void fb_dist_kernel(const float* __restrict__ X, const float* __restrict__ E,
                               const float* __restrict__ enorm,
                               int* __restrict__ idx_out, float* __restrict__ gap_out) {
    __shared__ float xT[D_DIM][64];
    __shared__ float es[64][64];
    const int tid = threadIdx.x;
    const int tx = tid & 15, ty = tid >> 4;
    const int rowBase = blockIdx.x * 64;
    {
        const int r = tid >> 2;
        const int d0 = (tid & 3) * 64;
        const float* xp = X + (size_t)(rowBase + r) * D_DIM + d0;
#pragma unroll
        for (int i = 0; i < 64; i += 4) {
            float4 v = *reinterpret_cast<const float4*>(xp + i);
            xT[d0+i+0][r]=v.x; xT[d0+i+1][r]=v.y; xT[d0+i+2][r]=v.z; xT[d0+i+3][r]=v.w;
        }
    }
    float bestVal[4], secVal[4]; int bestIdx[4];
#pragma unroll
    for (int i = 0; i < 4; ++i) { bestVal[i]=INFINITY; secVal[i]=INFINITY; bestIdx[i]=0; }
    for (int kc = 0; kc < K_DIM; kc += 64) {
        float acc[4][4];
#pragma unroll
        for (int i=0;i<4;++i)
#pragma unroll
            for (int j=0;j<4;++j) acc[i][j]=0.f;
        for (int dc = 0; dc < D_DIM; dc += 64) {
            __syncthreads();
#pragma unroll
            for (int dd = 0; dd < 64; dd += 16) {
                int d = dd + (tid >> 4);
                float4 v = *reinterpret_cast<const float4*>(
                    &E[(size_t)(dc+d)*K_DIM + kc + (tid&15)*4]);
                *reinterpret_cast<float4*>(&es[d][(tid&15)*4]) = v;
            }
            __syncthreads();
#pragma unroll 8
            for (int d = 0; d < 64; ++d) {
                float4 xv = *reinterpret_cast<const float4*>(&xT[dc+d][ty*4]);
                float4 ev = *reinterpret_cast<const float4*>(&es[d][tx*4]);
                float xr[4]={xv.x,xv.y,xv.z,xv.w}, ec[4]={ev.x,ev.y,ev.z,ev.w};
#pragma unroll
                for (int i=0;i<4;++i)
#pragma unroll
                    for (int j=0;j<4;++j) acc[i][j]=fmaf(xr[i],ec[j],acc[i][j]);
            }
        }
        float4 env = *reinterpret_cast<const float4*>(&enorm[kc + tx*4]);
        float en[4]={env.x,env.y,env.z,env.w};
#pragma unroll
        for (int j=0;j<4;++j) {
            int k = kc + tx*4 + j;
#pragma unroll
            for (int i=0;i<4;++i) {
                float s = fmaf(-2.0f, acc[i][j], en[j]);
                if (s < bestVal[i]) { secVal[i]=bestVal[i]; bestVal[i]=s; bestIdx[i]=k; }
                else if (s < secVal[i]) secVal[i]=s;
            }
        }
    }
#pragma unroll
    for (int off=8; off>=1; off>>=1) {
#pragma unroll
        for (int i=0;i<4;++i) {
            float oB=__shfl_xor(bestVal[i],off,16);
            int oI=__shfl_xor(bestIdx[i],off,16);
            float oS=__shfl_xor(secVal[i],off,16);
            float ms=fminf(fminf(secVal[i],oS),fmaxf(bestVal[i],oB));
            if (oB<bestVal[i] || (oB==bestVal[i] && oI<bestIdx[i])) { bestVal[i]=oB; bestIdx[i]=oI; }
            secVal[i]=ms;
        }
    }
    if (tx==0) {
#pragma unroll
        for (int i=0;i<4;++i) {
            idx_out[rowBase + ty*4 + i] = bestIdx[i];
            gap_out[rowBase + ty*4 + i] = secVal[i]-bestVal[i];
        }
    }
}

__launch_bounds__(256)
__global__ void fb_refine_kernel(const float* __restrict__ X, const float* __restrict__ E,
                                 const float* __restrict__ gap, int* __restrict__ idx) {
    const int n = blockIdx.x;
    if (gap[n] >= 0.0625f) return;
    __shared__ float xs[D_DIM];
    const int tid = threadIdx.x;
    xs[tid] = X[(size_t)n * D_DIM + tid];
    __syncthreads();
    double best = DBL_MAX; int bi = 0x7fffffff;
    for (int k = tid; k < K_DIM; k += 256) {
        double s0=0,s1=0,s2=0,s3=0;
#pragma unroll 4
        for (int d = 0; d < D_DIM; d += 4) {
            double f0=(double)xs[d+0]-(double)E[(size_t)(d+0)*K_DIM+k];
            double f1=(double)xs[d+1]-(double)E[(size_t)(d+1)*K_DIM+k];
            double f2=(double)xs[d+2]-(double)E[(size_t)(d+2)*K_DIM+k];
            double f3=(double)xs[d+3]-(double)E[(size_t)(d+3)*K_DIM+k];
            s0=fma(f0,f0,s0); s1=fma(f1,f1,s1); s2=fma(f2,f2,s2); s3=fma(f3,f3,s3);
        }
        double s=(s0+s1)+(s2+s3);
        if (s<best){best=s;bi=k;}
    }
    __shared__ double bv[256]; __shared__ int bix[256];
    bv[tid]=best; bix[tid]=bi;
    __syncthreads();
    if (tid==0) {
        double b=bv[0]; int ix=bix[0];
        for (int t=1;t<256;++t)
            if (bv[t]<b || (bv[t]==b && bix[t]<ix)) { b=bv[t]; ix=bix[t]; }
        idx[n]=ix;
    }
}

// ---------------------------------------------------------------------------
extern "C" void kernel_launch(void* const* d_in, const int* in_sizes, int n_in,
                              void* d_out, int out_size, void* d_ws, size_t ws_size,
                              hipStream_t stream) {
    const float* X = (const float*)d_in[0];
    const float* E = (const float*)d_in[1];
    float* out = (float*)d_out;
    char* ws = (char*)d_ws;

    // fast-path workspace layout
    const size_t o_nhen  = 0;                                       // K*4
    const size_t o_pb    = 32768;
    const size_t o_ps    = o_pb  + (size_t)KSPLIT * N_ROWS * 4;
    const size_t o_pi    = o_ps  + (size_t)KSPLIT * N_ROWS * 4;
    const size_t o_idx   = o_pi  + (size_t)KSPLIT * N_ROWS * 4;
    const size_t o_list  = o_idx + (size_t)N_ROWS * 4;
    const size_t o_count = o_list + (size_t)T2CAP * 4;              // count @+0, count3 @+4
    const size_t o_t2b   = o_count + 256;
    const size_t o_t2s   = o_t2b + (size_t)16 * T2CAP * 4;
    const size_t o_t2i   = o_t2s + (size_t)16 * T2CAP * 4;
    const size_t o_list3 = o_t2i + (size_t)16 * T2CAP * 4;
    const size_t o_t3b   = o_list3 + (size_t)T3CAP * 4;             // 8B-aligned
    const size_t o_t3i   = o_t3b + (size_t)NSPLIT3 * T3CAP * 8;
    const size_t o_x16   = o_t3i + (size_t)NSPLIT3 * T3CAP * 4;
    const size_t o_epack = o_x16 + (size_t)N_ROWS * D_DIM * 2;
    const size_t NEED_BASE = o_epack + (size_t)D_DIM * K_DIM * 2;
    const size_t o_et    = NEED_BASE;                               // optional ET
    const size_t NEED_FULL = o_et + (size_t)D_DIM * K_DIM * 4;

    if (ws_size >= NEED_BASE) {
        float*  nhen  = (float*) (ws + o_nhen);
        float*  p_b   = (float*) (ws + o_pb);
        float*  p_s   = (float*) (ws + o_ps);
        int*    p_i   = (int*)   (ws + o_pi);
        int*    idxf  = (int*)   (ws + o_idx);
        int*    list  = (int*)   (ws + o_list);
        int*    count = (int*)   (ws + o_count);
        int*    count3= (int*)   (ws + o_count + 4);
        float*  t2b   = (float*) (ws + o_t2b);
        float*  t2s   = (float*) (ws + o_t2s);
        int*    t2i   = (int*)   (ws + o_t2i);
        int*    list3 = (int*)   (ws + o_list3);
        double* t3b   = (double*)(ws + o_t3b);
        int*    t3i   = (int*)   (ws + o_t3i);
        f16*    X16   = (f16*)   (ws + o_x16);
        f16*    Epack = (f16*)   (ws + o_epack);
        float*  ET    = (float*) (ws + o_et);
        const bool haveET = ws_size >= NEED_FULL;

        convx_kernel<<<(N_ROWS * D_DIM / 8) / 256, 256, 0, stream>>>(X, X16);
        if (haveET) {
            transpose_kernel<<<(K_DIM / 64) * (D_DIM / 64), 256, 0, stream>>>(E, ET);
            packe_et_kernel<<<(K_DIM / 16) * 8 * 64 / 256, 256, 0, stream>>>(ET, Epack);
        } else {
            packe_kernel<<<(K_DIM / 16) * 8 * 64 / 256, 256, 0, stream>>>(E, Epack);
        }
        nhen_kernel<<<K_DIM / 256, 256, 0, stream>>>(E, nhen);
        zero_counts_kernel<<<1, 1, 0, stream>>>(count, count3);
        pass1_kernel<<<(N_ROWS / 256) * KSPLIT, 256, 0, stream>>>(
            X16, Epack, nhen, p_b, p_s, p_i);
        merge_kernel<<<N_ROWS / 256, 256, 0, stream>>>(
            p_b, p_s, p_i, idxf, list, count);
        tier2_kernel<<<(T2CAP / 64) * 16, 256, 0, stream>>>(
            X, E, nhen, list, count, t2b, t2s, t2i);
        merge2_kernel<<<T2CAP / 256, 256, 0, stream>>>(
            t2b, t2s, t2i, list, count, idxf, list3, count3);
        tier3_kernel<<<T3CAP * NSPLIT3, 256, 0, stream>>>(
            X, E, list3, count3, t3b, t3i);
        merge3_kernel<<<T3CAP / 256, 256, 0, stream>>>(
            t3b, t3i, list3, count3, idxf);
        if (haveET)
            gather2_kernel<<<N_ROWS / 4, 256, 0, stream>>>(ET, idxf, out);
        else
            gather_kernel<<<N_ROWS, 256, 0, stream>>>(E, idxf, out);
    } else {
        float* enorm = (float*)ws;
        int*   idx   = (int*)(ws + 32768);
        float* gap   = (float*)(ws + 32768 + (size_t)N_ROWS * 4);
        fb_enorm_kernel<<<K_DIM / 256, 256, 0, stream>>>(E, enorm);
        fb_dist_kernel<<<N_ROWS / 64, 256, 0, stream>>>(X, E, enorm, idx, gap);
        fb_refine_kernel<<<N_ROWS, 256, 0, stream>>>(X, E, gap, idx);
        gather_kernel<<<N_ROWS, 256, 0, stream>>>(E, idx, out);
    }
}

// Round 10
// 324.321 us; speedup vs baseline: 1.1415x; 1.0026x over previous
//
#include <hip/hip_runtime.h>
#include <math.h>
#include <float.h>

#define N_ROWS 32768
#define D_DIM  256
#define K_DIM  8192

#define EPS1 0.25f   // tier-1 (f16) gap threshold, full-distance scale (28 sigma)
#define EPS2 0.02f   // tier-2 (fp32) gap threshold
#define T2CAP 4096   // tier-2 row capacity
#define T3CAP 512    // tier-3 row capacity
#define NSPLIT3 16   // tier-3 K splits (512 cols each)

typedef _Float16 f16;
typedef _Float16 f16x8 __attribute__((ext_vector_type(8)));
typedef float f32x4 __attribute__((ext_vector_type(4)));

#define KSPLIT 8
#define COLS_PER_SPLIT (K_DIM / KSPLIT)      // 1024
#define CHUNK_COLS 32
#define NCHUNK (COLS_PER_SPLIT / CHUNK_COLS) // 32
#define CHUNK_BYTES (CHUNK_COLS * D_DIM * 2) // 16384

// global_load_lds plumbing (clang builtin needs explicit address spaces)
typedef unsigned int u32;
typedef const u32 __attribute__((address_space(1)))* gas1_u32;
typedef u32 __attribute__((address_space(3)))* las3_u32;
__device__ __forceinline__ void gload_lds16(const void* g, void* l) {
    __builtin_amdgcn_global_load_lds((gas1_u32)g, (las3_u32)l, 16, 0, 0);
}

// ---------------------------------------------------------------------------
// convert X fp32 -> f16, [N][D] row-major. 8 elems/thread.
// ---------------------------------------------------------------------------
__global__ void convx_kernel(const float* __restrict__ X, f16* __restrict__ X16) {
    const size_t i = ((size_t)blockIdx.x * 256 + threadIdx.x) * 8;
    float4 a = *reinterpret_cast<const float4*>(X + i);
    float4 b = *reinterpret_cast<const float4*>(X + i + 4);
    f16x8 o;
    o[0]=(f16)a.x; o[1]=(f16)a.y; o[2]=(f16)a.z; o[3]=(f16)a.w;
    o[4]=(f16)b.x; o[5]=(f16)b.y; o[6]=(f16)b.z; o[7]=(f16)b.w;
    *reinterpret_cast<f16x8*>(X16 + i) = o;
}

// ---------------------------------------------------------------------------
// tiled transpose: ET[k][d] = E[d][k]  (for coalesced gather + packe)
// ---------------------------------------------------------------------------
__global__ void transpose_kernel(const float* __restrict__ E, float* __restrict__ ET) {
    __shared__ float t[64][65];
    const int bk = blockIdx.x & (K_DIM / 64 - 1);   // 128 k-tiles
    const int bd = blockIdx.x >> 7;                 // 4 d-tiles
    const int c  = threadIdx.x & 63;
    const int r0 = (threadIdx.x >> 6) * 16;
    const int d0 = bd * 64, k0 = bk * 64;
#pragma unroll
    for (int i = 0; i < 16; ++i)
        t[r0 + i][c] = E[(size_t)(d0 + r0 + i) * K_DIM + k0 + c];
    __syncthreads();
#pragma unroll
    for (int i = 0; i < 16; ++i)
        ET[(size_t)(k0 + r0 + i) * D_DIM + d0 + c] = t[c][r0 + i];
}

// ---------------------------------------------------------------------------
// pack E -> Epack f16 in B-fragment-linear order, reading from ET (coalesced).
// B-frag (16x16x32): lane l, elem j <- E[32t + (l>>4)*8 + j][16*tile + (l&15)]
// Epack[(tile*8 + t)*512 + l*8 + j]   (one tile = 16 cols = 4096 f16)
// ---------------------------------------------------------------------------
__global__ void packe_et_kernel(const float* __restrict__ ET, f16* __restrict__ Epack) {
    const int gid = blockIdx.x * 256 + threadIdx.x;  // 512*8*64 = 262144
    const int l    = gid & 63;
    const int t    = (gid >> 6) & 7;
    const int tile = gid >> 9;
    const int k  = 16 * tile + (l & 15);
    const int d0 = 32 * t + (l >> 4) * 8;
    float4 a = *reinterpret_cast<const float4*>(&ET[(size_t)k * D_DIM + d0]);
    float4 b = *reinterpret_cast<const float4*>(&ET[(size_t)k * D_DIM + d0 + 4]);
    f16x8 o;
    o[0]=(f16)a.x; o[1]=(f16)a.y; o[2]=(f16)a.z; o[3]=(f16)a.w;
    o[4]=(f16)b.x; o[5]=(f16)b.y; o[6]=(f16)b.z; o[7]=(f16)b.w;
    *reinterpret_cast<f16x8*>(Epack + (size_t)gid * 8) = o;
}

// fallback packe reading E directly (no ET workspace)
__global__ void packe_kernel(const float* __restrict__ E, f16* __restrict__ Epack) {
    const int gid = blockIdx.x * 256 + threadIdx.x;
    const int l    = gid & 63;
    const int t    = (gid >> 6) & 7;
    const int tile = gid >> 9;
    const int k  = 16 * tile + (l & 15);
    const int d0 = 32 * t + (l >> 4) * 8;
    f16x8 o;
#pragma unroll
    for (int j = 0; j < 8; ++j) o[j] = (f16)E[(size_t)(d0 + j) * K_DIM + k];
    *reinterpret_cast<f16x8*>(Epack + (size_t)gid * 8) = o;
}

// ---------------------------------------------------------------------------
// nhen[k] = -0.5 * sum_d E[d][k]^2   (fp32)
// ---------------------------------------------------------------------------
__global__ void nhen_kernel(const float* __restrict__ E, float* __restrict__ nhen) {
    const int k = blockIdx.x * 256 + threadIdx.x;
    float s = 0.0f;
#pragma unroll 8
    for (int d = 0; d < D_DIM; ++d) {
        float v = E[(size_t)d * K_DIM + k];
        s = fmaf(v, v, s);
    }
    nhen[k] = -0.5f * s;
}

// ---------------------------------------------------------------------------
// pass1 v3: f16 MFMA fused GEMM + per-row top-2 argmax of u = x.e - 0.5||e||^2.
// Deferred-scoring pipeline (att[2] pattern): while tile i's MFMA chain
// issues, the scoring VALU of tile i-1 is interleaved between its t-steps --
// MFMA pipe and VALU pipe overlap within one wave. Two ping-pong acc sets.
// Staging: 3 rotating LDS buffers, global_load_lds, counted vmcnt (round 9).
// ---------------------------------------------------------------------------
__launch_bounds__(256, 2)
__global__ void pass1_kernel(const f16* __restrict__ X16,
                             const f16* __restrict__ Epack,
                             const float* __restrict__ nhen,
                             float* __restrict__ p_best,
                             float* __restrict__ p_sec,
                             int*   __restrict__ p_idx) {
    __shared__ f16 B_lds[3][CHUNK_BYTES / 2];   // 3 x 16KB rotating
    __shared__ float nh_lds[COLS_PER_SPLIT];    // 4KB

    const int tid = threadIdx.x;
    const int wv = tid >> 6;
    const int lane = tid & 63;
    const int l15 = lane & 15;
    const int l4  = lane >> 4;
    const int rg = blockIdx.x >> 3;
    const int ks = blockIdx.x & 7;
    const int rowW = rg * 256 + wv * 64;
    const int colBase = ks * COLS_PER_SPLIT;

    // A fragments resident in VGPRs
    f16x8 A[4][8];
#pragma unroll
    for (int rt = 0; rt < 4; ++rt)
#pragma unroll
        for (int t = 0; t < 8; ++t)
            A[rt][t] = *reinterpret_cast<const f16x8*>(
                X16 + (size_t)(rowW + 16*rt + l15) * D_DIM + 32*t + l4*8);

    // nhen split -> LDS (256 x float4)
    *reinterpret_cast<float4*>(&nh_lds[tid * 4]) =
        *reinterpret_cast<const float4*>(nhen + colBase + tid * 4);

    float best[16], sec[16];
    int bbase[16];
#pragma unroll
    for (int s = 0; s < 16; ++s) { best[s] = -INFINITY; sec[s] = -INFINITY; bbase[s] = 0; }

    const char* splitSrc = (const char*)Epack + (size_t)colBase * 512;

    auto STAGE = [&](int buf, int ci) {
        const char* csrc = splitSrc + (size_t)ci * CHUNK_BYTES;
        char* cdst = (char*)&B_lds[buf][0];
#pragma unroll
        for (int c = 0; c < 4; ++c) {
            const int seg = wv * 4 + c;
            gload_lds16(csrc + seg * 1024 + (lane << 4), cdst + seg * 1024);
        }
    };

    // ping-pong accumulators; TILE computes accN for (bufc, ct) while
    // interleaving the scoring of accP (prev tile, col base cP).
    f32x4 accA[4], accB[4];
    int cA = 0, cB = 0;

    auto TILE = [&](const f16* bufc, int ct, int nhoff,
                    f32x4 (&accN)[4], f32x4 (&accP)[4], int cP, bool doScore) {
        const float nh = nh_lds[nhoff + l15];
        const f32x4 nh4 = {nh, nh, nh, nh};
#pragma unroll
        for (int t = 0; t < 8; ++t) {
            f16x8 B = *reinterpret_cast<const f16x8*>(bufc + (ct*8 + t)*512 + lane*8);
            if (t == 0) {
#pragma unroll
                for (int rt = 0; rt < 4; ++rt)
                    accN[rt] = __builtin_amdgcn_mfma_f32_16x16x32_f16(A[rt][0], B, nh4, 0, 0, 0);
            } else {
#pragma unroll
                for (int rt = 0; rt < 4; ++rt)
                    accN[rt] = __builtin_amdgcn_mfma_f32_16x16x32_f16(A[rt][t], B, accN[rt], 0, 0, 0);
            }
            if (doScore) {
                // score 2 slots of the PREVIOUS tile while these MFMAs execute
#pragma unroll
                for (int s = 2*t; s <= 2*t + 1; ++s) {
                    const int rt2 = s >> 2, r2 = s & 3;
                    const float v = accP[rt2][r2];
                    sec[s] = __builtin_amdgcn_fmed3f(v, best[s], sec[s]);
                    const bool gt = v > best[s];
                    best[s] = gt ? v : best[s];
                    bbase[s] = gt ? cP : bbase[s];
                }
            }
        }
    };

    STAGE(0, 0);
    STAGE(1, 1);
    asm volatile("s_waitcnt lgkmcnt(0)" ::: "memory");  // nh_lds writes drained

    int cur = 0;
    for (int ci = 0; ci < NCHUNK; ++ci) {
        if (ci < NCHUNK - 1) {
            asm volatile("s_waitcnt vmcnt(4)" ::: "memory");  // own stage(ci) done
        } else {
            asm volatile("s_waitcnt vmcnt(0)" ::: "memory");
        }
        __builtin_amdgcn_s_barrier();
        if (ci + 2 < NCHUNK) {
            int nb = cur + 2; if (nb >= 3) nb -= 3;
            STAGE(nb, ci + 2);
        }
        const f16* bufc = &B_lds[cur][0];
        const int base = colBase + ci * CHUNK_COLS;
        if (ci == 0) {
            TILE(bufc, 0, ci*32,      accA, accB, cB, false); cA = base;
            TILE(bufc, 1, ci*32 + 16, accB, accA, cA, true);  cB = base + 16;
        } else {
            TILE(bufc, 0, ci*32,      accA, accB, cB, true);  cA = base;
            TILE(bufc, 1, ci*32 + 16, accB, accA, cA, true);  cB = base + 16;
        }
        cur = (cur + 1 == 3) ? 0 : cur + 1;
    }
    // epilogue: score the final tile (accB)
#pragma unroll
    for (int s = 0; s < 16; ++s) {
        const int rt2 = s >> 2, r2 = s & 3;
        const float v = accB[rt2][r2];
        sec[s] = __builtin_amdgcn_fmed3f(v, best[s], sec[s]);
        const bool gt = v > best[s];
        best[s] = gt ? v : best[s];
        bbase[s] = gt ? cB : bbase[s];
    }

    // top-2 merge across the 16 l15 lanes of each quarter-wave
#pragma unroll
    for (int s = 0; s < 16; ++s) {
        float b = best[s], sc = sec[s];
        int k = bbase[s] + l15;
#pragma unroll
        for (int off = 8; off >= 1; off >>= 1) {
            float ob = __shfl_xor(b, off, 16);
            float os = __shfl_xor(sc, off, 16);
            int   ok = __shfl_xor(k, off, 16);
            float sm = fmaxf(fmaxf(sc, os), fminf(b, ob));
            bool take = (ob > b) || (ob == b && ok < k);
            b = take ? ob : b;
            k = take ? ok : k;
            sc = sm;
        }
        if (l15 == 0) {
            const int row = rowW + 16*(s >> 2) + 4*l4 + (s & 3);
            p_best[ks * N_ROWS + row] = b;
            p_sec [ks * N_ROWS + row] = sc;
            p_idx [ks * N_ROWS + row] = k;
        }
    }
}

// ---------------------------------------------------------------------------
__global__ void zero_counts_kernel(int* count, int* count3) { *count = 0; *count3 = 0; }

// merge K-splits; flag rows with gap < EPS1 into compacted tier-2 list
__global__ void merge_kernel(const float* __restrict__ p_best,
                             const float* __restrict__ p_sec,
                             const int*   __restrict__ p_idx,
                             int* __restrict__ idxf,
                             int* __restrict__ list, int* __restrict__ count) {
    const int n = blockIdx.x * 256 + threadIdx.x;
    float b = p_best[n], sc = p_sec[n];
    int k = p_idx[n];
#pragma unroll
    for (int s = 1; s < KSPLIT; ++s) {
        float ob = p_best[s * N_ROWS + n];
        float os = p_sec [s * N_ROWS + n];
        int   ok = p_idx [s * N_ROWS + n];
        float sm = fmaxf(fmaxf(sc, os), fminf(b, ob));
        bool take = ob > b;            // equal -> keep earlier split (smaller k)
        b = take ? ob : b; k = take ? ok : k; sc = sm;
    }
    idxf[n] = k;
    if (2.0f * (b - sc) < EPS1) {
        int pos = atomicAdd(count, 1);
        if (pos < T2CAP) list[pos] = n;
    }
}

// ---------------------------------------------------------------------------
// tier-2: fp32 rescan of flagged rows. Block = (group of 64 rows) x (512-col
// split). Tracks top-2 max of u = dot + nhen.
// ---------------------------------------------------------------------------
__launch_bounds__(256, 2)
__global__ void tier2_kernel(const float* __restrict__ X,
                             const float* __restrict__ E,
                             const float* __restrict__ nhen,
                             const int* __restrict__ list,
                             const int* __restrict__ count,
                             float* __restrict__ t2b, float* __restrict__ t2s,
                             int* __restrict__ t2i) {
    const int g  = blockIdx.x >> 4;
    const int sp = blockIdx.x & 15;
    const int cnt = min(*count, T2CAP);
    if (g * 64 >= cnt) return;

    __shared__ float xT[D_DIM][64];
    __shared__ float es[64][64];
    const int tid = threadIdx.x;
    const int tx = tid & 15, ty = tid >> 4;

    {
        const int r = tid >> 2;
        const int slot = min(g * 64 + r, cnt - 1);
        const int row = list[slot];
        const int d0 = (tid & 3) * 64;
        const float* xp = X + (size_t)row * D_DIM + d0;
#pragma unroll
        for (int i = 0; i < 64; i += 4) {
            float4 v = *reinterpret_cast<const float4*>(xp + i);
            xT[d0+i+0][r] = v.x; xT[d0+i+1][r] = v.y;
            xT[d0+i+2][r] = v.z; xT[d0+i+3][r] = v.w;
        }
    }

    float best[4], sec[4]; int bidx[4];
#pragma unroll
    for (int i = 0; i < 4; ++i) { best[i] = -INFINITY; sec[i] = -INFINITY; bidx[i] = 0; }

    const int colBase = sp * 512;
    for (int kc = 0; kc < 512; kc += 64) {
        float acc[4][4];
#pragma unroll
        for (int i = 0; i < 4; ++i)
#pragma unroll
            for (int j = 0; j < 4; ++j) acc[i][j] = 0.0f;

        for (int dc = 0; dc < D_DIM; dc += 64) {
            __syncthreads();
#pragma unroll
            for (int dd = 0; dd < 64; dd += 16) {
                int d = dd + (tid >> 4);
                float4 v = *reinterpret_cast<const float4*>(
                    &E[(size_t)(dc + d) * K_DIM + colBase + kc + (tid & 15) * 4]);
                *reinterpret_cast<float4*>(&es[d][(tid & 15) * 4]) = v;
            }
            __syncthreads();
#pragma unroll 8
            for (int d = 0; d < 64; ++d) {
                float4 xv = *reinterpret_cast<const float4*>(&xT[dc + d][ty * 4]);
                float4 ev = *reinterpret_cast<const float4*>(&es[d][tx * 4]);
                float xr[4] = {xv.x, xv.y, xv.z, xv.w};
                float ec[4] = {ev.x, ev.y, ev.z, ev.w};
#pragma unroll
                for (int i = 0; i < 4; ++i)
#pragma unroll
                    for (int j = 0; j < 4; ++j)
                        acc[i][j] = fmaf(xr[i], ec[j], acc[i][j]);
            }
        }
        float4 nhv = *reinterpret_cast<const float4*>(&nhen[colBase + kc + tx * 4]);
        float nh[4] = {nhv.x, nhv.y, nhv.z, nhv.w};
#pragma unroll
        for (int j = 0; j < 4; ++j) {
            const int k = colBase + kc + tx * 4 + j;
#pragma unroll
            for (int i = 0; i < 4; ++i) {
                float u = nh[j] + acc[i][j];
                bool gt = u > best[i];
                sec[i]  = fmaxf(sec[i], fminf(u, best[i]));
                best[i] = gt ? u : best[i];
                bidx[i] = gt ? k : bidx[i];
            }
        }
    }

#pragma unroll
    for (int off = 8; off >= 1; off >>= 1) {
#pragma unroll
        for (int i = 0; i < 4; ++i) {
            float ob = __shfl_xor(best[i], off, 16);
            float os = __shfl_xor(sec[i], off, 16);
            int   ok = __shfl_xor(bidx[i], off, 16);
            float sm = fmaxf(fmaxf(sec[i], os), fminf(best[i], ob));
            bool take = (ob > best[i]) || (ob == best[i] && ok < bidx[i]);
            best[i] = take ? ob : best[i];
            bidx[i] = take ? ok : bidx[i];
            sec[i] = sm;
        }
    }
    if (tx == 0) {
#pragma unroll
        for (int i = 0; i < 4; ++i) {
            const int slot = g * 64 + ty * 4 + i;
            if (slot < cnt) {
                t2b[sp * T2CAP + slot] = best[i];
                t2s[sp * T2CAP + slot] = sec[i];
                t2i[sp * T2CAP + slot] = bidx[i];
            }
        }
    }
}

// merge tier-2 splits; flag knife-edge rows into compacted tier-3 list
__global__ void merge2_kernel(const float* __restrict__ t2b,
                              const float* __restrict__ t2s,
                              const int*   __restrict__ t2i,
                              const int* __restrict__ list,
                              const int* __restrict__ count,
                              int* __restrict__ idxf,
                              int* __restrict__ list3, int* __restrict__ count3) {
    const int slot = blockIdx.x * 256 + threadIdx.x;
    const int cnt = min(*count, T2CAP);
    if (slot >= cnt) return;
    float b = t2b[slot], sc = t2s[slot];
    int k = t2i[slot];
#pragma unroll
    for (int sp = 1; sp < 16; ++sp) {
        float ob = t2b[sp * T2CAP + slot];
        float os = t2s[sp * T2CAP + slot];
        int   ok = t2i[sp * T2CAP + slot];
        float sm = fmaxf(fmaxf(sc, os), fminf(b, ob));
        bool take = ob > b;
        b = take ? ob : b; k = take ? ok : k; sc = sm;
    }
    const int n = list[slot];
    idxf[n] = k;
    if (2.0f * (b - sc) < EPS2) {
        int pos = atomicAdd(count3, 1);
        if (pos < T3CAP) list3[pos] = n;
    }
}

// ---------------------------------------------------------------------------
// tier-3: fp64 exact rescan, K split 16 ways across blocks.
// ---------------------------------------------------------------------------
__launch_bounds__(256)
__global__ void tier3_kernel(const float* __restrict__ X,
                             const float* __restrict__ E,
                             const int* __restrict__ list3,
                             const int* __restrict__ count3,
                             double* __restrict__ t3b, int* __restrict__ t3i) {
    const int slot = blockIdx.x >> 4;
    const int sp   = blockIdx.x & 15;
    const int cnt = min(*count3, T3CAP);
    if (slot >= cnt) return;
    const int n = list3[slot];

    __shared__ float xs[D_DIM];
    const int tid = threadIdx.x;
    xs[tid] = X[(size_t)n * D_DIM + tid];
    __syncthreads();

    const int colBase = sp * 512;
    double best = DBL_MAX;
    int bi = 0x7fffffff;
#pragma unroll
    for (int kk = 0; kk < 512; kk += 256) {
        const int k = colBase + kk + tid;
        double s0 = 0.0, s1 = 0.0, s2 = 0.0, s3 = 0.0;
#pragma unroll 4
        for (int d = 0; d < D_DIM; d += 4) {
            double f0 = (double)xs[d+0] - (double)E[(size_t)(d+0) * K_DIM + k];
            double f1 = (double)xs[d+1] - (double)E[(size_t)(d+1) * K_DIM + k];
            double f2 = (double)xs[d+2] - (double)E[(size_t)(d+2) * K_DIM + k];
            double f3 = (double)xs[d+3] - (double)E[(size_t)(d+3) * K_DIM + k];
            s0 = fma(f0, f0, s0); s1 = fma(f1, f1, s1);
            s2 = fma(f2, f2, s2); s3 = fma(f3, f3, s3);
        }
        double s = (s0 + s1) + (s2 + s3);
        if (s < best) { best = s; bi = k; }
    }

    __shared__ double bv[256];
    __shared__ int bix[256];
    bv[tid] = best; bix[tid] = bi;
    __syncthreads();
    if (tid == 0) {
        double b = bv[0]; int ix = bix[0];
        for (int t = 1; t < 256; ++t)
            if (bv[t] < b || (bv[t] == b && bix[t] < ix)) { b = bv[t]; ix = bix[t]; }
        t3b[sp * T3CAP + slot] = b;
        t3i[sp * T3CAP + slot] = ix;
    }
}

__global__ void merge3_kernel(const double* __restrict__ t3b,
                              const int* __restrict__ t3i,
                              const int* __restrict__ list3,
                              const int* __restrict__ count3,
                              int* __restrict__ idxf) {
    const int slot = blockIdx.x * 256 + threadIdx.x;
    const int cnt = min(*count3, T3CAP);
    if (slot >= cnt) return;
    double b = t3b[slot];
    int k = t3i[slot];
#pragma unroll
    for (int sp = 1; sp < NSPLIT3; ++sp) {
        double ob = t3b[sp * T3CAP + slot];
        int   ok = t3i[sp * T3CAP + slot];
        if (ob < b || (ob == b && ok < k)) { b = ob; k = ok; }
    }
    idxf[list3[slot]] = k;
}

// ---------------------------------------------------------------------------
// gather from transposed table: out[n][:] = ET[idx[n]][:]  (coalesced)
// ---------------------------------------------------------------------------
__global__ void gather2_kernel(const float* __restrict__ ET,
                               const int* __restrict__ idx,
                               float* __restrict__ out) {
    const int n  = blockIdx.x * 4 + (threadIdx.x >> 6);
    const int d4 = (threadIdx.x & 63) * 4;
    const int k  = idx[n];
    *reinterpret_cast<float4*>(&out[(size_t)n * D_DIM + d4]) =
        *reinterpret_cast<const float4*>(&ET[(size_t)k * D_DIM + d4]);
}

// strided fallback gather (no ET workspace)
__global__ void gather_kernel(const float* __restrict__ E,
                              const int* __restrict__ idx,
                              float* __restrict__ out) {
    const int n = blockIdx.x;
    const int d = threadIdx.x;
    const int k = idx[n];
    out[(size_t)n * D_DIM + d] = E[(size_t)d * K_DIM + k];
}

// ======================= fallback path (proven round-2) =====================
__global__ void fb_enorm_kernel(const float* __restrict__ E, float* __restrict__ enorm) {
    int k = blockIdx.x * 256 + threadIdx.x;
    float s = 0.0f;
#pragma unroll 8
    for (int d = 0; d < D_DIM; ++d) { float v = E[(size_t)d * K_DIM + k]; s = fmaf(v, v, s); }
    enorm[k] = s;
}

__launch_bounds__(256, 2)
__global__ void fb_dist_kernel(const float* __restrict__ X, const float* __restrict__ E,
                               const float* __restrict__ enorm,
                               int* __restrict__ idx_out, float* __restrict__ gap_out) {
    __shared__ float xT[D_DIM][64];
    __shared__ float es[64][64];
    const int tid = threadIdx.x;
    const int tx = tid & 15, ty = tid >> 4;
    const int rowBase = blockIdx.x * 64;
    {
        const int r = tid >> 2;
        const int d0 = (tid & 3) * 64;
        const float* xp = X + (size_t)(rowBase + r) * D_DIM + d0;
#pragma unroll
        for (int i = 0; i < 64; i += 4) {
            float4 v = *reinterpret_cast<const float4*>(xp + i);
            xT[d0+i+0][r]=v.x; xT[d0+i+1][r]=v.y; xT[d0+i+2][r]=v.z; xT[d0+i+3][r]=v.w;
        }
    }
    float bestVal[4], secVal[4]; int bestIdx[4];
#pragma unroll
    for (int i = 0; i < 4; ++i) { bestVal[i]=INFINITY; secVal[i]=INFINITY; bestIdx[i]=0; }
    for (int kc = 0; kc < K_DIM; kc += 64) {
        float acc[4][4];
#pragma unroll
        for (int i=0;i<4;++i)
#pragma unroll
            for (int j=0;j<4;++j) acc[i][j]=0.f;
        for (int dc = 0; dc < D_DIM; dc += 64) {
            __syncthreads();
#pragma unroll
            for (int dd = 0; dd < 64; dd += 16) {
                int d = dd + (tid >> 4);
                float4 v = *reinterpret_cast<const float4*>(
                    &E[(size_t)(dc+d)*K_DIM + kc + (tid&15)*4]);
                *reinterpret_cast<float4*>(&es[d][(tid&15)*4]) = v;
            }
            __syncthreads();
#pragma unroll 8
            for (int d = 0; d < 64; ++d) {
                float4 xv = *reinterpret_cast<const float4*>(&xT[dc+d][ty*4]);
                float4 ev = *reinterpret_cast<const float4*>(&es[d][tx*4]);
                float xr[4]={xv.x,xv.y,xv.z,xv.w}, ec[4]={ev.x,ev.y,ev.z,ev.w};
#pragma unroll
                for (int i=0;i<4;++i)
#pragma unroll
                    for (int j=0;j<4;++j) acc[i][j]=fmaf(xr[i],ec[j],acc[i][j]);
            }
        }
        float4 env = *reinterpret_cast<const float4*>(&enorm[kc + tx*4]);
        float en[4]={env.x,env.y,env.z,env.w};
#pragma unroll
        for (int j=0;j<4;++j) {
            int k = kc + tx*4 + j;
#pragma unroll
            for (int i=0;i<4;++i) {
                float s = fmaf(-2.0f, acc[i][j], en[j]);
                if (s < bestVal[i]) { secVal[i]=bestVal[i]; bestVal[i]=s; bestIdx[i]=k; }
                else if (s < secVal[i]) secVal[i]=s;
            }
        }
    }
#pragma unroll
    for (int off=8; off>=1; off>>=1) {
#pragma unroll
        for (int i=0;i<4;++i) {
            float oB=__shfl_xor(bestVal[i],off,16);
            int oI=__shfl_xor(bestIdx[i],off,16);
            float oS=__shfl_xor(secVal[i],off,16);
            float ms=fminf(fminf(secVal[i],oS),fmaxf(bestVal[i],oB));
            if (oB<bestVal[i] || (oB==bestVal[i] && oI<bestIdx[i])) { bestVal[i]=oB; bestIdx[i]=oI; }
            secVal[i]=ms;
        }
    }
    if (tx==0) {
#pragma unroll
        for (int i=0;i<4;++i) {
            idx_out[rowBase + ty*4 + i] = bestIdx[i];
            gap_out[rowBase + ty*4 + i] = secVal[i]-bestVal[i];
        }
    }
}

__launch_bounds__(256)
__global__ void fb_refine_kernel(const float* __restrict__ X, const float* __restrict__ E,
                                 const float* __restrict__ gap, int* __restrict__ idx) {
    const int n = blockIdx.x;
    if (gap[n] >= 0.0625f) return;
    __shared__ float xs[D_DIM];
    const int tid = threadIdx.x;
    xs[tid] = X[(size_t)n * D_DIM + tid];
    __syncthreads();
    double best = DBL_MAX; int bi = 0x7fffffff;
    for (int k = tid; k < K_DIM; k += 256) {
        double s0=0,s1=0,s2=0,s3=0;
#pragma unroll 4
        for (int d = 0; d < D_DIM; d += 4) {
            double f0=(double)xs[d+0]-(double)E[(size_t)(d+0)*K_DIM+k];
            double f1=(double)xs[d+1]-(double)E[(size_t)(d+1)*K_DIM+k];
            double f2=(double)xs[d+2]-(double)E[(size_t)(d+2)*K_DIM+k];
            double f3=(double)xs[d+3]-(double)E[(size_t)(d+3)*K_DIM+k];
            s0=fma(f0,f0,s0); s1=fma(f1,f1,s1); s2=fma(f2,f2,s2); s3=fma(f3,f3,s3);
        }
        double s=(s0+s1)+(s2+s3);
        if (s<best){best=s;bi=k;}
    }
    __shared__ double bv[256]; __shared__ int bix[256];
    bv[tid]=best; bix[tid]=bi;
    __syncthreads();
    if (tid==0) {
        double b=bv[0]; int ix=bix[0];
        for (int t=1;t<256;++t)
            if (bv[t]<b || (bv[t]==b && bix[t]<ix)) { b=bv[t]; ix=bix[t]; }
        idx[n]=ix;
    }
}

// ---------------------------------------------------------------------------
extern "C" void kernel_launch(void* const* d_in, const int* in_sizes, int n_in,
                              void* d_out, int out_size, void* d_ws, size_t ws_size,
                              hipStream_t stream) {
    const float* X = (const float*)d_in[0];
    const float* E = (const float*)d_in[1];
    float* out = (float*)d_out;
    char* ws = (char*)d_ws;

    // fast-path workspace layout
    const size_t o_nhen  = 0;                                       // K*4
    const size_t o_pb    = 32768;
    const size_t o_ps    = o_pb  + (size_t)KSPLIT * N_ROWS * 4;
    const size_t o_pi    = o_ps  + (size_t)KSPLIT * N_ROWS * 4;
    const size_t o_idx   = o_pi  + (size_t)KSPLIT * N_ROWS * 4;
    const size_t o_list  = o_idx + (size_t)N_ROWS * 4;
    const size_t o_count = o_list + (size_t)T2CAP * 4;              // count @+0, count3 @+4
    const size_t o_t2b   = o_count + 256;
    const size_t o_t2s   = o_t2b + (size_t)16 * T2CAP * 4;
    const size_t o_t2i   = o_t2s + (size_t)16 * T2CAP * 4;
    const size_t o_list3 = o_t2i + (size_t)16 * T2CAP * 4;
    const size_t o_t3b   = o_list3 + (size_t)T3CAP * 4;             // 8B-aligned
    const size_t o_t3i   = o_t3b + (size_t)NSPLIT3 * T3CAP * 8;
    const size_t o_x16   = o_t3i + (size_t)NSPLIT3 * T3CAP * 4;
    const size_t o_epack = o_x16 + (size_t)N_ROWS * D_DIM * 2;
    const size_t NEED_BASE = o_epack + (size_t)D_DIM * K_DIM * 2;
    const size_t o_et    = NEED_BASE;                               // optional ET
    const size_t NEED_FULL = o_et + (size_t)D_DIM * K_DIM * 4;

    if (ws_size >= NEED_BASE) {
        float*  nhen  = (float*) (ws + o_nhen);
        float*  p_b   = (float*) (ws + o_pb);
        float*  p_s   = (float*) (ws + o_ps);
        int*    p_i   = (int*)   (ws + o_pi);
        int*    idxf  = (int*)   (ws + o_idx);
        int*    list  = (int*)   (ws + o_list);
        int*    count = (int*)   (ws + o_count);
        int*    count3= (int*)   (ws + o_count + 4);
        float*  t2b   = (float*) (ws + o_t2b);
        float*  t2s   = (float*) (ws + o_t2s);
        int*    t2i   = (int*)   (ws + o_t2i);
        int*    list3 = (int*)   (ws + o_list3);
        double* t3b   = (double*)(ws + o_t3b);
        int*    t3i   = (int*)   (ws + o_t3i);
        f16*    X16   = (f16*)   (ws + o_x16);
        f16*    Epack = (f16*)   (ws + o_epack);
        float*  ET    = (float*) (ws + o_et);
        const bool haveET = ws_size >= NEED_FULL;

        convx_kernel<<<(N_ROWS * D_DIM / 8) / 256, 256, 0, stream>>>(X, X16);
        if (haveET) {
            transpose_kernel<<<(K_DIM / 64) * (D_DIM / 64), 256, 0, stream>>>(E, ET);
            packe_et_kernel<<<(K_DIM / 16) * 8 * 64 / 256, 256, 0, stream>>>(ET, Epack);
        } else {
            packe_kernel<<<(K_DIM / 16) * 8 * 64 / 256, 256, 0, stream>>>(E, Epack);
        }
        nhen_kernel<<<K_DIM / 256, 256, 0, stream>>>(E, nhen);
        zero_counts_kernel<<<1, 1, 0, stream>>>(count, count3);
        pass1_kernel<<<(N_ROWS / 256) * KSPLIT, 256, 0, stream>>>(
            X16, Epack, nhen, p_b, p_s, p_i);
        merge_kernel<<<N_ROWS / 256, 256, 0, stream>>>(
            p_b, p_s, p_i, idxf, list, count);
        tier2_kernel<<<(T2CAP / 64) * 16, 256, 0, stream>>>(
            X, E, nhen, list, count, t2b, t2s, t2i);
        merge2_kernel<<<T2CAP / 256, 256, 0, stream>>>(
            t2b, t2s, t2i, list, count, idxf, list3, count3);
        tier3_kernel<<<T3CAP * NSPLIT3, 256, 0, stream>>>(
            X, E, list3, count3, t3b, t3i);
        merge3_kernel<<<T3CAP / 256, 256, 0, stream>>>(
            t3b, t3i, list3, count3, idxf);
        if (haveET)
            gather2_kernel<<<N_ROWS / 4, 256, 0, stream>>>(ET, idxf, out);
        else
            gather_kernel<<<N_ROWS, 256, 0, stream>>>(E, idxf, out);
    } else {
        float* enorm = (float*)ws;
        int*   idx   = (int*)(ws + 32768);
        float* gap   = (float*)(ws + 32768 + (size_t)N_ROWS * 4);
        fb_enorm_kernel<<<K_DIM / 256, 256, 0, stream>>>(E, enorm);
        fb_dist_kernel<<<N_ROWS / 64, 256, 0, stream>>>(X, E, enorm, idx, gap);
        fb_refine_kernel<<<N_ROWS, 256, 0, stream>>>(X, E, gap, idx);
        gather_kernel<<<N_ROWS, 256, 0, stream>>>(E, idx, out);
    }
}

// Round 11
// 310.663 us; speedup vs baseline: 1.1917x; 1.0440x over previous
//
#include <hip/hip_runtime.h>
#include <math.h>
#include <float.h>

#define N_ROWS 32768
#define D_DIM  256
#define K_DIM  8192

#define EPS1 0.25f   // tier-1 (f16) gap threshold, full-distance scale (28 sigma)
#define EPS2 0.02f   // tier-2 (fp32) gap threshold
#define T2CAP 4096   // tier-2 row capacity
#define NSPLIT2 32   // tier-2 K splits (256 cols each)
#define T3CAP 512    // tier-3 row capacity
#define NSPLIT3 16   // tier-3 K splits (512 cols each)

typedef _Float16 f16;
typedef _Float16 f16x8 __attribute__((ext_vector_type(8)));
typedef float f32x4 __attribute__((ext_vector_type(4)));

#define KSPLIT 8
#define COLS_PER_SPLIT (K_DIM / KSPLIT)      // 1024
#define CHUNK_COLS 32
#define NCHUNK (COLS_PER_SPLIT / CHUNK_COLS) // 32
#define CHUNK_BYTES (CHUNK_COLS * D_DIM * 2) // 16384

// global_load_lds plumbing (clang builtin needs explicit address spaces)
typedef unsigned int u32;
typedef const u32 __attribute__((address_space(1)))* gas1_u32;
typedef u32 __attribute__((address_space(3)))* las3_u32;
__device__ __forceinline__ void gload_lds16(const void* g, void* l) {
    __builtin_amdgcn_global_load_lds((gas1_u32)g, (las3_u32)l, 16, 0, 0);
}

// ---------------------------------------------------------------------------
// convert X fp32 -> f16, [N][D] row-major; block 0 also zeroes the counters.
// ---------------------------------------------------------------------------
__global__ void convx_kernel(const float* __restrict__ X, f16* __restrict__ X16,
                             int* __restrict__ count, int* __restrict__ count3) {
    if (blockIdx.x == 0 && threadIdx.x == 0) { *count = 0; *count3 = 0; }
    const size_t i = ((size_t)blockIdx.x * 256 + threadIdx.x) * 8;
    float4 a = *reinterpret_cast<const float4*>(X + i);
    float4 b = *reinterpret_cast<const float4*>(X + i + 4);
    f16x8 o;
    o[0]=(f16)a.x; o[1]=(f16)a.y; o[2]=(f16)a.z; o[3]=(f16)a.w;
    o[4]=(f16)b.x; o[5]=(f16)b.y; o[6]=(f16)b.z; o[7]=(f16)b.w;
    *reinterpret_cast<f16x8*>(X16 + i) = o;
}

// ---------------------------------------------------------------------------
// prep_e: one pass over E producing BOTH ET (transpose, for coalesced gather)
// and Epack (f16 B-fragment-linear, for pass1) from the same LDS tile.
// t[dd][kk] = E[d0+dd][k0+kk].
// Epack[(tile*8 + t)*512 + l*8 + j] = E[32t + (l>>4)*8 + j][16*tile + (l&15)]
// ---------------------------------------------------------------------------
__global__ void prep_e_kernel(const float* __restrict__ E, float* __restrict__ ET,
                              f16* __restrict__ Epack) {
    __shared__ float t[64][65];
    const int bk = blockIdx.x & (K_DIM / 64 - 1);   // 128 k-tiles
    const int bd = blockIdx.x >> 7;                 // 4 d-tiles
    const int c  = threadIdx.x & 63;
    const int r0 = (threadIdx.x >> 6) * 16;
    const int d0 = bd * 64, k0 = bk * 64;
#pragma unroll
    for (int i = 0; i < 16; ++i)
        t[r0 + i][c] = E[(size_t)(d0 + r0 + i) * K_DIM + k0 + c];
    __syncthreads();
    // ET[k][d] = E[d][k]
#pragma unroll
    for (int i = 0; i < 16; ++i)
        ET[(size_t)(k0 + r0 + i) * D_DIM + d0 + c] = t[c][r0 + i];
    // Epack fragments for this 64k x 64d region: 512 f16x8 stores, 2/thread.
#pragma unroll
    for (int o = 0; o < 2; ++o) {
        const int out = threadIdx.x + o * 256;
        const int i16 = out >> 7;          // k-subtile 0..3
        const int th  = (out >> 6) & 1;    // d-half 0..1
        const int l   = out & 63;          // lane
        const int tile = bk * 4 + i16;
        const int tg   = bd * 2 + th;
        f16x8 frag;
#pragma unroll
        for (int j = 0; j < 8; ++j)
            frag[j] = (f16)t[32*th + (l >> 4) * 8 + j][16*i16 + (l & 15)];
        *reinterpret_cast<f16x8*>(Epack + ((size_t)(tile*8 + tg) * 512 + l * 8)) = frag;
    }
}

// fallback packe reading E directly (no ET workspace)
__global__ void packe_kernel(const float* __restrict__ E, f16* __restrict__ Epack) {
    const int gid = blockIdx.x * 256 + threadIdx.x;
    const int l    = gid & 63;
    const int t    = (gid >> 6) & 7;
    const int tile = gid >> 9;
    const int k  = 16 * tile + (l & 15);
    const int d0 = 32 * t + (l >> 4) * 8;
    f16x8 o;
#pragma unroll
    for (int j = 0; j < 8; ++j) o[j] = (f16)E[(size_t)(d0 + j) * K_DIM + k];
    *reinterpret_cast<f16x8*>(Epack + (size_t)gid * 8) = o;
}

// ---------------------------------------------------------------------------
// nhen[k] = -0.5 * sum_d E[d][k]^2   (fp32)
// ---------------------------------------------------------------------------
__global__ void nhen_kernel(const float* __restrict__ E, float* __restrict__ nhen) {
    const int k = blockIdx.x * 256 + threadIdx.x;
    float s = 0.0f;
#pragma unroll 8
    for (int d = 0; d < D_DIM; ++d) {
        float v = E[(size_t)d * K_DIM + k];
        s = fmaf(v, v, s);
    }
    nhen[k] = -0.5f * s;
}

// ---------------------------------------------------------------------------
// pass1 (round-10): f16 MFMA fused GEMM + per-row top-2 argmax of
// u = x.e - 0.5||e||^2, deferred-scoring ping-pong + counted-vmcnt staging.
// ---------------------------------------------------------------------------
__launch_bounds__(256, 2)
__global__ void pass1_kernel(const f16* __restrict__ X16,
                             const f16* __restrict__ Epack,
                             const float* __restrict__ nhen,
                             float* __restrict__ p_best,
                             float* __restrict__ p_sec,
                             int*   __restrict__ p_idx) {
    __shared__ f16 B_lds[3][CHUNK_BYTES / 2];   // 3 x 16KB rotating
    __shared__ float nh_lds[COLS_PER_SPLIT];    // 4KB

    const int tid = threadIdx.x;
    const int wv = tid >> 6;
    const int lane = tid & 63;
    const int l15 = lane & 15;
    const int l4  = lane >> 4;
    const int rg = blockIdx.x >> 3;
    const int ks = blockIdx.x & 7;
    const int rowW = rg * 256 + wv * 64;
    const int colBase = ks * COLS_PER_SPLIT;

    f16x8 A[4][8];
#pragma unroll
    for (int rt = 0; rt < 4; ++rt)
#pragma unroll
        for (int t = 0; t < 8; ++t)
            A[rt][t] = *reinterpret_cast<const f16x8*>(
                X16 + (size_t)(rowW + 16*rt + l15) * D_DIM + 32*t + l4*8);

    *reinterpret_cast<float4*>(&nh_lds[tid * 4]) =
        *reinterpret_cast<const float4*>(nhen + colBase + tid * 4);

    float best[16], sec[16];
    int bbase[16];
#pragma unroll
    for (int s = 0; s < 16; ++s) { best[s] = -INFINITY; sec[s] = -INFINITY; bbase[s] = 0; }

    const char* splitSrc = (const char*)Epack + (size_t)colBase * 512;

    auto STAGE = [&](int buf, int ci) {
        const char* csrc = splitSrc + (size_t)ci * CHUNK_BYTES;
        char* cdst = (char*)&B_lds[buf][0];
#pragma unroll
        for (int c = 0; c < 4; ++c) {
            const int seg = wv * 4 + c;
            gload_lds16(csrc + seg * 1024 + (lane << 4), cdst + seg * 1024);
        }
    };

    f32x4 accA[4], accB[4];
    int cA = 0, cB = 0;

    auto TILE = [&](const f16* bufc, int ct, int nhoff,
                    f32x4 (&accN)[4], f32x4 (&accP)[4], int cP, bool doScore) {
        const float nh = nh_lds[nhoff + l15];
        const f32x4 nh4 = {nh, nh, nh, nh};
#pragma unroll
        for (int t = 0; t < 8; ++t) {
            f16x8 B = *reinterpret_cast<const f16x8*>(bufc + (ct*8 + t)*512 + lane*8);
            if (t == 0) {
#pragma unroll
                for (int rt = 0; rt < 4; ++rt)
                    accN[rt] = __builtin_amdgcn_mfma_f32_16x16x32_f16(A[rt][0], B, nh4, 0, 0, 0);
            } else {
#pragma unroll
                for (int rt = 0; rt < 4; ++rt)
                    accN[rt] = __builtin_amdgcn_mfma_f32_16x16x32_f16(A[rt][t], B, accN[rt], 0, 0, 0);
            }
            if (doScore) {
#pragma unroll
                for (int s = 2*t; s <= 2*t + 1; ++s) {
                    const int rt2 = s >> 2, r2 = s & 3;
                    const float v = accP[rt2][r2];
                    sec[s] = __builtin_amdgcn_fmed3f(v, best[s], sec[s]);
                    const bool gt = v > best[s];
                    best[s] = gt ? v : best[s];
                    bbase[s] = gt ? cP : bbase[s];
                }
            }
        }
    };

    STAGE(0, 0);
    STAGE(1, 1);
    asm volatile("s_waitcnt lgkmcnt(0)" ::: "memory");  // nh_lds writes drained

    int cur = 0;
    for (int ci = 0; ci < NCHUNK; ++ci) {
        if (ci < NCHUNK - 1) {
            asm volatile("s_waitcnt vmcnt(4)" ::: "memory");  // own stage(ci) done
        } else {
            asm volatile("s_waitcnt vmcnt(0)" ::: "memory");
        }
        __builtin_amdgcn_s_barrier();
        if (ci + 2 < NCHUNK) {
            int nb = cur + 2; if (nb >= 3) nb -= 3;
            STAGE(nb, ci + 2);
        }
        const f16* bufc = &B_lds[cur][0];
        const int base = colBase + ci * CHUNK_COLS;
        if (ci == 0) {
            TILE(bufc, 0, ci*32,      accA, accB, cB, false); cA = base;
            TILE(bufc, 1, ci*32 + 16, accB, accA, cA, true);  cB = base + 16;
        } else {
            TILE(bufc, 0, ci*32,      accA, accB, cB, true);  cA = base;
            TILE(bufc, 1, ci*32 + 16, accB, accA, cA, true);  cB = base + 16;
        }
        cur = (cur + 1 == 3) ? 0 : cur + 1;
    }
#pragma unroll
    for (int s = 0; s < 16; ++s) {
        const int rt2 = s >> 2, r2 = s & 3;
        const float v = accB[rt2][r2];
        sec[s] = __builtin_amdgcn_fmed3f(v, best[s], sec[s]);
        const bool gt = v > best[s];
        best[s] = gt ? v : best[s];
        bbase[s] = gt ? cB : bbase[s];
    }

#pragma unroll
    for (int s = 0; s < 16; ++s) {
        float b = best[s], sc = sec[s];
        int k = bbase[s] + l15;
#pragma unroll
        for (int off = 8; off >= 1; off >>= 1) {
            float ob = __shfl_xor(b, off, 16);
            float os = __shfl_xor(sc, off, 16);
            int   ok = __shfl_xor(k, off, 16);
            float sm = fmaxf(fmaxf(sc, os), fminf(b, ob));
            bool take = (ob > b) || (ob == b && ok < k);
            b = take ? ob : b;
            k = take ? ok : k;
            sc = sm;
        }
        if (l15 == 0) {
            const int row = rowW + 16*(s >> 2) + 4*l4 + (s & 3);
            p_best[ks * N_ROWS + row] = b;
            p_sec [ks * N_ROWS + row] = sc;
            p_idx [ks * N_ROWS + row] = k;
        }
    }
}

// ---------------------------------------------------------------------------
// merge K-splits; flag rows with gap < EPS1 into compacted tier-2 list
__global__ void merge_kernel(const float* __restrict__ p_best,
                             const float* __restrict__ p_sec,
                             const int*   __restrict__ p_idx,
                             int* __restrict__ idxf,
                             int* __restrict__ list, int* __restrict__ count) {
    const int n = blockIdx.x * 256 + threadIdx.x;
    float b = p_best[n], sc = p_sec[n];
    int k = p_idx[n];
#pragma unroll
    for (int s = 1; s < KSPLIT; ++s) {
        float ob = p_best[s * N_ROWS + n];
        float os = p_sec [s * N_ROWS + n];
        int   ok = p_idx [s * N_ROWS + n];
        float sm = fmaxf(fmaxf(sc, os), fminf(b, ob));
        bool take = ob > b;            // equal -> keep earlier split (smaller k)
        b = take ? ob : b; k = take ? ok : k; sc = sm;
    }
    idxf[n] = k;
    if (2.0f * (b - sc) < EPS1) {
        int pos = atomicAdd(count, 1);
        if (pos < T2CAP) list[pos] = n;
    }
}

// ---------------------------------------------------------------------------
// tier-2: fp32 rescan of flagged rows. Block = (group of 64 rows) x (256-col
// split, 32 splits). Tracks top-2 max of u = dot + nhen.
// ---------------------------------------------------------------------------
__launch_bounds__(256, 2)
__global__ void tier2_kernel(const float* __restrict__ X,
                             const float* __restrict__ E,
                             const float* __restrict__ nhen,
                             const int* __restrict__ list,
                             const int* __restrict__ count,
                             float* __restrict__ t2b, float* __restrict__ t2s,
                             int* __restrict__ t2i) {
    const int g  = blockIdx.x >> 5;
    const int sp = blockIdx.x & 31;
    const int cnt = min(*count, T2CAP);
    if (g * 64 >= cnt) return;

    __shared__ float xT[D_DIM][64];
    __shared__ float es[64][64];
    const int tid = threadIdx.x;
    const int tx = tid & 15, ty = tid >> 4;

    {
        const int r = tid >> 2;
        const int slot = min(g * 64 + r, cnt - 1);
        const int row = list[slot];
        const int d0 = (tid & 3) * 64;
        const float* xp = X + (size_t)row * D_DIM + d0;
#pragma unroll
        for (int i = 0; i < 64; i += 4) {
            float4 v = *reinterpret_cast<const float4*>(xp + i);
            xT[d0+i+0][r] = v.x; xT[d0+i+1][r] = v.y;
            xT[d0+i+2][r] = v.z; xT[d0+i+3][r] = v.w;
        }
    }

    float best[4], sec[4]; int bidx[4];
#pragma unroll
    for (int i = 0; i < 4; ++i) { best[i] = -INFINITY; sec[i] = -INFINITY; bidx[i] = 0; }

    const int colBase = sp * 256;
    for (int kc = 0; kc < 256; kc += 64) {
        float acc[4][4];
#pragma unroll
        for (int i = 0; i < 4; ++i)
#pragma unroll
            for (int j = 0; j < 4; ++j) acc[i][j] = 0.0f;

        for (int dc = 0; dc < D_DIM; dc += 64) {
            __syncthreads();
#pragma unroll
            for (int dd = 0; dd < 64; dd += 16) {
                int d = dd + (tid >> 4);
                float4 v = *reinterpret_cast<const float4*>(
                    &E[(size_t)(dc + d) * K_DIM + colBase + kc + (tid & 15) * 4]);
                *reinterpret_cast<float4*>(&es[d][(tid & 15) * 4]) = v;
            }
            __syncthreads();
#pragma unroll 8
            for (int d = 0; d < 64; ++d) {
                float4 xv = *reinterpret_cast<const float4*>(&xT[dc + d][ty * 4]);
                float4 ev = *reinterpret_cast<const float4*>(&es[d][tx * 4]);
                float xr[4] = {xv.x, xv.y, xv.z, xv.w};
                float ec[4] = {ev.x, ev.y, ev.z, ev.w};
#pragma unroll
                for (int i = 0; i < 4; ++i)
#pragma unroll
                    for (int j = 0; j < 4; ++j)
                        acc[i][j] = fmaf(xr[i], ec[j], acc[i][j]);
            }
        }
        float4 nhv = *reinterpret_cast<const float4*>(&nhen[colBase + kc + tx * 4]);
        float nh[4] = {nhv.x, nhv.y, nhv.z, nhv.w};
#pragma unroll
        for (int j = 0; j < 4; ++j) {
            const int k = colBase + kc + tx * 4 + j;
#pragma unroll
            for (int i = 0; i < 4; ++i) {
                float u = nh[j] + acc[i][j];
                bool gt = u > best[i];
                sec[i]  = fmaxf(sec[i], fminf(u, best[i]));
                best[i] = gt ? u : best[i];
                bidx[i] = gt ? k : bidx[i];
            }
        }
    }

#pragma unroll
    for (int off = 8; off >= 1; off >>= 1) {
#pragma unroll
        for (int i = 0; i < 4; ++i) {
            float ob = __shfl_xor(best[i], off, 16);
            float os = __shfl_xor(sec[i], off, 16);
            int   ok = __shfl_xor(bidx[i], off, 16);
            float sm = fmaxf(fmaxf(sec[i], os), fminf(best[i], ob));
            bool take = (ob > best[i]) || (ob == best[i] && ok < bidx[i]);
            best[i] = take ? ob : best[i];
            bidx[i] = take ? ok : bidx[i];
            sec[i] = sm;
        }
    }
    if (tx == 0) {
#pragma unroll
        for (int i = 0; i < 4; ++i) {
            const int slot = g * 64 + ty * 4 + i;
            if (slot < cnt) {
                t2b[sp * T2CAP + slot] = best[i];
                t2s[sp * T2CAP + slot] = sec[i];
                t2i[sp * T2CAP + slot] = bidx[i];
            }
        }
    }
}

// merge tier-2 splits; flag knife-edge rows into compacted tier-3 list
__global__ void merge2_kernel(const float* __restrict__ t2b,
                              const float* __restrict__ t2s,
                              const int*   __restrict__ t2i,
                              const int* __restrict__ list,
                              const int* __restrict__ count,
                              int* __restrict__ idxf,
                              int* __restrict__ list3, int* __restrict__ count3) {
    const int slot = blockIdx.x * 256 + threadIdx.x;
    const int cnt = min(*count, T2CAP);
    if (slot >= cnt) return;
    float b = t2b[slot], sc = t2s[slot];
    int k = t2i[slot];
#pragma unroll
    for (int sp = 1; sp < NSPLIT2; ++sp) {
        float ob = t2b[sp * T2CAP + slot];
        float os = t2s[sp * T2CAP + slot];
        int   ok = t2i[sp * T2CAP + slot];
        float sm = fmaxf(fmaxf(sc, os), fminf(b, ob));
        bool take = ob > b;
        b = take ? ob : b; k = take ? ok : k; sc = sm;
    }
    const int n = list[slot];
    idxf[n] = k;
    if (2.0f * (b - sc) < EPS2) {
        int pos = atomicAdd(count3, 1);
        if (pos < T3CAP) list3[pos] = n;
    }
}

// ---------------------------------------------------------------------------
// tier-3: fp64 exact rescan, K split 16 ways across blocks.
// ---------------------------------------------------------------------------
__launch_bounds__(256)
__global__ void tier3_kernel(const float* __restrict__ X,
                             const float* __restrict__ E,
                             const int* __restrict__ list3,
                             const int* __restrict__ count3,
                             double* __restrict__ t3b, int* __restrict__ t3i) {
    const int slot = blockIdx.x >> 4;
    const int sp   = blockIdx.x & 15;
    const int cnt = min(*count3, T3CAP);
    if (slot >= cnt) return;
    const int n = list3[slot];

    __shared__ float xs[D_DIM];
    const int tid = threadIdx.x;
    xs[tid] = X[(size_t)n * D_DIM + tid];
    __syncthreads();

    const int colBase = sp * 512;
    double best = DBL_MAX;
    int bi = 0x7fffffff;
#pragma unroll
    for (int kk = 0; kk < 512; kk += 256) {
        const int k = colBase + kk + tid;
        double s0 = 0.0, s1 = 0.0, s2 = 0.0, s3 = 0.0;
#pragma unroll 4
        for (int d = 0; d < D_DIM; d += 4) {
            double f0 = (double)xs[d+0] - (double)E[(size_t)(d+0) * K_DIM + k];
            double f1 = (double)xs[d+1] - (double)E[(size_t)(d+1) * K_DIM + k];
            double f2 = (double)xs[d+2] - (double)E[(size_t)(d+2) * K_DIM + k];
            double f3 = (double)xs[d+3] - (double)E[(size_t)(d+3) * K_DIM + k];
            s0 = fma(f0, f0, s0); s1 = fma(f1, f1, s1);
            s2 = fma(f2, f2, s2); s3 = fma(f3, f3, s3);
        }
        double s = (s0 + s1) + (s2 + s3);
        if (s < best) { best = s; bi = k; }
    }

    __shared__ double bv[256];
    __shared__ int bix[256];
    bv[tid] = best; bix[tid] = bi;
    __syncthreads();
    if (tid == 0) {
        double b = bv[0]; int ix = bix[0];
        for (int t = 1; t < 256; ++t)
            if (bv[t] < b || (bv[t] == b && bix[t] < ix)) { b = bv[t]; ix = bix[t]; }
        t3b[sp * T3CAP + slot] = b;
        t3i[sp * T3CAP + slot] = ix;
    }
}

__global__ void merge3_kernel(const double* __restrict__ t3b,
                              const int* __restrict__ t3i,
                              const int* __restrict__ list3,
                              const int* __restrict__ count3,
                              int* __restrict__ idxf) {
    const int slot = blockIdx.x * 256 + threadIdx.x;
    const int cnt = min(*count3, T3CAP);
    if (slot >= cnt) return;
    double b = t3b[slot];
    int k = t3i[slot];
#pragma unroll
    for (int sp = 1; sp < NSPLIT3; ++sp) {
        double ob = t3b[sp * T3CAP + slot];
        int   ok = t3i[sp * T3CAP + slot];
        if (ob < b || (ob == b && ok < k)) { b = ob; k = ok; }
    }
    idxf[list3[slot]] = k;
}

// ---------------------------------------------------------------------------
// gather from transposed table: out[n][:] = ET[idx[n]][:]  (coalesced)
// ---------------------------------------------------------------------------
__global__ void gather2_kernel(const float* __restrict__ ET,
                               const int* __restrict__ idx,
                               float* __restrict__ out) {
    const int n  = blockIdx.x * 4 + (threadIdx.x >> 6);
    const int d4 = (threadIdx.x & 63) * 4;
    const int k  = idx[n];
    *reinterpret_cast<float4*>(&out[(size_t)n * D_DIM + d4]) =
        *reinterpret_cast<const float4*>(&ET[(size_t)k * D_DIM + d4]);
}

// strided fallback gather (no ET workspace)
__global__ void gather_kernel(const float* __restrict__ E,
                              const int* __restrict__ idx,
                              float* __restrict__ out) {
    const int n = blockIdx.x;
    const int d = threadIdx.x;
    const int k = idx[n];
    out[(size_t)n * D_DIM + d] = E[(size_t)d * K_DIM + k];
}

// ======================= fallback path (proven round-2) =====================
__global__ void fb_enorm_kernel(const float* __restrict__ E, float* __restrict__ enorm) {
    int k = blockIdx.x * 256 + threadIdx.x;
    float s = 0.0f;
#pragma unroll 8
    for (int d = 0; d < D_DIM; ++d) { float v = E[(size_t)d * K_DIM + k]; s = fmaf(v, v, s); }
    enorm[k] = s;
}

__launch_bounds__(256, 2)
__global__ void fb_dist_kernel(const float* __restrict__ X, const float* __restrict__ E,
                               const float* __restrict__ enorm,
                               int* __restrict__ idx_out, float* __restrict__ gap_out) {
    __shared__ float xT[D_DIM][64];
    __shared__ float es[64][64];
    const int tid = threadIdx.x;
    const int tx = tid & 15, ty = tid >> 4;
    const int rowBase = blockIdx.x * 64;
    {
        const int r = tid >> 2;
        const int d0 = (tid & 3) * 64;
        const float* xp = X + (size_t)(rowBase + r) * D_DIM + d0;
#pragma unroll
        for (int i = 0; i < 64; i += 4) {
            float4 v = *reinterpret_cast<const float4*>(xp + i);
            xT[d0+i+0][r]=v.x; xT[d0+i+1][r]=v.y; xT[d0+i+2][r]=v.z; xT[d0+i+3][r]=v.w;
        }
    }
    float bestVal[4], secVal[4]; int bestIdx[4];
#pragma unroll
    for (int i = 0; i < 4; ++i) { bestVal[i]=INFINITY; secVal[i]=INFINITY; bestIdx[i]=0; }
    for (int kc = 0; kc < K_DIM; kc += 64) {
        float acc[4][4];
#pragma unroll
        for (int i=0;i<4;++i)
#pragma unroll
            for (int j=0;j<4;++j) acc[i][j]=0.f;
        for (int dc = 0; dc < D_DIM; dc += 64) {
            __syncthreads();
#pragma unroll
            for (int dd = 0; dd < 64; dd += 16) {
                int d = dd + (tid >> 4);
                float4 v = *reinterpret_cast<const float4*>(
                    &E[(size_t)(dc+d)*K_DIM + kc + (tid&15)*4]);
                *reinterpret_cast<float4*>(&es[d][(tid&15)*4]) = v;
            }
            __syncthreads();
#pragma unroll 8
            for (int d = 0; d < 64; ++d) {
                float4 xv = *reinterpret_cast<const float4*>(&xT[dc+d][ty*4]);
                float4 ev = *reinterpret_cast<const float4*>(&es[d][tx*4]);
                float xr[4]={xv.x,xv.y,xv.z,xv.w}, ec[4]={ev.x,ev.y,ev.z,ev.w};
#pragma unroll
                for (int i=0;i<4;++i)
#pragma unroll
                    for (int j=0;j<4;++j) acc[i][j]=fmaf(xr[i],ec[j],acc[i][j]);
            }
        }
        float4 env = *reinterpret_cast<const float4*>(&enorm[kc + tx*4]);
        float en[4]={env.x,env.y,env.z,env.w};
#pragma unroll
        for (int j=0;j<4;++j) {
            int k = kc + tx*4 + j;
#pragma unroll
            for (int i=0;i<4;++i) {
                float s = fmaf(-2.0f, acc[i][j], en[j]);
                if (s < bestVal[i]) { secVal[i]=bestVal[i]; bestVal[i]=s; bestIdx[i]=k; }
                else if (s < secVal[i]) secVal[i]=s;
            }
        }
    }
#pragma unroll
    for (int off=8; off>=1; off>>=1) {
#pragma unroll
        for (int i=0;i<4;++i) {
            float oB=__shfl_xor(bestVal[i],off,16);
            int oI=__shfl_xor(bestIdx[i],off,16);
            float oS=__shfl_xor(secVal[i],off,16);
            float ms=fminf(fminf(secVal[i],oS),fmaxf(bestVal[i],oB));
            if (oB<bestVal[i] || (oB==bestVal[i] && oI<bestIdx[i])) { bestVal[i]=oB; bestIdx[i]=oI; }
            secVal[i]=ms;
        }
    }
    if (tx==0) {
#pragma unroll
        for (int i=0;i<4;++i) {
            idx_out[rowBase + ty*4 + i] = bestIdx[i];
            gap_out[rowBase + ty*4 + i] = secVal[i]-bestVal[i];
        }
    }
}

__launch_bounds__(256)
__global__ void fb_refine_kernel(const float* __restrict__ X, const float* __restrict__ E,
                                 const float* __restrict__ gap, int* __restrict__ idx) {
    const int n = blockIdx.x;
    if (gap[n] >= 0.0625f) return;
    __shared__ float xs[D_DIM];
    const int tid = threadIdx.x;
    xs[tid] = X[(size_t)n * D_DIM + tid];
    __syncthreads();
    double best = DBL_MAX; int bi = 0x7fffffff;
    for (int k = tid; k < K_DIM; k += 256) {
        double s0=0,s1=0,s2=0,s3=0;
#pragma unroll 4
        for (int d = 0; d < D_DIM; d += 4) {
            double f0=(double)xs[d+0]-(double)E[(size_t)(d+0)*K_DIM+k];
            double f1=(double)xs[d+1]-(double)E[(size_t)(d+1)*K_DIM+k];
            double f2=(double)xs[d+2]-(double)E[(size_t)(d+2)*K_DIM+k];
            double f3=(double)xs[d+3]-(double)E[(size_t)(d+3)*K_DIM+k];
            s0=fma(f0,f0,s0); s1=fma(f1,f1,s1); s2=fma(f2,f2,s2); s3=fma(f3,f3,s3);
        }
        double s=(s0+s1)+(s2+s3);
        if (s<best){best=s;bi=k;}
    }
    __shared__ double bv[256]; __shared__ int bix[256];
    bv[tid]=best; bix[tid]=bi;
    __syncthreads();
    if (tid==0) {
        double b=bv[0]; int ix=bix[0];
        for (int t=1;t<256;++t)
            if (bv[t]<b || (bv[t]==b && bix[t]<ix)) { b=bv[t]; ix=bix[t]; }
        idx[n]=ix;
    }
}

// ---------------------------------------------------------------------------
extern "C" void kernel_launch(void* const* d_in, const int* in_sizes, int n_in,
                              void* d_out, int out_size, void* d_ws, size_t ws_size,
                              hipStream_t stream) {
    const float* X = (const float*)d_in[0];
    const float* E = (const float*)d_in[1];
    float* out = (float*)d_out;
    char* ws = (char*)d_ws;

    // fast-path workspace layout
    const size_t o_nhen  = 0;                                       // K*4
    const size_t o_pb    = 32768;
    const size_t o_ps    = o_pb  + (size_t)KSPLIT * N_ROWS * 4;
    const size_t o_pi    = o_ps  + (size_t)KSPLIT * N_ROWS * 4;
    const size_t o_idx   = o_pi  + (size_t)KSPLIT * N_ROWS * 4;
    const size_t o_list  = o_idx + (size_t)N_ROWS * 4;
    const size_t o_count = o_list + (size_t)T2CAP * 4;              // count @+0, count3 @+4
    const size_t o_t2b   = o_count + 256;
    const size_t o_t2s   = o_t2b + (size_t)NSPLIT2 * T2CAP * 4;
    const size_t o_t2i   = o_t2s + (size_t)NSPLIT2 * T2CAP * 4;
    const size_t o_list3 = o_t2i + (size_t)NSPLIT2 * T2CAP * 4;
    const size_t o_t3b   = o_list3 + (size_t)T3CAP * 4;             // 8B-aligned
    const size_t o_t3i   = o_t3b + (size_t)NSPLIT3 * T3CAP * 8;
    const size_t o_x16   = o_t3i + (size_t)NSPLIT3 * T3CAP * 4;
    const size_t o_epack = o_x16 + (size_t)N_ROWS * D_DIM * 2;
    const size_t NEED_BASE = o_epack + (size_t)D_DIM * K_DIM * 2;
    const size_t o_et    = NEED_BASE;                               // optional ET
    const size_t NEED_FULL = o_et + (size_t)D_DIM * K_DIM * 4;

    if (ws_size >= NEED_BASE) {
        float*  nhen  = (float*) (ws + o_nhen);
        float*  p_b   = (float*) (ws + o_pb);
        float*  p_s   = (float*) (ws + o_ps);
        int*    p_i   = (int*)   (ws + o_pi);
        int*    idxf  = (int*)   (ws + o_idx);
        int*    list  = (int*)   (ws + o_list);
        int*    count = (int*)   (ws + o_count);
        int*    count3= (int*)   (ws + o_count + 4);
        float*  t2b   = (float*) (ws + o_t2b);
        float*  t2s   = (float*) (ws + o_t2s);
        int*    t2i   = (int*)   (ws + o_t2i);
        int*    list3 = (int*)   (ws + o_list3);
        double* t3b   = (double*)(ws + o_t3b);
        int*    t3i   = (int*)   (ws + o_t3i);
        f16*    X16   = (f16*)   (ws + o_x16);
        f16*    Epack = (f16*)   (ws + o_epack);
        float*  ET    = (float*) (ws + o_et);
        const bool haveET = ws_size >= NEED_FULL;

        convx_kernel<<<(N_ROWS * D_DIM / 8) / 256, 256, 0, stream>>>(X, X16, count, count3);
        if (haveET) {
            prep_e_kernel<<<(K_DIM / 64) * (D_DIM / 64), 256, 0, stream>>>(E, ET, Epack);
        } else {
            packe_kernel<<<(K_DIM / 16) * 8 * 64 / 256, 256, 0, stream>>>(E, Epack);
        }
        nhen_kernel<<<K_DIM / 256, 256, 0, stream>>>(E, nhen);
        pass1_kernel<<<(N_ROWS / 256) * KSPLIT, 256, 0, stream>>>(
            X16, Epack, nhen, p_b, p_s, p_i);
        merge_kernel<<<N_ROWS / 256, 256, 0, stream>>>(
            p_b, p_s, p_i, idxf, list, count);
        tier2_kernel<<<(T2CAP / 64) * NSPLIT2, 256, 0, stream>>>(
            X, E, nhen, list, count, t2b, t2s, t2i);
        merge2_kernel<<<T2CAP / 256, 256, 0, stream>>>(
            t2b, t2s, t2i, list, count, idxf, list3, count3);
        tier3_kernel<<<T3CAP * NSPLIT3, 256, 0, stream>>>(
            X, E, list3, count3, t3b, t3i);
        merge3_kernel<<<T3CAP / 256, 256, 0, stream>>>(
            t3b, t3i, list3, count3, idxf);
        if (haveET)
            gather2_kernel<<<N_ROWS / 4, 256, 0, stream>>>(ET, idxf, out);
        else
            gather_kernel<<<N_ROWS, 256, 0, stream>>>(E, idxf, out);
    } else {
        float* enorm = (float*)ws;
        int*   idx   = (int*)(ws + 32768);
        float* gap   = (float*)(ws + 32768 + (size_t)N_ROWS * 4);
        fb_enorm_kernel<<<K_DIM / 256, 256, 0, stream>>>(E, enorm);
        fb_dist_kernel<<<N_ROWS / 64, 256, 0, stream>>>(X, E, enorm, idx, gap);
        fb_refine_kernel<<<N_ROWS, 256, 0, stream>>>(X, E, gap, idx);
        gather_kernel<<<N_ROWS, 256, 0, stream>>>(E, idx, out);
    }
}

// Round 12
// 300.176 us; speedup vs baseline: 1.2334x; 1.0349x over previous
//
#include <hip/hip_runtime.h>
#include <math.h>
#include <float.h>

#define N_ROWS 32768
#define D_DIM  256
#define K_DIM  8192

#define EPS1 0.25f   // tier-1 (f16) gap threshold, full-distance scale (28 sigma)
#define EPS2 0.02f   // tier-2 (fp32) gap threshold
#define T2CAP 4096   // tier-2 row capacity
#define NSPLIT2 32   // tier-2 K splits (256 cols each)
#define T3CAP 512    // tier-3 row capacity
#define NSPLIT3 16   // tier-3 K splits (512 cols each)

typedef _Float16 f16;
typedef _Float16 f16x8 __attribute__((ext_vector_type(8)));
typedef float f32x4 __attribute__((ext_vector_type(4)));
typedef unsigned long long u64;

#define KSPLIT 8
#define COLS_PER_SPLIT (K_DIM / KSPLIT)      // 1024
#define CHUNK_COLS 32
#define NCHUNK (COLS_PER_SPLIT / CHUNK_COLS) // 32
#define CHUNK_BYTES (CHUNK_COLS * D_DIM * 2) // 16384

// prep_kernel block ranges
#define NB_CONV 4096   // N*D/8/256
#define NB_PREPE 512   // (K/64)*(D/64)
#define NB_NHEN 32     // K/256

// global_load_lds plumbing (clang builtin needs explicit address spaces)
typedef unsigned int u32;
typedef const u32 __attribute__((address_space(1)))* gas1_u32;
typedef u32 __attribute__((address_space(3)))* las3_u32;
__device__ __forceinline__ void gload_lds16(const void* g, void* l) {
    __builtin_amdgcn_global_load_lds((gas1_u32)g, (las3_u32)l, 16, 0, 0);
}

// ---------------------------------------------------------------------------
// prep: fused convx (X->f16) + prep_e (ET + Epack from one LDS tile) + nhen
// + counter zeroing. Branch by blockIdx range; the three jobs are independent.
// ---------------------------------------------------------------------------
__global__ void prep_kernel(const float* __restrict__ X, const float* __restrict__ E,
                            f16* __restrict__ X16, float* __restrict__ ET,
                            f16* __restrict__ Epack, float* __restrict__ nhen,
                            int* __restrict__ count, int* __restrict__ count3) {
    __shared__ float t[64][65];
    const int bid = blockIdx.x;
    if (bid < NB_CONV) {
        if (bid == 0 && threadIdx.x == 0) { *count = 0; *count3 = 0; }
        const size_t i = ((size_t)bid * 256 + threadIdx.x) * 8;
        float4 a = *reinterpret_cast<const float4*>(X + i);
        float4 b = *reinterpret_cast<const float4*>(X + i + 4);
        f16x8 o;
        o[0]=(f16)a.x; o[1]=(f16)a.y; o[2]=(f16)a.z; o[3]=(f16)a.w;
        o[4]=(f16)b.x; o[5]=(f16)b.y; o[6]=(f16)b.z; o[7]=(f16)b.w;
        *reinterpret_cast<f16x8*>(X16 + i) = o;
    } else if (bid < NB_CONV + NB_PREPE) {
        const int pb = bid - NB_CONV;
        const int bk = pb & (K_DIM / 64 - 1);   // 128 k-tiles
        const int bd = pb >> 7;                 // 4 d-tiles
        const int c  = threadIdx.x & 63;
        const int r0 = (threadIdx.x >> 6) * 16;
        const int d0 = bd * 64, k0 = bk * 64;
#pragma unroll
        for (int i = 0; i < 16; ++i)
            t[r0 + i][c] = E[(size_t)(d0 + r0 + i) * K_DIM + k0 + c];
        __syncthreads();
        // ET[k][d] = E[d][k]
#pragma unroll
        for (int i = 0; i < 16; ++i)
            ET[(size_t)(k0 + r0 + i) * D_DIM + d0 + c] = t[c][r0 + i];
        // Epack[(tile*8+tg)*512 + l*8 + j] = E[32tg+(l>>4)*8+j][16*tile+(l&15)]
#pragma unroll
        for (int o = 0; o < 2; ++o) {
            const int out = threadIdx.x + o * 256;
            const int i16 = out >> 7;          // k-subtile 0..3
            const int th  = (out >> 6) & 1;    // d-half 0..1
            const int l   = out & 63;
            const int tile = bk * 4 + i16;
            const int tg   = bd * 2 + th;
            f16x8 frag;
#pragma unroll
            for (int j = 0; j < 8; ++j)
                frag[j] = (f16)t[32*th + (l >> 4) * 8 + j][16*i16 + (l & 15)];
            *reinterpret_cast<f16x8*>(Epack + ((size_t)(tile*8 + tg) * 512 + l * 8)) = frag;
        }
    } else {
        const int k = (bid - NB_CONV - NB_PREPE) * 256 + threadIdx.x;
        float s = 0.0f;
#pragma unroll 8
        for (int d = 0; d < D_DIM; ++d) {
            float v = E[(size_t)d * K_DIM + k];
            s = fmaf(v, v, s);
        }
        nhen[k] = -0.5f * s;
    }
}

// ---- standalone kernels for the reduced-workspace path ---------------------
__global__ void convx_kernel(const float* __restrict__ X, f16* __restrict__ X16,
                             int* __restrict__ count, int* __restrict__ count3) {
    if (blockIdx.x == 0 && threadIdx.x == 0) { *count = 0; *count3 = 0; }
    const size_t i = ((size_t)blockIdx.x * 256 + threadIdx.x) * 8;
    float4 a = *reinterpret_cast<const float4*>(X + i);
    float4 b = *reinterpret_cast<const float4*>(X + i + 4);
    f16x8 o;
    o[0]=(f16)a.x; o[1]=(f16)a.y; o[2]=(f16)a.z; o[3]=(f16)a.w;
    o[4]=(f16)b.x; o[5]=(f16)b.y; o[6]=(f16)b.z; o[7]=(f16)b.w;
    *reinterpret_cast<f16x8*>(X16 + i) = o;
}

__global__ void packe_kernel(const float* __restrict__ E, f16* __restrict__ Epack) {
    const int gid = blockIdx.x * 256 + threadIdx.x;
    const int l    = gid & 63;
    const int t    = (gid >> 6) & 7;
    const int tile = gid >> 9;
    const int k  = 16 * tile + (l & 15);
    const int d0 = 32 * t + (l >> 4) * 8;
    f16x8 o;
#pragma unroll
    for (int j = 0; j < 8; ++j) o[j] = (f16)E[(size_t)(d0 + j) * K_DIM + k];
    *reinterpret_cast<f16x8*>(Epack + (size_t)gid * 8) = o;
}

__global__ void nhen_kernel(const float* __restrict__ E, float* __restrict__ nhen) {
    const int k = blockIdx.x * 256 + threadIdx.x;
    float s = 0.0f;
#pragma unroll 8
    for (int d = 0; d < D_DIM; ++d) {
        float v = E[(size_t)d * K_DIM + k];
        s = fmaf(v, v, s);
    }
    nhen[k] = -0.5f * s;
}

// ---------------------------------------------------------------------------
// pass1 (round-10, unchanged): f16 MFMA fused GEMM + per-row top-2 argmax of
// u = x.e - 0.5||e||^2, deferred-scoring ping-pong + counted-vmcnt staging.
// ---------------------------------------------------------------------------
__launch_bounds__(256, 2)
__global__ void pass1_kernel(const f16* __restrict__ X16,
                             const f16* __restrict__ Epack,
                             const float* __restrict__ nhen,
                             float* __restrict__ p_best,
                             float* __restrict__ p_sec,
                             int*   __restrict__ p_idx) {
    __shared__ f16 B_lds[3][CHUNK_BYTES / 2];   // 3 x 16KB rotating
    __shared__ float nh_lds[COLS_PER_SPLIT];    // 4KB

    const int tid = threadIdx.x;
    const int wv = tid >> 6;
    const int lane = tid & 63;
    const int l15 = lane & 15;
    const int l4  = lane >> 4;
    const int rg = blockIdx.x >> 3;
    const int ks = blockIdx.x & 7;
    const int rowW = rg * 256 + wv * 64;
    const int colBase = ks * COLS_PER_SPLIT;

    f16x8 A[4][8];
#pragma unroll
    for (int rt = 0; rt < 4; ++rt)
#pragma unroll
        for (int t = 0; t < 8; ++t)
            A[rt][t] = *reinterpret_cast<const f16x8*>(
                X16 + (size_t)(rowW + 16*rt + l15) * D_DIM + 32*t + l4*8);

    *reinterpret_cast<float4*>(&nh_lds[tid * 4]) =
        *reinterpret_cast<const float4*>(nhen + colBase + tid * 4);

    float best[16], sec[16];
    int bbase[16];
#pragma unroll
    for (int s = 0; s < 16; ++s) { best[s] = -INFINITY; sec[s] = -INFINITY; bbase[s] = 0; }

    const char* splitSrc = (const char*)Epack + (size_t)colBase * 512;

    auto STAGE = [&](int buf, int ci) {
        const char* csrc = splitSrc + (size_t)ci * CHUNK_BYTES;
        char* cdst = (char*)&B_lds[buf][0];
#pragma unroll
        for (int c = 0; c < 4; ++c) {
            const int seg = wv * 4 + c;
            gload_lds16(csrc + seg * 1024 + (lane << 4), cdst + seg * 1024);
        }
    };

    f32x4 accA[4], accB[4];
    int cA = 0, cB = 0;

    auto TILE = [&](const f16* bufc, int ct, int nhoff,
                    f32x4 (&accN)[4], f32x4 (&accP)[4], int cP, bool doScore) {
        const float nh = nh_lds[nhoff + l15];
        const f32x4 nh4 = {nh, nh, nh, nh};
#pragma unroll
        for (int t = 0; t < 8; ++t) {
            f16x8 B = *reinterpret_cast<const f16x8*>(bufc + (ct*8 + t)*512 + lane*8);
            if (t == 0) {
#pragma unroll
                for (int rt = 0; rt < 4; ++rt)
                    accN[rt] = __builtin_amdgcn_mfma_f32_16x16x32_f16(A[rt][0], B, nh4, 0, 0, 0);
            } else {
#pragma unroll
                for (int rt = 0; rt < 4; ++rt)
                    accN[rt] = __builtin_amdgcn_mfma_f32_16x16x32_f16(A[rt][t], B, accN[rt], 0, 0, 0);
            }
            if (doScore) {
#pragma unroll
                for (int s = 2*t; s <= 2*t + 1; ++s) {
                    const int rt2 = s >> 2, r2 = s & 3;
                    const float v = accP[rt2][r2];
                    sec[s] = __builtin_amdgcn_fmed3f(v, best[s], sec[s]);
                    const bool gt = v > best[s];
                    best[s] = gt ? v : best[s];
                    bbase[s] = gt ? cP : bbase[s];
                }
            }
        }
    };

    STAGE(0, 0);
    STAGE(1, 1);
    asm volatile("s_waitcnt lgkmcnt(0)" ::: "memory");  // nh_lds writes drained

    int cur = 0;
    for (int ci = 0; ci < NCHUNK; ++ci) {
        if (ci < NCHUNK - 1) {
            asm volatile("s_waitcnt vmcnt(4)" ::: "memory");  // own stage(ci) done
        } else {
            asm volatile("s_waitcnt vmcnt(0)" ::: "memory");
        }
        __builtin_amdgcn_s_barrier();
        if (ci + 2 < NCHUNK) {
            int nb = cur + 2; if (nb >= 3) nb -= 3;
            STAGE(nb, ci + 2);
        }
        const f16* bufc = &B_lds[cur][0];
        const int base = colBase + ci * CHUNK_COLS;
        if (ci == 0) {
            TILE(bufc, 0, ci*32,      accA, accB, cB, false); cA = base;
            TILE(bufc, 1, ci*32 + 16, accB, accA, cA, true);  cB = base + 16;
        } else {
            TILE(bufc, 0, ci*32,      accA, accB, cB, true);  cA = base;
            TILE(bufc, 1, ci*32 + 16, accB, accA, cA, true);  cB = base + 16;
        }
        cur = (cur + 1 == 3) ? 0 : cur + 1;
    }
#pragma unroll
    for (int s = 0; s < 16; ++s) {
        const int rt2 = s >> 2, r2 = s & 3;
        const float v = accB[rt2][r2];
        sec[s] = __builtin_amdgcn_fmed3f(v, best[s], sec[s]);
        const bool gt = v > best[s];
        best[s] = gt ? v : best[s];
        bbase[s] = gt ? cB : bbase[s];
    }

#pragma unroll
    for (int s = 0; s < 16; ++s) {
        float b = best[s], sc = sec[s];
        int k = bbase[s] + l15;
#pragma unroll
        for (int off = 8; off >= 1; off >>= 1) {
            float ob = __shfl_xor(b, off, 16);
            float os = __shfl_xor(sc, off, 16);
            int   ok = __shfl_xor(k, off, 16);
            float sm = fmaxf(fmaxf(sc, os), fminf(b, ob));
            bool take = (ob > b) || (ob == b && ok < k);
            b = take ? ob : b;
            k = take ? ok : k;
            sc = sm;
        }
        if (l15 == 0) {
            const int row = rowW + 16*(s >> 2) + 4*l4 + (s & 3);
            p_best[ks * N_ROWS + row] = b;
            p_sec [ks * N_ROWS + row] = sc;
            p_idx [ks * N_ROWS + row] = k;
        }
    }
}

// ---------------------------------------------------------------------------
// merge K-splits; flag rows with gap < EPS1 into compacted tier-2 list
__global__ void merge_kernel(const float* __restrict__ p_best,
                             const float* __restrict__ p_sec,
                             const int*   __restrict__ p_idx,
                             int* __restrict__ idxf,
                             int* __restrict__ list, int* __restrict__ count) {
    const int n = blockIdx.x * 256 + threadIdx.x;
    float b = p_best[n], sc = p_sec[n];
    int k = p_idx[n];
#pragma unroll
    for (int s = 1; s < KSPLIT; ++s) {
        float ob = p_best[s * N_ROWS + n];
        float os = p_sec [s * N_ROWS + n];
        int   ok = p_idx [s * N_ROWS + n];
        float sm = fmaxf(fmaxf(sc, os), fminf(b, ob));
        bool take = ob > b;            // equal -> keep earlier split (smaller k)
        b = take ? ob : b; k = take ? ok : k; sc = sm;
    }
    idxf[n] = k;
    if (2.0f * (b - sc) < EPS1) {
        int pos = atomicAdd(count, 1);
        if (pos < T2CAP) list[pos] = n;
    }
}

// ---------------------------------------------------------------------------
// tier-2: fp32 rescan of flagged rows. Block = (group of 64 rows) x (256-col
// split, 32 splits). Tracks top-2 max of u = dot + nhen.
// ---------------------------------------------------------------------------
__launch_bounds__(256, 2)
__global__ void tier2_kernel(const float* __restrict__ X,
                             const float* __restrict__ E,
                             const float* __restrict__ nhen,
                             const int* __restrict__ list,
                             const int* __restrict__ count,
                             float* __restrict__ t2b, float* __restrict__ t2s,
                             int* __restrict__ t2i) {
    const int g  = blockIdx.x >> 5;
    const int sp = blockIdx.x & 31;
    const int cnt = min(*count, T2CAP);
    if (g * 64 >= cnt) return;

    __shared__ float xT[D_DIM][64];
    __shared__ float es[64][64];
    const int tid = threadIdx.x;
    const int tx = tid & 15, ty = tid >> 4;

    {
        const int r = tid >> 2;
        const int slot = min(g * 64 + r, cnt - 1);
        const int row = list[slot];
        const int d0 = (tid & 3) * 64;
        const float* xp = X + (size_t)row * D_DIM + d0;
#pragma unroll
        for (int i = 0; i < 64; i += 4) {
            float4 v = *reinterpret_cast<const float4*>(xp + i);
            xT[d0+i+0][r] = v.x; xT[d0+i+1][r] = v.y;
            xT[d0+i+2][r] = v.z; xT[d0+i+3][r] = v.w;
        }
    }

    float best[4], sec[4]; int bidx[4];
#pragma unroll
    for (int i = 0; i < 4; ++i) { best[i] = -INFINITY; sec[i] = -INFINITY; bidx[i] = 0; }

    const int colBase = sp * 256;
    for (int kc = 0; kc < 256; kc += 64) {
        float acc[4][4];
#pragma unroll
        for (int i = 0; i < 4; ++i)
#pragma unroll
            for (int j = 0; j < 4; ++j) acc[i][j] = 0.0f;

        for (int dc = 0; dc < D_DIM; dc += 64) {
            __syncthreads();
#pragma unroll
            for (int dd = 0; dd < 64; dd += 16) {
                int d = dd + (tid >> 4);
                float4 v = *reinterpret_cast<const float4*>(
                    &E[(size_t)(dc + d) * K_DIM + colBase + kc + (tid & 15) * 4]);
                *reinterpret_cast<float4*>(&es[d][(tid & 15) * 4]) = v;
            }
            __syncthreads();
#pragma unroll 8
            for (int d = 0; d < 64; ++d) {
                float4 xv = *reinterpret_cast<const float4*>(&xT[dc + d][ty * 4]);
                float4 ev = *reinterpret_cast<const float4*>(&es[d][tx * 4]);
                float xr[4] = {xv.x, xv.y, xv.z, xv.w};
                float ec[4] = {ev.x, ev.y, ev.z, ev.w};
#pragma unroll
                for (int i = 0; i < 4; ++i)
#pragma unroll
                    for (int j = 0; j < 4; ++j)
                        acc[i][j] = fmaf(xr[i], ec[j], acc[i][j]);
            }
        }
        float4 nhv = *reinterpret_cast<const float4*>(&nhen[colBase + kc + tx * 4]);
        float nh[4] = {nhv.x, nhv.y, nhv.z, nhv.w};
#pragma unroll
        for (int j = 0; j < 4; ++j) {
            const int k = colBase + kc + tx * 4 + j;
#pragma unroll
            for (int i = 0; i < 4; ++i) {
                float u = nh[j] + acc[i][j];
                bool gt = u > best[i];
                sec[i]  = fmaxf(sec[i], fminf(u, best[i]));
                best[i] = gt ? u : best[i];
                bidx[i] = gt ? k : bidx[i];
            }
        }
    }

#pragma unroll
    for (int off = 8; off >= 1; off >>= 1) {
#pragma unroll
        for (int i = 0; i < 4; ++i) {
            float ob = __shfl_xor(best[i], off, 16);
            float os = __shfl_xor(sec[i], off, 16);
            int   ok = __shfl_xor(bidx[i], off, 16);
            float sm = fmaxf(fmaxf(sec[i], os), fminf(best[i], ob));
            bool take = (ob > best[i]) || (ob == best[i] && ok < bidx[i]);
            best[i] = take ? ob : best[i];
            bidx[i] = take ? ok : bidx[i];
            sec[i] = sm;
        }
    }
    if (tx == 0) {
#pragma unroll
        for (int i = 0; i < 4; ++i) {
            const int slot = g * 64 + ty * 4 + i;
            if (slot < cnt) {
                t2b[sp * T2CAP + slot] = best[i];
                t2s[sp * T2CAP + slot] = sec[i];
                t2i[sp * T2CAP + slot] = bidx[i];
            }
        }
    }
}

// merge tier-2 splits; flag knife-edge rows into tier-3 list; init atomic
// slots and mark flagged rows in idxf with -(slot+1).
__global__ void merge2_kernel(const float* __restrict__ t2b,
                              const float* __restrict__ t2s,
                              const int*   __restrict__ t2i,
                              const int* __restrict__ list,
                              const int* __restrict__ count,
                              int* __restrict__ idxf,
                              int* __restrict__ list3, int* __restrict__ count3,
                              u64* __restrict__ t3min) {
    const int slot = blockIdx.x * 256 + threadIdx.x;
    const int cnt = min(*count, T2CAP);
    if (slot >= cnt) return;
    float b = t2b[slot], sc = t2s[slot];
    int k = t2i[slot];
#pragma unroll
    for (int sp = 1; sp < NSPLIT2; ++sp) {
        float ob = t2b[sp * T2CAP + slot];
        float os = t2s[sp * T2CAP + slot];
        int   ok = t2i[sp * T2CAP + slot];
        float sm = fmaxf(fmaxf(sc, os), fminf(b, ob));
        bool take = ob > b;
        b = take ? ob : b; k = take ? ok : k; sc = sm;
    }
    const int n = list[slot];
    if (2.0f * (b - sc) < EPS2) {
        int pos = atomicAdd(count3, 1);
        if (pos < T3CAP) {
            list3[pos] = n;
            t3min[pos] = ~0ull;
            idxf[n] = -(pos + 1);       // gather decodes from t3min
            return;
        }
    }
    idxf[n] = k;
}

// ---------------------------------------------------------------------------
// tier-3: fp64 exact rescan, K split 16 ways across blocks; result merged via
// atomicMin on packed key = (f64 dist bits & ~0x1FFF) | idx  (first-idx ties).
// ---------------------------------------------------------------------------
__launch_bounds__(256)
__global__ void tier3_kernel(const float* __restrict__ X,
                             const float* __restrict__ E,
                             const int* __restrict__ list3,
                             const int* __restrict__ count3,
                             u64* __restrict__ t3min) {
    const int slot = blockIdx.x >> 4;
    const int sp   = blockIdx.x & 15;
    const int cnt = min(*count3, T3CAP);
    if (slot >= cnt) return;
    const int n = list3[slot];

    __shared__ float xs[D_DIM];
    const int tid = threadIdx.x;
    xs[tid] = X[(size_t)n * D_DIM + tid];
    __syncthreads();

    const int colBase = sp * 512;
    double best = DBL_MAX;
    int bi = 0x7fffffff;
#pragma unroll
    for (int kk = 0; kk < 512; kk += 256) {
        const int k = colBase + kk + tid;
        double s0 = 0.0, s1 = 0.0, s2 = 0.0, s3 = 0.0;
#pragma unroll 4
        for (int d = 0; d < D_DIM; d += 4) {
            double f0 = (double)xs[d+0] - (double)E[(size_t)(d+0) * K_DIM + k];
            double f1 = (double)xs[d+1] - (double)E[(size_t)(d+1) * K_DIM + k];
            double f2 = (double)xs[d+2] - (double)E[(size_t)(d+2) * K_DIM + k];
            double f3 = (double)xs[d+3] - (double)E[(size_t)(d+3) * K_DIM + k];
            s0 = fma(f0, f0, s0); s1 = fma(f1, f1, s1);
            s2 = fma(f2, f2, s2); s3 = fma(f3, f3, s3);
        }
        double s = (s0 + s1) + (s2 + s3);
        if (s < best || (s == best && k < bi)) { best = s; bi = k; }
    }

    __shared__ double bv[256];
    __shared__ int bix[256];
    bv[tid] = best; bix[tid] = bi;
    __syncthreads();
    if (tid == 0) {
        double b = bv[0]; int ix = bix[0];
        for (int t = 1; t < 256; ++t)
            if (bv[t] < b || (bv[t] == b && bix[t] < ix)) { b = bv[t]; ix = bix[t]; }
        u64 key = ((u64)__double_as_longlong(b) & ~0x1FFFull) | (u64)(unsigned)ix;
        atomicMin(&t3min[slot], key);
    }
}

// ---------------------------------------------------------------------------
// gather: out[n][:] = ET[idx[n]][:]; negative idx decodes tier-3 atomic slot.
// ---------------------------------------------------------------------------
__global__ void gather2_kernel(const float* __restrict__ ET,
                               const int* __restrict__ idx,
                               const u64* __restrict__ t3min,
                               float* __restrict__ out) {
    const int n  = blockIdx.x * 4 + (threadIdx.x >> 6);
    const int d4 = (threadIdx.x & 63) * 4;
    int k  = idx[n];
    if (k < 0) k = (int)(t3min[-k - 1] & 0x1FFFull);
    *reinterpret_cast<float4*>(&out[(size_t)n * D_DIM + d4]) =
        *reinterpret_cast<const float4*>(&ET[(size_t)k * D_DIM + d4]);
}

// strided gather (no ET workspace); also decodes tier-3 slots
__global__ void gather_kernel(const float* __restrict__ E,
                              const int* __restrict__ idx,
                              const u64* __restrict__ t3min,
                              float* __restrict__ out) {
    const int n = blockIdx.x;
    const int d = threadIdx.x;
    int k = idx[n];
    if (k < 0) k = (int)(t3min[-k - 1] & 0x1FFFull);
    out[(size_t)n * D_DIM + d] = E[(size_t)d * K_DIM + k];
}

// ======================= fallback path (proven round-2) =====================
__global__ void fb_enorm_kernel(const float* __restrict__ E, float* __restrict__ enorm) {
    int k = blockIdx.x * 256 + threadIdx.x;
    float s = 0.0f;
#pragma unroll 8
    for (int d = 0; d < D_DIM; ++d) { float v = E[(size_t)d * K_DIM + k]; s = fmaf(v, v, s); }
    enorm[k] = s;
}

__launch_bounds__(256, 2)
__global__ void fb_dist_kernel(const float* __restrict__ X, const float* __restrict__ E,
                               const float* __restrict__ enorm,
                               int* __restrict__ idx_out, float* __restrict__ gap_out) {
    __shared__ float xT[D_DIM][64];
    __shared__ float es[64][64];
    const int tid = threadIdx.x;
    const int tx = tid & 15, ty = tid >> 4;
    const int rowBase = blockIdx.x * 64;
    {
        const int r = tid >> 2;
        const int d0 = (tid & 3) * 64;
        const float* xp = X + (size_t)(rowBase + r) * D_DIM + d0;
#pragma unroll
        for (int i = 0; i < 64; i += 4) {
            float4 v = *reinterpret_cast<const float4*>(xp + i);
            xT[d0+i+0][r]=v.x; xT[d0+i+1][r]=v.y; xT[d0+i+2][r]=v.z; xT[d0+i+3][r]=v.w;
        }
    }
    float bestVal[4], secVal[4]; int bestIdx[4];
#pragma unroll
    for (int i = 0; i < 4; ++i) { bestVal[i]=INFINITY; secVal[i]=INFINITY; bestIdx[i]=0; }
    for (int kc = 0; kc < K_DIM; kc += 64) {
        float acc[4][4];
#pragma unroll
        for (int i=0;i<4;++i)
#pragma unroll
            for (int j=0;j<4;++j) acc[i][j]=0.f;
        for (int dc = 0; dc < D_DIM; dc += 64) {
            __syncthreads();
#pragma unroll
            for (int dd = 0; dd < 64; dd += 16) {
                int d = dd + (tid >> 4);
                float4 v = *reinterpret_cast<const float4*>(
                    &E[(size_t)(dc+d)*K_DIM + kc + (tid&15)*4]);
                *reinterpret_cast<float4*>(&es[d][(tid&15)*4]) = v;
            }
            __syncthreads();
#pragma unroll 8
            for (int d = 0; d < 64; ++d) {
                float4 xv = *reinterpret_cast<const float4*>(&xT[dc+d][ty*4]);
                float4 ev = *reinterpret_cast<const float4*>(&es[d][tx*4]);
                float xr[4]={xv.x,xv.y,xv.z,xv.w}, ec[4]={ev.x,ev.y,ev.z,ev.w};
#pragma unroll
                for (int i=0;i<4;++i)
#pragma unroll
                    for (int j=0;j<4;++j) acc[i][j]=fmaf(xr[i],ec[j],acc[i][j]);
            }
        }
        float4 env = *reinterpret_cast<const float4*>(&enorm[kc + tx*4]);
        float en[4]={env.x,env.y,env.z,env.w};
#pragma unroll
        for (int j=0;j<4;++j) {
            int k = kc + tx*4 + j;
#pragma unroll
            for (int i=0;i<4;++i) {
                float s = fmaf(-2.0f, acc[i][j], en[j]);
                if (s < bestVal[i]) { secVal[i]=bestVal[i]; bestVal[i]=s; bestIdx[i]=k; }
                else if (s < secVal[i]) secVal[i]=s;
            }
        }
    }
#pragma unroll
    for (int off=8; off>=1; off>>=1) {
#pragma unroll
        for (int i=0;i<4;++i) {
            float oB=__shfl_xor(bestVal[i],off,16);
            int oI=__shfl_xor(bestIdx[i],off,16);
            float oS=__shfl_xor(secVal[i],off,16);
            float ms=fminf(fminf(secVal[i],oS),fmaxf(bestVal[i],oB));
            if (oB<bestVal[i] || (oB==bestVal[i] && oI<bestIdx[i])) { bestVal[i]=oB; bestIdx[i]=oI; }
            secVal[i]=ms;
        }
    }
    if (tx==0) {
#pragma unroll
        for (int i=0;i<4;++i) {
            idx_out[rowBase + ty*4 + i] = bestIdx[i];
            gap_out[rowBase + ty*4 + i] = secVal[i]-bestVal[i];
        }
    }
}

__launch_bounds__(256)
__global__ void fb_refine_kernel(const float* __restrict__ X, const float* __restrict__ E,
                                 const float* __restrict__ gap, int* __restrict__ idx) {
    const int n = blockIdx.x;
    if (gap[n] >= 0.0625f) return;
    __shared__ float xs[D_DIM];
    const int tid = threadIdx.x;
    xs[tid] = X[(size_t)n * D_DIM + tid];
    __syncthreads();
    double best = DBL_MAX; int bi = 0x7fffffff;
    for (int k = tid; k < K_DIM; k += 256) {
        double s0=0,s1=0,s2=0,s3=0;
#pragma unroll 4
        for (int d = 0; d < D_DIM; d += 4) {
            double f0=(double)xs[d+0]-(double)E[(size_t)(d+0)*K_DIM+k];
            double f1=(double)xs[d+1]-(double)E[(size_t)(d+1)*K_DIM+k];
            double f2=(double)xs[d+2]-(double)E[(size_t)(d+2)*K_DIM+k];
            double f3=(double)xs[d+3]-(double)E[(size_t)(d+3)*K_DIM+k];
            s0=fma(f0,f0,s0); s1=fma(f1,f1,s1); s2=fma(f2,f2,s2); s3=fma(f3,f3,s3);
        }
        double s=(s0+s1)+(s2+s3);
        if (s<best){best=s;bi=k;}
    }
    __shared__ double bv[256]; __shared__ int bix[256];
    bv[tid]=best; bix[tid]=bi;
    __syncthreads();
    if (tid==0) {
        double b=bv[0]; int ix=bix[0];
        for (int t=1;t<256;++t)
            if (bv[t]<b || (bv[t]==b && bix[t]<ix)) { b=bv[t]; ix=bix[t]; }
        idx[n]=ix;
    }
}

__global__ void fb_gather_kernel(const float* __restrict__ E,
                                 const int* __restrict__ idx,
                                 float* __restrict__ out) {
    const int n = blockIdx.x;
    const int d = threadIdx.x;
    const int k = idx[n];
    out[(size_t)n * D_DIM + d] = E[(size_t)d * K_DIM + k];
}

// ---------------------------------------------------------------------------
extern "C" void kernel_launch(void* const* d_in, const int* in_sizes, int n_in,
                              void* d_out, int out_size, void* d_ws, size_t ws_size,
                              hipStream_t stream) {
    const float* X = (const float*)d_in[0];
    const float* E = (const float*)d_in[1];
    float* out = (float*)d_out;
    char* ws = (char*)d_ws;

    // fast-path workspace layout
    const size_t o_nhen  = 0;                                       // K*4
    const size_t o_pb    = 32768;
    const size_t o_ps    = o_pb  + (size_t)KSPLIT * N_ROWS * 4;
    const size_t o_pi    = o_ps  + (size_t)KSPLIT * N_ROWS * 4;
    const size_t o_idx   = o_pi  + (size_t)KSPLIT * N_ROWS * 4;
    const size_t o_list  = o_idx + (size_t)N_ROWS * 4;
    const size_t o_count = o_list + (size_t)T2CAP * 4;              // count @+0, count3 @+4
    const size_t o_t2b   = o_count + 256;
    const size_t o_t2s   = o_t2b + (size_t)NSPLIT2 * T2CAP * 4;
    const size_t o_t2i   = o_t2s + (size_t)NSPLIT2 * T2CAP * 4;
    const size_t o_list3 = o_t2i + (size_t)NSPLIT2 * T2CAP * 4;
    const size_t o_t3min = o_list3 + (size_t)T3CAP * 4;             // 8B-aligned
    const size_t o_x16   = o_t3min + (size_t)T3CAP * 8;
    const size_t o_epack = o_x16 + (size_t)N_ROWS * D_DIM * 2;
    const size_t NEED_BASE = o_epack + (size_t)D_DIM * K_DIM * 2;
    const size_t o_et    = NEED_BASE;                               // optional ET
    const size_t NEED_FULL = o_et + (size_t)D_DIM * K_DIM * 4;

    if (ws_size >= NEED_BASE) {
        float*  nhen  = (float*) (ws + o_nhen);
        float*  p_b   = (float*) (ws + o_pb);
        float*  p_s   = (float*) (ws + o_ps);
        int*    p_i   = (int*)   (ws + o_pi);
        int*    idxf  = (int*)   (ws + o_idx);
        int*    list  = (int*)   (ws + o_list);
        int*    count = (int*)   (ws + o_count);
        int*    count3= (int*)   (ws + o_count + 4);
        float*  t2b   = (float*) (ws + o_t2b);
        float*  t2s   = (float*) (ws + o_t2s);
        int*    t2i   = (int*)   (ws + o_t2i);
        int*    list3 = (int*)   (ws + o_list3);
        u64*    t3min = (u64*)   (ws + o_t3min);
        f16*    X16   = (f16*)   (ws + o_x16);
        f16*    Epack = (f16*)   (ws + o_epack);
        float*  ET    = (float*) (ws + o_et);
        const bool haveET = ws_size >= NEED_FULL;

        if (haveET) {
            prep_kernel<<<NB_CONV + NB_PREPE + NB_NHEN, 256, 0, stream>>>(
                X, E, X16, ET, Epack, nhen, count, count3);
        } else {
            convx_kernel<<<NB_CONV, 256, 0, stream>>>(X, X16, count, count3);
            packe_kernel<<<(K_DIM / 16) * 8 * 64 / 256, 256, 0, stream>>>(E, Epack);
            nhen_kernel<<<NB_NHEN, 256, 0, stream>>>(E, nhen);
        }
        pass1_kernel<<<(N_ROWS / 256) * KSPLIT, 256, 0, stream>>>(
            X16, Epack, nhen, p_b, p_s, p_i);
        merge_kernel<<<N_ROWS / 256, 256, 0, stream>>>(
            p_b, p_s, p_i, idxf, list, count);
        tier2_kernel<<<(T2CAP / 64) * NSPLIT2, 256, 0, stream>>>(
            X, E, nhen, list, count, t2b, t2s, t2i);
        merge2_kernel<<<T2CAP / 256, 256, 0, stream>>>(
            t2b, t2s, t2i, list, count, idxf, list3, count3, t3min);
        tier3_kernel<<<T3CAP * NSPLIT3, 256, 0, stream>>>(
            X, E, list3, count3, t3min);
        if (haveET)
            gather2_kernel<<<N_ROWS / 4, 256, 0, stream>>>(ET, idxf, t3min, out);
        else
            gather_kernel<<<N_ROWS, 256, 0, stream>>>(E, idxf, t3min, out);
    } else {
        float* enorm = (float*)ws;
        int*   idx   = (int*)(ws + 32768);
        float* gap   = (float*)(ws + 32768 + (size_t)N_ROWS * 4);
        fb_enorm_kernel<<<K_DIM / 256, 256, 0, stream>>>(E, enorm);
        fb_dist_kernel<<<N_ROWS / 64, 256, 0, stream>>>(X, E, enorm, idx, gap);
        fb_refine_kernel<<<N_ROWS, 256, 0, stream>>>(X, E, gap, idx);
        fb_gather_kernel<<<N_ROWS, 256, 0, stream>>>(E, idx, out);
    }
}